// Round 5
// baseline (4148.795 us; speedup 1.0000x reference)
//
#include <hip/hip_runtime.h>

#define FD 32
#define KNB 8
#define NITER 5
#define NB 16         // blocks for CSR build kernels
#define H_SPAN 12500  // hist LDS span (50 KB)
#define SC_SPAN 3200  // scatter LDS span (12.8 KB) >= ceil(C/NB)

typedef __bf16 bf16x8 __attribute__((ext_vector_type(8)));
typedef float  f32x4  __attribute__((ext_vector_type(4)));

__device__ __forceinline__ float sigmoidf_(float a) {
    return 1.0f / (1.0f + __expf(-a));
}
__device__ __forceinline__ float tanhf_(float a) {
    return 1.0f - 2.0f / (__expf(2.0f * a) + 1.0f);
}
__device__ __forceinline__ float bf2f(unsigned short u) {
    union { unsigned int i; float f; } v; v.i = ((unsigned int)u) << 16; return v.f;
}

// ---------------- atomic-free CSR build -------------------------------------
// hist: 16 edge-chunked blocks, LDS histogram over 4 channel spans, coalesced
// subcnt[b][c] writes. No global atomics.
__global__ __launch_bounds__(256) void hist_kernel(
    const int* __restrict__ p2c, int* __restrict__ subcnt, int E, int C)
{
    __shared__ int lds[H_SPAN];
    int b = blockIdx.x;
    int EB = (E + NB - 1) / NB;
    int s0 = b * EB;
    int s1 = s0 + EB; if (s1 > E) s1 = E;
    for (int h0 = 0; h0 < C; h0 += H_SPAN) {
        int span = C - h0; if (span > H_SPAN) span = H_SPAN;
        for (int i = threadIdx.x; i < span; i += 256) lds[i] = 0;
        __syncthreads();
        for (int e = s0 + threadIdx.x; e < s1; e += 256) {
            int lo = p2c[e] - h0;
            if (lo >= 0 && lo < span) atomicAdd(&lds[lo], 1);
        }
        __syncthreads();
        for (int i = threadIdx.x; i < span; i += 256)
            subcnt[(size_t)b * C + h0 + i] = lds[i];
        __syncthreads();
    }
}

__global__ __launch_bounds__(256) void colprefix_kernel(
    const int* __restrict__ subcnt, int* __restrict__ counts, int C)
{
    int c = blockIdx.x * blockDim.x + threadIdx.x;
    if (c >= C) return;
    int run = 0;
    #pragma unroll
    for (int b = 0; b < NB; b++) run += subcnt[(size_t)b * C + c];
    counts[c] = run;
}

// single block, 1024 threads: exclusive scan of counts -> offsets
__global__ __launch_bounds__(1024) void scan_offsets_kernel(
    const int* __restrict__ counts, int* __restrict__ offsets, int C)
{
    __shared__ int part[1024];
    int t = threadIdx.x;
    int chunk = (C + 1023) >> 10;
    int base = t * chunk;
    int end = base + chunk; if (end > C) end = C;
    int s = 0;
    for (int i = base; i < end; i++) s += counts[i];
    part[t] = s;
    __syncthreads();
    for (int d = 1; d < 1024; d <<= 1) {
        int v = (t >= d) ? part[t - d] : 0;
        __syncthreads();
        part[t] += v;
        __syncthreads();
    }
    int run = (t == 0) ? 0 : part[t - 1];
    for (int i = base; i < end; i++) {
        offsets[i] = run;
        run += counts[i];
    }
    if (t == 1023) offsets[C] = part[1023];
}

// scatter: each block OWNS a channel range -> every channel's elist segment is
// written by exactly one block (no cross-XCD line sharing, no global atomics).
// Ranks within a channel come from LDS atomics (order irrelevant).
__global__ __launch_bounds__(256) void scatter_kernel(
    const int* __restrict__ p2c, const int* __restrict__ offsets,
    int* __restrict__ elist, int E, int C)
{
    __shared__ int lds[SC_SPAN];
    int b = blockIdx.x;
    int cpb = (C + NB - 1) / NB;
    int c0 = b * cpb;
    int c1 = c0 + cpb; if (c1 > C) c1 = C;
    for (int h0 = c0; h0 < c1; h0 += SC_SPAN) {
        int span = c1 - h0; if (span > SC_SPAN) span = SC_SPAN;
        for (int i = threadIdx.x; i < span; i += 256) lds[i] = 0;
        __syncthreads();
        for (int e = threadIdx.x; e < E; e += 256) {
            int ch = p2c[e];
            int lo = ch - h0;
            if (lo >= 0 && lo < span) {
                int lr = atomicAdd(&lds[lo], 1);
                elist[offsets[ch] + lr] = e >> 3;   // path id (KNB == 8)
            }
        }
        __syncthreads();
    }
}

// ---------------- bf16 shadow init for h_c ----------------------------------

__global__ __launch_bounds__(256) void hc_init_kernel(
    const float* __restrict__ src, __bf16* __restrict__ dst, int n8)
{
    int i = blockIdx.x * blockDim.x + threadIdx.x;
    if (i >= n8) return;
    const float4* s = (const float4*)(src + (size_t)i * 8);
    float4 u = s[0], v = s[1];
    bf16x8 o;
    o[0]=(__bf16)u.x; o[1]=(__bf16)u.y; o[2]=(__bf16)u.z; o[3]=(__bf16)u.w;
    o[4]=(__bf16)v.x; o[5]=(__bf16)v.y; o[6]=(__bf16)v.z; o[7]=(__bf16)v.w;
    ((bf16x8*)dst)[i] = o;
}

// ---------------- fused path kernel (x-side + h-side MFMA) ------------------
template<int HPS>
__global__ __launch_bounds__(256) void path_fused_kernel(
    float* __restrict__ h_p, const int* __restrict__ p2c,
    const __bf16* __restrict__ hcb,
    const float* __restrict__ Wih, const float* __restrict__ Whh,
    const float* __restrict__ bih, const float* __restrict__ bhh,
    __bf16* __restrict__ hpb)
{
    __shared__ float hl[64 * 36];
    const int tid  = threadIdx.x;
    const int wid  = tid >> 6;
    const int lane = tid & 63;
    const int c    = lane & 15;
    const int kg   = lane >> 4;
    const int blk0 = blockIdx.x * 64;

    {
        int r  = tid >> 2;
        int c0 = (tid & 3) * 8;
        const float4* src = (const float4*)(h_p + ((size_t)(blk0 + r)) * FD + c0);
        float4 a = src[0], b = src[1];
        float* d = &hl[r * 36 + c0];
        d[0]=a.x; d[1]=a.y; d[2]=a.z; d[3]=a.w;
        d[4]=b.x; d[5]=b.y; d[6]=b.z; d[7]=b.w;
    }

    bf16x8 Bx[6], Bh[6];
    #pragma unroll
    for (int t = 0; t < 6; t++) {
        const float* wi = Wih + (size_t)(16*t + c) * FD + 8*kg;
        const float* wh = Whh + (size_t)(16*t + c) * FD + 8*kg;
        #pragma unroll
        for (int j = 0; j < 8; j++) {
            Bx[t][j] = (__bf16)wi[j];
            Bh[t][j] = (__bf16)wh[j];
        }
    }
    float bsum[4], bin[2], bhn[2];
    #pragma unroll
    for (int t = 0; t < 4; t++) bsum[t] = bih[16*t + c] + bhh[16*t + c];
    #pragma unroll
    for (int fi = 0; fi < 2; fi++) {
        bin[fi] = bih[64 + 16*fi + c];
        bhn[fi] = bhh[64 + 16*fi + c];
    }

    const int pA = blk0 + wid*16 + c;
    const int4* pp = (const int4*)(p2c + (size_t)pA * KNB);
    int4 ia = pp[0], ib = pp[1];
    int idxA[KNB] = {ia.x, ia.y, ia.z, ia.w, ib.x, ib.y, ib.z, ib.w};
    bf16x8 Ax[KNB];
    #pragma unroll
    for (int k = 0; k < KNB; k++)
        Ax[k] = *(const bf16x8*)(hcb + (size_t)idxA[k] * FD + 8*kg);

    const int rowA = wid*16 + c;
    #pragma unroll
    for (int k = 0; k < KNB; k++) {
        bf16x8 Ah;
        const float* ar = &hl[rowA * 36 + 8*kg];
        #pragma unroll
        for (int j = 0; j < 8; j++) Ah[j] = (__bf16)ar[j];

        const f32x4 z4 = {0.f, 0.f, 0.f, 0.f};
        f32x4 arz[4], xn[2], hn[2];
        #pragma unroll
        for (int t = 0; t < 4; t++) {
            arz[t] = __builtin_amdgcn_mfma_f32_16x16x32_bf16(Ax[k], Bx[t], z4, 0, 0, 0);
            arz[t] = __builtin_amdgcn_mfma_f32_16x16x32_bf16(Ah,    Bh[t], arz[t], 0, 0, 0);
        }
        #pragma unroll
        for (int fi = 0; fi < 2; fi++) {
            xn[fi] = __builtin_amdgcn_mfma_f32_16x16x32_bf16(Ax[k], Bx[4+fi], z4, 0, 0, 0);
            hn[fi] = __builtin_amdgcn_mfma_f32_16x16x32_bf16(Ah,    Bh[4+fi], z4, 0, 0, 0);
        }

        #pragma unroll
        for (int q = 0; q < 4; q++) {
            float* hrow = &hl[(wid*16 + 4*kg + q) * 36];
            #pragma unroll
            for (int fi = 0; fi < 2; fi++) {
                float r = sigmoidf_(arz[fi][q]   + bsum[fi]);
                float z = sigmoidf_(arz[2+fi][q] + bsum[2+fi]);
                float n = tanhf_(xn[fi][q] + bin[fi] + r * (hn[fi][q] + bhn[fi]));
                float ho = hrow[c + 16*fi];
                hrow[c + 16*fi] = (1.0f - z) * n + z * ho;
            }
        }
    }

    {
        int r  = tid >> 2;
        int c0 = (tid & 3) * 8;
        const float* s = &hl[r * 36 + c0];
        float4 a, b;
        a.x=s[0]; a.y=s[1]; a.z=s[2]; a.w=s[3];
        b.x=s[4]; b.y=s[5]; b.z=s[6]; b.w=s[7];
        float4* dst = (float4*)(h_p + ((size_t)(blk0 + r)) * FD + c0);
        dst[0] = a; dst[1] = b;
        if (HPS) {
            bf16x8 o;
            o[0]=(__bf16)a.x; o[1]=(__bf16)a.y; o[2]=(__bf16)a.z; o[3]=(__bf16)a.w;
            o[4]=(__bf16)b.x; o[5]=(__bf16)b.y; o[6]=(__bf16)b.z; o[7]=(__bf16)b.w;
            *(bf16x8*)(hpb + ((size_t)(blk0 + r)) * FD + c0) = o;
        }
    }
}

// ---------------- fused gather + GRU2 (1 thread / channel) ------------------
// Math identical to gather_agg + channel_update: bf16 rows summed in f32,
// GRU2 fully scalar f32 -> no new rounding vs round 4.
template<int GBF, int WSH>
__global__ __launch_bounds__(256) void gather_gru2_kernel(
    const void* __restrict__ hsrc, const int* __restrict__ offsets,
    const int* __restrict__ elist, float* __restrict__ h_c,
    const float* __restrict__ Wih, const float* __restrict__ Whh,
    const float* __restrict__ bih, const float* __restrict__ bhh,
    __bf16* __restrict__ hcb, int C)
{
    int c = blockIdx.x * blockDim.x + threadIdx.x;
    if (c >= C) return;
    int s = offsets[c], e = offsets[c + 1];

    float x[FD];
    #pragma unroll
    for (int i = 0; i < FD; i++) x[i] = 0.f;

    if (GBF) {
        const __bf16* hb = (const __bf16*)hsrc;
        #pragma unroll 2
        for (int i = s; i < e; i++) {
            const bf16x8* r = (const bf16x8*)(hb + (size_t)elist[i] * FD);
            bf16x8 v0 = r[0], v1 = r[1], v2 = r[2], v3 = r[3];
            #pragma unroll
            for (int j = 0; j < 8; j++) {
                x[j]      += (float)v0[j];
                x[8 + j]  += (float)v1[j];
                x[16 + j] += (float)v2[j];
                x[24 + j] += (float)v3[j];
            }
        }
    } else {
        const float* hf = (const float*)hsrc;
        #pragma unroll 2
        for (int i = s; i < e; i++) {
            const float4* r = (const float4*)(hf + (size_t)elist[i] * FD);
            #pragma unroll
            for (int g = 0; g < 8; g++) {
                float4 v = r[g];
                x[4*g] += v.x; x[4*g+1] += v.y; x[4*g+2] += v.z; x[4*g+3] += v.w;
            }
        }
    }

    float h[FD];
    const float4* hr = (const float4*)(h_c + (size_t)c * FD);
    #pragma unroll
    for (int i = 0; i < FD / 4; i++) {
        float4 v = hr[i];
        h[4*i] = v.x; h[4*i+1] = v.y; h[4*i+2] = v.z; h[4*i+3] = v.w;
    }

    float hn[FD];
    #pragma unroll 4
    for (int j = 0; j < FD; j++) {
        float air = bih[j],        ahr = bhh[j];
        float aiz = bih[FD + j],   ahz = bhh[FD + j];
        float ain = bih[2*FD + j], ahn = bhh[2*FD + j];
        #pragma unroll
        for (int i = 0; i < FD; i++) {
            air = fmaf(Wih[j*FD + i],          x[i], air);
            ahr = fmaf(Whh[j*FD + i],          h[i], ahr);
            aiz = fmaf(Wih[(FD + j)*FD + i],   x[i], aiz);
            ahz = fmaf(Whh[(FD + j)*FD + i],   h[i], ahz);
            ain = fmaf(Wih[(2*FD + j)*FD + i], x[i], ain);
            ahn = fmaf(Whh[(2*FD + j)*FD + i], h[i], ahn);
        }
        float r = sigmoidf_(air + ahr);
        float z = sigmoidf_(aiz + ahz);
        float n = tanhf_(ain + r * ahn);
        hn[j] = (1.0f - z) * n + z * h[j];
    }

    float4* hw = (float4*)(h_c + (size_t)c * FD);
    #pragma unroll
    for (int i = 0; i < FD / 4; i++) {
        float4 v;
        v.x = hn[4*i]; v.y = hn[4*i+1]; v.z = hn[4*i+2]; v.w = hn[4*i+3];
        hw[i] = v;
    }
    if (WSH) {
        #pragma unroll
        for (int g = 0; g < 4; g++) {
            bf16x8 o;
            #pragma unroll
            for (int j = 0; j < 8; j++) o[j] = (__bf16)hn[8*g + j];
            *(bf16x8*)(hcb + (size_t)c * FD + 8*g) = o;
        }
    }
}

// ---------------- fallback kernels (tiers 3/4) ------------------------------

__global__ __launch_bounds__(256) void path_update_kernel(
    const float* __restrict__ h_c, float* __restrict__ h_p,
    const int* __restrict__ p2c,
    const float* __restrict__ Wih, const float* __restrict__ Whh,
    const float* __restrict__ bih, const float* __restrict__ bhh, int P)
{
    int p = blockIdx.x * blockDim.x + threadIdx.x;
    if (p >= P) return;

    float h[FD];
    const float4* hp4 = (const float4*)(h_p + (size_t)p * FD);
    #pragma unroll
    for (int i = 0; i < FD / 4; i++) {
        float4 v = hp4[i];
        h[4*i] = v.x; h[4*i+1] = v.y; h[4*i+2] = v.z; h[4*i+3] = v.w;
    }

    int idx[KNB];
    const int4* pi = (const int4*)(p2c + (size_t)p * KNB);
    int4 i0 = pi[0], i1 = pi[1];
    idx[0]=i0.x; idx[1]=i0.y; idx[2]=i0.z; idx[3]=i0.w;
    idx[4]=i1.x; idx[5]=i1.y; idx[6]=i1.z; idx[7]=i1.w;

    for (int k = 0; k < KNB; k++) {
        float x[FD];
        const float4* xr = (const float4*)(h_c + (size_t)idx[k] * FD);
        #pragma unroll
        for (int i = 0; i < FD / 4; i++) {
            float4 v = xr[i];
            x[4*i] = v.x; x[4*i+1] = v.y; x[4*i+2] = v.z; x[4*i+3] = v.w;
        }

        float hn[FD];
        #pragma unroll 4
        for (int j = 0; j < FD; j++) {
            float air = bih[j],        ahr = bhh[j];
            float aiz = bih[FD + j],   ahz = bhh[FD + j];
            float ain = bih[2*FD + j], ahn = bhh[2*FD + j];
            #pragma unroll
            for (int i = 0; i < FD; i++) {
                air = fmaf(Wih[j*FD + i],          x[i], air);
                ahr = fmaf(Whh[j*FD + i],          h[i], ahr);
                aiz = fmaf(Wih[(FD + j)*FD + i],   x[i], aiz);
                ahz = fmaf(Whh[(FD + j)*FD + i],   h[i], ahz);
                ain = fmaf(Wih[(2*FD + j)*FD + i], x[i], ain);
                ahn = fmaf(Whh[(2*FD + j)*FD + i], h[i], ahn);
            }
            float r = sigmoidf_(air + ahr);
            float z = sigmoidf_(aiz + ahz);
            float n = tanhf_(ain + r * ahn);
            hn[j] = (1.0f - z) * n + z * h[j];
        }
        #pragma unroll
        for (int j = 0; j < FD; j++) h[j] = hn[j];
    }

    float4* hpw = (float4*)(h_p + (size_t)p * FD);
    #pragma unroll
    for (int i = 0; i < FD / 4; i++) {
        float4 v;
        v.x = h[4*i]; v.y = h[4*i+1]; v.z = h[4*i+2]; v.w = h[4*i+3];
        hpw[i] = v;
    }
}

__global__ __launch_bounds__(256) void scatter_agg_atomic_kernel(
    const float* __restrict__ h_p, const int* __restrict__ p2c,
    float* __restrict__ agg, int P)
{
    int p = blockIdx.x * blockDim.x + threadIdx.x;
    if (p >= P) return;
    const float* hr = h_p + (size_t)p * FD;
    #pragma unroll
    for (int k = 0; k < KNB; k++) {
        int c = p2c[(size_t)p * KNB + k];
        float* ar = agg + (size_t)c * FD;
        #pragma unroll
        for (int i = 0; i < FD; i++) atomicAdd(ar + i, hr[i]);
    }
}

__global__ __launch_bounds__(256) void gather_agg_kernel(
    const float* __restrict__ hsrc, const int* __restrict__ offsets,
    const int* __restrict__ elist, float* __restrict__ agg, int C)
{
    int tid = blockIdx.x * blockDim.x + threadIdx.x;
    int c = tid >> 5;
    int feat = tid & 31;
    if (c >= C) return;
    int s = offsets[c], e = offsets[c + 1];
    float acc0 = 0.f, acc1 = 0.f;
    int i = s;
    for (; i + 2 <= e; i += 2) {
        acc0 += hsrc[(size_t)elist[i]     * FD + feat];
        acc1 += hsrc[(size_t)elist[i + 1] * FD + feat];
    }
    if (i < e) acc0 += hsrc[(size_t)elist[i] * FD + feat];
    agg[(size_t)c * FD + feat] = acc0 + acc1;
}

__global__ __launch_bounds__(256) void channel_update_kernel(
    const float* __restrict__ agg, float* __restrict__ h_c,
    const float* __restrict__ Wih, const float* __restrict__ Whh,
    const float* __restrict__ bih, const float* __restrict__ bhh, int C)
{
    int c = blockIdx.x * blockDim.x + threadIdx.x;
    if (c >= C) return;

    float h[FD], x[FD];
    const float4* hr = (const float4*)(h_c + (size_t)c * FD);
    const float4* xr = (const float4*)(agg + (size_t)c * FD);
    #pragma unroll
    for (int i = 0; i < FD / 4; i++) {
        float4 v = hr[i];
        h[4*i] = v.x; h[4*i+1] = v.y; h[4*i+2] = v.z; h[4*i+3] = v.w;
        float4 w = xr[i];
        x[4*i] = w.x; x[4*i+1] = w.y; x[4*i+2] = w.z; x[4*i+3] = w.w;
    }

    float hn[FD];
    #pragma unroll 4
    for (int j = 0; j < FD; j++) {
        float air = bih[j],        ahr = bhh[j];
        float aiz = bih[FD + j],   ahz = bhh[FD + j];
        float ain = bih[2*FD + j], ahn = bhh[2*FD + j];
        #pragma unroll
        for (int i = 0; i < FD; i++) {
            air = fmaf(Wih[j*FD + i],          x[i], air);
            ahr = fmaf(Whh[j*FD + i],          h[i], ahr);
            aiz = fmaf(Wih[(FD + j)*FD + i],   x[i], aiz);
            ahz = fmaf(Whh[(FD + j)*FD + i],   h[i], ahz);
            ain = fmaf(Wih[(2*FD + j)*FD + i], x[i], ain);
            ahn = fmaf(Whh[(2*FD + j)*FD + i], h[i], ahn);
        }
        float r = sigmoidf_(air + ahr);
        float z = sigmoidf_(aiz + ahz);
        float n = tanhf_(ain + r * ahn);
        hn[j] = (1.0f - z) * n + z * h[j];
    }

    float4* hw = (float4*)(h_c + (size_t)c * FD);
    #pragma unroll
    for (int i = 0; i < FD / 4; i++) {
        float4 v;
        v.x = hn[4*i]; v.y = hn[4*i+1]; v.z = hn[4*i+2]; v.w = hn[4*i+3];
        hw[i] = v;
    }
}

extern "C" void kernel_launch(void* const* d_in, const int* in_sizes, int n_in,
                              void* d_out, int out_size, void* d_ws, size_t ws_size,
                              hipStream_t stream) {
    const float* paths    = (const float*)d_in[0];
    const float* channels = (const float*)d_in[1];
    const int*   p2c      = (const int*)d_in[2];
    const float* Wih1 = (const float*)d_in[3];
    const float* Whh1 = (const float*)d_in[4];
    const float* bih1 = (const float*)d_in[5];
    const float* bhh1 = (const float*)d_in[6];
    const float* Wih2 = (const float*)d_in[7];
    const float* Whh2 = (const float*)d_in[8];
    const float* bih2 = (const float*)d_in[9];
    const float* bhh2 = (const float*)d_in[10];

    const int P = in_sizes[0] / FD;   // 200000
    const int C = in_sizes[1] / FD;   // 50000
    const int E = P * KNB;            // 1.6M edges

    float* h_p = (float*)d_out;                  // [P*FD]
    float* h_c = h_p + (size_t)P * FD;           // [C*FD]

    // ws layout: subcnt[NB*C] | counts[C] | offsets[C+1] | elist[E] | hcb | hpb
    char* ws = (char*)d_ws;
    size_t sub_off  = 0;
    size_t sub_b    = (size_t)NB * C * sizeof(int);               // 3.2 MB
    size_t cnt_off  = (sub_off + sub_b + 255) & ~(size_t)255;
    size_t cnt_b    = (size_t)C * sizeof(int);
    size_t ofs_off  = (cnt_off + cnt_b + 255) & ~(size_t)255;
    size_t ofs_b    = (size_t)(C + 1) * sizeof(int);
    size_t el_off   = (ofs_off + ofs_b + 255) & ~(size_t)255;
    size_t el_b     = (size_t)E * sizeof(int);
    size_t hcb_off  = (el_off + el_b + 255) & ~(size_t)255;
    size_t hcb_b    = (size_t)C * FD * sizeof(unsigned short);    // 3.2 MB
    size_t hpb_off  = (hcb_off + hcb_b + 255) & ~(size_t)255;
    size_t hpb_b    = (size_t)P * FD * sizeof(unsigned short);    // 12.8 MB
    size_t agg_b    = (size_t)C * FD * sizeof(float);             // 6.4 MB

    int*    subcnt  = (int*)(ws + sub_off);
    int*    counts  = (int*)(ws + cnt_off);
    int*    offsets = (int*)(ws + ofs_off);
    int*    elist   = (int*)(ws + el_off);
    __bf16* hcb     = (__bf16*)(ws + hcb_off);
    __bf16* hpb     = (__bf16*)(ws + hpb_off);
    float*  agg     = (float*)(ws + hcb_off);   // tier-3 only (agg replaces hcb slot)

    const bool mfma_ok = (P % 64 == 0) && ((C * FD) % 8 == 0);
    int tier;
    if      (mfma_ok && ws_size >= hpb_off + hpb_b) tier = 1;  // bf16 hp shadow
    else if (mfma_ok && ws_size >= hcb_off + hcb_b) tier = 2;  // hc shadow only
    else if (ws_size >= hcb_off + agg_b)            tier = 3;  // round-2 style
    else                                            tier = 4;  // atomic fallback

    hipMemcpyAsync(h_p, paths,    (size_t)P * FD * sizeof(float),
                   hipMemcpyDeviceToDevice, stream);
    hipMemcpyAsync(h_c, channels, (size_t)C * FD * sizeof(float),
                   hipMemcpyDeviceToDevice, stream);

    dim3 pb(256), pg((P + 255) / 256);
    dim3 cb(256), cg((C + 255) / 256);

    if (tier <= 3) {
        // atomic-free CSR build
        hist_kernel<<<NB, 256, 0, stream>>>(p2c, subcnt, E, C);
        colprefix_kernel<<<cg, cb, 0, stream>>>(subcnt, counts, C);
        scan_offsets_kernel<<<1, 1024, 0, stream>>>(counts, offsets, C);
        scatter_kernel<<<NB, 256, 0, stream>>>(p2c, offsets, elist, E, C);
    }

    if (tier == 1 || tier == 2) {
        int n8 = C * FD / 8;
        hc_init_kernel<<<(n8 + 255) / 256, 256, 0, stream>>>(channels, hcb, n8);
        dim3 mg(P / 64), mb(256);
        for (int it = 0; it < NITER; it++) {
            if (tier == 1) {
                path_fused_kernel<1><<<mg, mb, 0, stream>>>(h_p, p2c, hcb,
                                                            Wih1, Whh1, bih1, bhh1, hpb);
                gather_gru2_kernel<1, 1><<<cg, cb, 0, stream>>>(hpb, offsets, elist, h_c,
                                                                Wih2, Whh2, bih2, bhh2, hcb, C);
            } else {
                path_fused_kernel<0><<<mg, mb, 0, stream>>>(h_p, p2c, hcb,
                                                            Wih1, Whh1, bih1, bhh1, nullptr);
                gather_gru2_kernel<0, 1><<<cg, cb, 0, stream>>>(h_p, offsets, elist, h_c,
                                                                Wih2, Whh2, bih2, bhh2, hcb, C);
            }
        }
    } else if (tier == 3) {
        dim3 gb(256), gg((C * 32 + 255) / 256);
        for (int it = 0; it < NITER; it++) {
            path_update_kernel<<<pg, pb, 0, stream>>>(h_c, h_p, p2c,
                                                      Wih1, Whh1, bih1, bhh1, P);
            gather_agg_kernel<<<gg, gb, 0, stream>>>(h_p, offsets, elist, agg, C);
            channel_update_kernel<<<cg, cb, 0, stream>>>(agg, h_c,
                                                         Wih2, Whh2, bih2, bhh2, C);
        }
    } else {
        float* agg0 = (float*)d_ws;
        for (int it = 0; it < NITER; it++) {
            path_update_kernel<<<pg, pb, 0, stream>>>(h_c, h_p, p2c,
                                                      Wih1, Whh1, bih1, bhh1, P);
            hipMemsetAsync(agg0, 0, agg_b, stream);
            scatter_agg_atomic_kernel<<<pg, pb, 0, stream>>>(h_p, p2c, agg0, P);
            channel_update_kernel<<<cg, cb, 0, stream>>>(agg0, h_c,
                                                         Wih2, Whh2, bih2, bhh2, C);
        }
    }
}

// Round 6
// 1269.649 us; speedup vs baseline: 3.2677x; 3.2677x over previous
//
#include <hip/hip_runtime.h>

#define FD 32
#define KNB 8
#define NITER 5
#define NCH 256   // edge chunks for the binning passes

typedef __bf16 bf16x8 __attribute__((ext_vector_type(8)));
typedef float  f32x4  __attribute__((ext_vector_type(4)));

__device__ __forceinline__ float sigmoidf_(float a) {
    return 1.0f / (1.0f + __expf(-a));
}
__device__ __forceinline__ float tanhf_(float a) {
    return 1.0f - 2.0f / (__expf(2.0f * a) + 1.0f);
}

// ---------------- atomic-free CSR build (two-level counting sort) -----------
// All passes are wide (>=196 blocks); no global atomics anywhere.
// bucket r = channel >> 8  (256 channels per bucket, NR = ceil(C/256) buckets)

// pass 1a: per-chunk bucket histogram. cnt1[chunk][NR]
__global__ __launch_bounds__(256) void bincount_kernel(
    const int* __restrict__ p2c, int* __restrict__ cnt1, int E, int NR)
{
    __shared__ int lds[256];
    int b = blockIdx.x;
    int per = (E + NCH - 1) / NCH;
    int s0 = b * per, s1 = s0 + per; if (s1 > E) s1 = E;
    int t = threadIdx.x;
    if (t < NR) lds[t] = 0;
    __syncthreads();
    for (int e = s0 + t; e < s1; e += 256)
        atomicAdd(&lds[p2c[e] >> 8], 1);
    __syncthreads();
    if (t < NR) cnt1[(size_t)b * NR + t] = lds[t];
}

// pass 1b: single block. cnt1[b][r] -> start offsets (in place); bstart[r].
__global__ __launch_bounds__(256) void scan_chunks_kernel(
    int* __restrict__ cnt1, int* __restrict__ bstart, int NR, int E)
{
    __shared__ int tt[256];
    int t = threadIdx.x;
    int tot = 0;
    if (t < NR)
        for (int b = 0; b < NCH; b++) tot += cnt1[(size_t)b * NR + t];
    tt[t] = (t < NR) ? tot : 0;
    __syncthreads();
    for (int d = 1; d < 256; d <<= 1) {
        int v = (t >= d) ? tt[t - d] : 0;
        __syncthreads();
        tt[t] += v;
        __syncthreads();
    }
    if (t < NR) {
        int run = (t == 0) ? 0 : tt[t - 1];
        bstart[t] = run;
        for (int b = 0; b < NCH; b++) {
            int v = cnt1[(size_t)b * NR + t];
            cnt1[(size_t)b * NR + t] = run;
            run += v;
        }
        if (t == NR - 1) bstart[NR] = E;
    }
}

// pass 1c: bin edges into bucket-partitioned ebuf. Each (chunk,bucket) region
// is written by exactly one block -> dense private appends.
__global__ __launch_bounds__(256) void binfill_kernel(
    const int* __restrict__ p2c, const int* __restrict__ cnt1,
    int2* __restrict__ ebuf, int E, int NR)
{
    __shared__ int cur[256];
    int b = blockIdx.x;
    int per = (E + NCH - 1) / NCH;
    int s0 = b * per, s1 = s0 + per; if (s1 > E) s1 = E;
    int t = threadIdx.x;
    if (t < NR) cur[t] = cnt1[(size_t)b * NR + t];
    __syncthreads();
    for (int e = s0 + t; e < s1; e += 256) {
        int ch = p2c[e];
        int slot = atomicAdd(&cur[ch >> 8], 1);
        ebuf[slot] = make_int2(e >> 3, ch);   // (path id, channel); KNB == 8
    }
}

// pass 2a: per-bucket channel histogram -> counts (coalesced writes).
__global__ __launch_bounds__(256) void buckcount_kernel(
    const int2* __restrict__ ebuf, const int* __restrict__ bstart,
    int* __restrict__ counts, int C)
{
    __shared__ int h[256];
    int r = blockIdx.x;
    int t = threadIdx.x;
    h[t] = 0;
    __syncthreads();
    int s0 = bstart[r], s1 = bstart[r + 1];
    for (int i = s0 + t; i < s1; i += 256)
        atomicAdd(&h[ebuf[i].y & 255], 1);
    __syncthreads();
    int c = (r << 8) + t;
    if (c < C) counts[c] = h[t];
}

// pass 2b: single block, 1024 threads: exclusive scan counts -> offsets
__global__ __launch_bounds__(1024) void scan_offsets_kernel(
    const int* __restrict__ counts, int* __restrict__ offsets, int C)
{
    __shared__ int part[1024];
    int t = threadIdx.x;
    int chunk = (C + 1023) >> 10;
    int base = t * chunk;
    int end = base + chunk; if (end > C) end = C;
    int s = 0;
    for (int i = base; i < end; i++) s += counts[i];
    part[t] = s;
    __syncthreads();
    for (int d = 1; d < 1024; d <<= 1) {
        int v = (t >= d) ? part[t - d] : 0;
        __syncthreads();
        part[t] += v;
        __syncthreads();
    }
    int run = (t == 0) ? 0 : part[t - 1];
    for (int i = base; i < end; i++) {
        offsets[i] = run;
        run += counts[i];
    }
    if (t == 1023) offsets[C] = part[1023];
}

// pass 2c: per-bucket rank via LDS cursors; elist writes land in the bucket's
// contiguous region (~32 KB) -> no cross-XCD line sharing.
__global__ __launch_bounds__(256) void buckfill_kernel(
    const int2* __restrict__ ebuf, const int* __restrict__ bstart,
    const int* __restrict__ offsets, int* __restrict__ elist, int C)
{
    __shared__ int cur[256];
    int r = blockIdx.x;
    int t = threadIdx.x;
    int c = (r << 8) + t;
    cur[t] = (c < C) ? offsets[c] : 0;
    __syncthreads();
    int s0 = bstart[r], s1 = bstart[r + 1];
    for (int i = s0 + t; i < s1; i += 256) {
        int2 v = ebuf[i];
        int slot = atomicAdd(&cur[v.y & 255], 1);
        elist[slot] = v.x;
    }
}

// ---------------- init: h_c copy + bf16 shadow in one pass ------------------

__global__ __launch_bounds__(256) void hc_init_kernel(
    const float* __restrict__ src, float* __restrict__ h_c,
    __bf16* __restrict__ dst, int n8)
{
    int i = blockIdx.x * blockDim.x + threadIdx.x;
    if (i >= n8) return;
    const float4* s = (const float4*)(src + (size_t)i * 8);
    float4 u = s[0], v = s[1];
    float4* d = (float4*)(h_c + (size_t)i * 8);
    d[0] = u; d[1] = v;
    bf16x8 o;
    o[0]=(__bf16)u.x; o[1]=(__bf16)u.y; o[2]=(__bf16)u.z; o[3]=(__bf16)u.w;
    o[4]=(__bf16)v.x; o[5]=(__bf16)v.y; o[6]=(__bf16)v.z; o[7]=(__bf16)v.w;
    ((bf16x8*)dst)[i] = o;
}

// ---------------- fused path kernel (x-side + h-side MFMA) ------------------
__global__ __launch_bounds__(256) void path_fused_kernel(
    float* __restrict__ h_p, const int* __restrict__ p2c,
    const __bf16* __restrict__ hcb,
    const float* __restrict__ Wih, const float* __restrict__ Whh,
    const float* __restrict__ bih, const float* __restrict__ bhh,
    __bf16* __restrict__ hpb)
{
    __shared__ float hl[64 * 36];
    const int tid  = threadIdx.x;
    const int wid  = tid >> 6;
    const int lane = tid & 63;
    const int c    = lane & 15;
    const int kg   = lane >> 4;
    const int blk0 = blockIdx.x * 64;

    {
        int r  = tid >> 2;
        int c0 = (tid & 3) * 8;
        const float4* src = (const float4*)(h_p + ((size_t)(blk0 + r)) * FD + c0);
        float4 a = src[0], b = src[1];
        float* d = &hl[r * 36 + c0];
        d[0]=a.x; d[1]=a.y; d[2]=a.z; d[3]=a.w;
        d[4]=b.x; d[5]=b.y; d[6]=b.z; d[7]=b.w;
    }

    bf16x8 Bx[6], Bh[6];
    #pragma unroll
    for (int t = 0; t < 6; t++) {
        const float* wi = Wih + (size_t)(16*t + c) * FD + 8*kg;
        const float* wh = Whh + (size_t)(16*t + c) * FD + 8*kg;
        #pragma unroll
        for (int j = 0; j < 8; j++) {
            Bx[t][j] = (__bf16)wi[j];
            Bh[t][j] = (__bf16)wh[j];
        }
    }
    float bsum[4], bin[2], bhn[2];
    #pragma unroll
    for (int t = 0; t < 4; t++) bsum[t] = bih[16*t + c] + bhh[16*t + c];
    #pragma unroll
    for (int fi = 0; fi < 2; fi++) {
        bin[fi] = bih[64 + 16*fi + c];
        bhn[fi] = bhh[64 + 16*fi + c];
    }

    const int pA = blk0 + wid*16 + c;
    const int4* pp = (const int4*)(p2c + (size_t)pA * KNB);
    int4 ia = pp[0], ib = pp[1];
    int idxA[KNB] = {ia.x, ia.y, ia.z, ia.w, ib.x, ib.y, ib.z, ib.w};
    bf16x8 Ax[KNB];
    #pragma unroll
    for (int k = 0; k < KNB; k++)
        Ax[k] = *(const bf16x8*)(hcb + (size_t)idxA[k] * FD + 8*kg);

    const int rowA = wid*16 + c;
    #pragma unroll
    for (int k = 0; k < KNB; k++) {
        bf16x8 Ah;
        const float* ar = &hl[rowA * 36 + 8*kg];
        #pragma unroll
        for (int j = 0; j < 8; j++) Ah[j] = (__bf16)ar[j];

        const f32x4 z4 = {0.f, 0.f, 0.f, 0.f};
        f32x4 arz[4], xn[2], hn[2];
        #pragma unroll
        for (int t = 0; t < 4; t++) {
            arz[t] = __builtin_amdgcn_mfma_f32_16x16x32_bf16(Ax[k], Bx[t], z4, 0, 0, 0);
            arz[t] = __builtin_amdgcn_mfma_f32_16x16x32_bf16(Ah,    Bh[t], arz[t], 0, 0, 0);
        }
        #pragma unroll
        for (int fi = 0; fi < 2; fi++) {
            xn[fi] = __builtin_amdgcn_mfma_f32_16x16x32_bf16(Ax[k], Bx[4+fi], z4, 0, 0, 0);
            hn[fi] = __builtin_amdgcn_mfma_f32_16x16x32_bf16(Ah,    Bh[4+fi], z4, 0, 0, 0);
        }

        #pragma unroll
        for (int q = 0; q < 4; q++) {
            float* hrow = &hl[(wid*16 + 4*kg + q) * 36];
            #pragma unroll
            for (int fi = 0; fi < 2; fi++) {
                float r = sigmoidf_(arz[fi][q]   + bsum[fi]);
                float z = sigmoidf_(arz[2+fi][q] + bsum[2+fi]);
                float n = tanhf_(xn[fi][q] + bin[fi] + r * (hn[fi][q] + bhn[fi]));
                float ho = hrow[c + 16*fi];
                hrow[c + 16*fi] = (1.0f - z) * n + z * ho;
            }
        }
    }

    {
        int r  = tid >> 2;
        int c0 = (tid & 3) * 8;
        const float* s = &hl[r * 36 + c0];
        float4 a, b;
        a.x=s[0]; a.y=s[1]; a.z=s[2]; a.w=s[3];
        b.x=s[4]; b.y=s[5]; b.z=s[6]; b.w=s[7];
        float4* dst = (float4*)(h_p + ((size_t)(blk0 + r)) * FD + c0);
        dst[0] = a; dst[1] = b;
        bf16x8 o;
        o[0]=(__bf16)a.x; o[1]=(__bf16)a.y; o[2]=(__bf16)a.z; o[3]=(__bf16)a.w;
        o[4]=(__bf16)b.x; o[5]=(__bf16)b.y; o[6]=(__bf16)b.z; o[7]=(__bf16)b.w;
        *(bf16x8*)(hpb + ((size_t)(blk0 + r)) * FD + c0) = o;
    }
}

// ---------------- fused gather + GRU2 (1 thread / channel) ------------------
__global__ __launch_bounds__(256) void gather_gru2_kernel(
    const __bf16* __restrict__ hpb, const int* __restrict__ offsets,
    const int* __restrict__ elist, float* __restrict__ h_c,
    const float* __restrict__ Wih, const float* __restrict__ Whh,
    const float* __restrict__ bih, const float* __restrict__ bhh,
    __bf16* __restrict__ hcb, int C)
{
    int c = blockIdx.x * blockDim.x + threadIdx.x;
    if (c >= C) return;
    int s = offsets[c], e = offsets[c + 1];

    float x[FD];
    #pragma unroll
    for (int i = 0; i < FD; i++) x[i] = 0.f;

    #pragma unroll 2
    for (int i = s; i < e; i++) {
        const bf16x8* r = (const bf16x8*)(hpb + (size_t)elist[i] * FD);
        bf16x8 v0 = r[0], v1 = r[1], v2 = r[2], v3 = r[3];
        #pragma unroll
        for (int j = 0; j < 8; j++) {
            x[j]      += (float)v0[j];
            x[8 + j]  += (float)v1[j];
            x[16 + j] += (float)v2[j];
            x[24 + j] += (float)v3[j];
        }
    }

    float h[FD];
    const float4* hr = (const float4*)(h_c + (size_t)c * FD);
    #pragma unroll
    for (int i = 0; i < FD / 4; i++) {
        float4 v = hr[i];
        h[4*i] = v.x; h[4*i+1] = v.y; h[4*i+2] = v.z; h[4*i+3] = v.w;
    }

    float hn[FD];
    #pragma unroll 4
    for (int j = 0; j < FD; j++) {
        float air = bih[j],        ahr = bhh[j];
        float aiz = bih[FD + j],   ahz = bhh[FD + j];
        float ain = bih[2*FD + j], ahn = bhh[2*FD + j];
        #pragma unroll
        for (int i = 0; i < FD; i++) {
            air = fmaf(Wih[j*FD + i],          x[i], air);
            ahr = fmaf(Whh[j*FD + i],          h[i], ahr);
            aiz = fmaf(Wih[(FD + j)*FD + i],   x[i], aiz);
            ahz = fmaf(Whh[(FD + j)*FD + i],   h[i], ahz);
            ain = fmaf(Wih[(2*FD + j)*FD + i], x[i], ain);
            ahn = fmaf(Whh[(2*FD + j)*FD + i], h[i], ahn);
        }
        float r = sigmoidf_(air + ahr);
        float z = sigmoidf_(aiz + ahz);
        float n = tanhf_(ain + r * ahn);
        hn[j] = (1.0f - z) * n + z * h[j];
    }

    float4* hw = (float4*)(h_c + (size_t)c * FD);
    #pragma unroll
    for (int i = 0; i < FD / 4; i++) {
        float4 v;
        v.x = hn[4*i]; v.y = hn[4*i+1]; v.z = hn[4*i+2]; v.w = hn[4*i+3];
        hw[i] = v;
    }
    #pragma unroll
    for (int g = 0; g < 4; g++) {
        bf16x8 o;
        #pragma unroll
        for (int j = 0; j < 8; j++) o[j] = (__bf16)hn[8*g + j];
        *(bf16x8*)(hcb + (size_t)c * FD + 8*g) = o;
    }
}

// ---------------- tier-4 fallback kernels (atomic path) ---------------------

__global__ __launch_bounds__(256) void path_update_kernel(
    const float* __restrict__ h_c, float* __restrict__ h_p,
    const int* __restrict__ p2c,
    const float* __restrict__ Wih, const float* __restrict__ Whh,
    const float* __restrict__ bih, const float* __restrict__ bhh, int P)
{
    int p = blockIdx.x * blockDim.x + threadIdx.x;
    if (p >= P) return;

    float h[FD];
    const float4* hp4 = (const float4*)(h_p + (size_t)p * FD);
    #pragma unroll
    for (int i = 0; i < FD / 4; i++) {
        float4 v = hp4[i];
        h[4*i] = v.x; h[4*i+1] = v.y; h[4*i+2] = v.z; h[4*i+3] = v.w;
    }

    int idx[KNB];
    const int4* pi = (const int4*)(p2c + (size_t)p * KNB);
    int4 i0 = pi[0], i1 = pi[1];
    idx[0]=i0.x; idx[1]=i0.y; idx[2]=i0.z; idx[3]=i0.w;
    idx[4]=i1.x; idx[5]=i1.y; idx[6]=i1.z; idx[7]=i1.w;

    for (int k = 0; k < KNB; k++) {
        float x[FD];
        const float4* xr = (const float4*)(h_c + (size_t)idx[k] * FD);
        #pragma unroll
        for (int i = 0; i < FD / 4; i++) {
            float4 v = xr[i];
            x[4*i] = v.x; x[4*i+1] = v.y; x[4*i+2] = v.z; x[4*i+3] = v.w;
        }

        float hn[FD];
        #pragma unroll 4
        for (int j = 0; j < FD; j++) {
            float air = bih[j],        ahr = bhh[j];
            float aiz = bih[FD + j],   ahz = bhh[FD + j];
            float ain = bih[2*FD + j], ahn = bhh[2*FD + j];
            #pragma unroll
            for (int i = 0; i < FD; i++) {
                air = fmaf(Wih[j*FD + i],          x[i], air);
                ahr = fmaf(Whh[j*FD + i],          h[i], ahr);
                aiz = fmaf(Wih[(FD + j)*FD + i],   x[i], aiz);
                ahz = fmaf(Whh[(FD + j)*FD + i],   h[i], ahz);
                ain = fmaf(Wih[(2*FD + j)*FD + i], x[i], ain);
                ahn = fmaf(Whh[(2*FD + j)*FD + i], h[i], ahn);
            }
            float r = sigmoidf_(air + ahr);
            float z = sigmoidf_(aiz + ahz);
            float n = tanhf_(ain + r * ahn);
            hn[j] = (1.0f - z) * n + z * h[j];
        }
        #pragma unroll
        for (int j = 0; j < FD; j++) h[j] = hn[j];
    }

    float4* hpw = (float4*)(h_p + (size_t)p * FD);
    #pragma unroll
    for (int i = 0; i < FD / 4; i++) {
        float4 v;
        v.x = h[4*i]; v.y = h[4*i+1]; v.z = h[4*i+2]; v.w = h[4*i+3];
        hpw[i] = v;
    }
}

__global__ __launch_bounds__(256) void scatter_agg_atomic_kernel(
    const float* __restrict__ h_p, const int* __restrict__ p2c,
    float* __restrict__ agg, int P)
{
    int p = blockIdx.x * blockDim.x + threadIdx.x;
    if (p >= P) return;
    const float* hr = h_p + (size_t)p * FD;
    #pragma unroll
    for (int k = 0; k < KNB; k++) {
        int c = p2c[(size_t)p * KNB + k];
        float* ar = agg + (size_t)c * FD;
        #pragma unroll
        for (int i = 0; i < FD; i++) atomicAdd(ar + i, hr[i]);
    }
}

__global__ __launch_bounds__(256) void channel_update_kernel(
    const float* __restrict__ agg, float* __restrict__ h_c,
    const float* __restrict__ Wih, const float* __restrict__ Whh,
    const float* __restrict__ bih, const float* __restrict__ bhh, int C)
{
    int c = blockIdx.x * blockDim.x + threadIdx.x;
    if (c >= C) return;

    float h[FD], x[FD];
    const float4* hr = (const float4*)(h_c + (size_t)c * FD);
    const float4* xr = (const float4*)(agg + (size_t)c * FD);
    #pragma unroll
    for (int i = 0; i < FD / 4; i++) {
        float4 v = hr[i];
        h[4*i] = v.x; h[4*i+1] = v.y; h[4*i+2] = v.z; h[4*i+3] = v.w;
        float4 w = xr[i];
        x[4*i] = w.x; x[4*i+1] = w.y; x[4*i+2] = w.z; x[4*i+3] = w.w;
    }

    float hn[FD];
    #pragma unroll 4
    for (int j = 0; j < FD; j++) {
        float air = bih[j],        ahr = bhh[j];
        float aiz = bih[FD + j],   ahz = bhh[FD + j];
        float ain = bih[2*FD + j], ahn = bhh[2*FD + j];
        #pragma unroll
        for (int i = 0; i < FD; i++) {
            air = fmaf(Wih[j*FD + i],          x[i], air);
            ahr = fmaf(Whh[j*FD + i],          h[i], ahr);
            aiz = fmaf(Wih[(FD + j)*FD + i],   x[i], aiz);
            ahz = fmaf(Whh[(FD + j)*FD + i],   h[i], ahz);
            ain = fmaf(Wih[(2*FD + j)*FD + i], x[i], ain);
            ahn = fmaf(Whh[(2*FD + j)*FD + i], h[i], ahn);
        }
        float r = sigmoidf_(air + ahr);
        float z = sigmoidf_(aiz + ahz);
        float n = tanhf_(ain + r * ahn);
        hn[j] = (1.0f - z) * n + z * h[j];
    }

    float4* hw = (float4*)(h_c + (size_t)c * FD);
    #pragma unroll
    for (int i = 0; i < FD / 4; i++) {
        float4 v;
        v.x = hn[4*i]; v.y = hn[4*i+1]; v.z = hn[4*i+2]; v.w = hn[4*i+3];
        hw[i] = v;
    }
}

extern "C" void kernel_launch(void* const* d_in, const int* in_sizes, int n_in,
                              void* d_out, int out_size, void* d_ws, size_t ws_size,
                              hipStream_t stream) {
    const float* paths    = (const float*)d_in[0];
    const float* channels = (const float*)d_in[1];
    const int*   p2c      = (const int*)d_in[2];
    const float* Wih1 = (const float*)d_in[3];
    const float* Whh1 = (const float*)d_in[4];
    const float* bih1 = (const float*)d_in[5];
    const float* bhh1 = (const float*)d_in[6];
    const float* Wih2 = (const float*)d_in[7];
    const float* Whh2 = (const float*)d_in[8];
    const float* bih2 = (const float*)d_in[9];
    const float* bhh2 = (const float*)d_in[10];

    const int P = in_sizes[0] / FD;     // 200000
    const int C = in_sizes[1] / FD;     // 50000
    const int E = P * KNB;              // 1.6M edges
    const int NR = (C + 255) >> 8;      // 196 buckets

    float* h_p = (float*)d_out;                  // [P*FD]
    float* h_c = h_p + (size_t)P * FD;           // [C*FD]

    // ws layout: counts[C] | offsets[C+1] | bstart[NR+1] | elist[E] | hcb |
    //            UNION{ ebuf[E](int2) + cnt1[NCH*NR]  |  hpb[P*FD](bf16) }
    char* ws = (char*)d_ws;
    size_t cnt_off = 0;
    size_t ofs_off = (cnt_off + (size_t)C * 4 + 255) & ~(size_t)255;
    size_t bst_off = (ofs_off + (size_t)(C + 1) * 4 + 255) & ~(size_t)255;
    size_t el_off  = (bst_off + (size_t)(NR + 1) * 4 + 255) & ~(size_t)255;
    size_t hcb_off = (el_off + (size_t)E * 4 + 255) & ~(size_t)255;
    size_t uni_off = (hcb_off + (size_t)C * FD * 2 + 255) & ~(size_t)255;
    size_t ebuf_b  = (size_t)E * 8;
    size_t cnt1_b  = (size_t)NCH * NR * 4;
    size_t hpb_b   = (size_t)P * FD * 2;
    size_t uni_b   = (ebuf_b + cnt1_b > hpb_b) ? (ebuf_b + cnt1_b) : hpb_b;

    int*    counts  = (int*)(ws + cnt_off);
    int*    offsets = (int*)(ws + ofs_off);
    int*    bstart  = (int*)(ws + bst_off);
    int*    elist   = (int*)(ws + el_off);
    __bf16* hcb     = (__bf16*)(ws + hcb_off);
    int2*   ebuf    = (int2*)(ws + uni_off);
    int*    cnt1    = (int*)(ws + uni_off + ebuf_b);
    __bf16* hpb     = (__bf16*)(ws + uni_off);   // time-disjoint with ebuf/cnt1

    const bool mfma_ok = (P % 64 == 0) && (C <= 65536);
    const bool tier1 = mfma_ok && (ws_size >= uni_off + uni_b);

    dim3 pb(256), pg((P + 255) / 256);
    dim3 cb(256), cg((C + 255) / 256);

    if (tier1) {
        hipMemcpyAsync(h_p, paths, (size_t)P * FD * sizeof(float),
                       hipMemcpyDeviceToDevice, stream);
        int n8 = C * FD / 8;
        hc_init_kernel<<<(n8 + 255) / 256, 256, 0, stream>>>(channels, h_c, hcb, n8);

        // atomic-free CSR build (two-level counting sort)
        bincount_kernel<<<NCH, 256, 0, stream>>>(p2c, cnt1, E, NR);
        scan_chunks_kernel<<<1, 256, 0, stream>>>(cnt1, bstart, NR, E);
        binfill_kernel<<<NCH, 256, 0, stream>>>(p2c, cnt1, ebuf, E, NR);
        buckcount_kernel<<<NR, 256, 0, stream>>>(ebuf, bstart, counts, C);
        scan_offsets_kernel<<<1, 1024, 0, stream>>>(counts, offsets, C);
        buckfill_kernel<<<NR, 256, 0, stream>>>(ebuf, bstart, offsets, elist, C);

        dim3 mg(P / 64), mb(256);
        for (int it = 0; it < NITER; it++) {
            path_fused_kernel<<<mg, mb, 0, stream>>>(h_p, p2c, hcb,
                                                     Wih1, Whh1, bih1, bhh1, hpb);
            gather_gru2_kernel<<<cg, cb, 0, stream>>>(hpb, offsets, elist, h_c,
                                                      Wih2, Whh2, bih2, bhh2, hcb, C);
        }
    } else {
        // fallback: atomic scatter path (needs only agg at ws base)
        float* agg0 = (float*)d_ws;
        size_t agg_b = (size_t)C * FD * sizeof(float);
        hipMemcpyAsync(h_p, paths, (size_t)P * FD * sizeof(float),
                       hipMemcpyDeviceToDevice, stream);
        hipMemcpyAsync(h_c, channels, (size_t)C * FD * sizeof(float),
                       hipMemcpyDeviceToDevice, stream);
        for (int it = 0; it < NITER; it++) {
            path_update_kernel<<<pg, pb, 0, stream>>>(h_c, h_p, p2c,
                                                      Wih1, Whh1, bih1, bhh1, P);
            hipMemsetAsync(agg0, 0, agg_b, stream);
            scatter_agg_atomic_kernel<<<pg, pb, 0, stream>>>(h_p, p2c, agg0, P);
            channel_update_kernel<<<cg, cb, 0, stream>>>(agg0, h_c,
                                                         Wih2, Whh2, bih2, bhh2, C);
        }
    }
}

// Round 7
// 1108.086 us; speedup vs baseline: 3.7441x; 1.1458x over previous
//
#include <hip/hip_runtime.h>

#define FD 32
#define KNB 8
#define NITER 5
#define NCH 256   // edge chunks for the binning passes

typedef __bf16 bf16x8 __attribute__((ext_vector_type(8)));
typedef float  f32x4  __attribute__((ext_vector_type(4)));

// Fast HW transcendentals: v_rcp_f32 / v_exp_f32 (~1 ulp on 22 bits) instead
// of the IEEE div expansion (div_scale/div_fmas/div_fixup ~9 instr per divide).
__device__ __forceinline__ float frcp_(float a) { return __builtin_amdgcn_rcpf(a); }
__device__ __forceinline__ float fexp2_(float a) { return __builtin_amdgcn_exp2f(a); }
__device__ __forceinline__ float sigmoidf_(float a) {
    return frcp_(1.0f + fexp2_(a * -1.44269504f));
}
__device__ __forceinline__ float tanhf_(float a) {
    return 1.0f - 2.0f * frcp_(fexp2_(a * 2.88539009f) + 1.0f);
}

// ---------------- atomic-free CSR build (two-level counting sort) -----------
// bucket r = channel >> 8; NR = ceil(C/256) buckets. ~17 us total (round 6).

__global__ __launch_bounds__(256) void bincount_kernel(
    const int* __restrict__ p2c, int* __restrict__ cnt1, int E, int NR)
{
    __shared__ int lds[256];
    int b = blockIdx.x;
    int per = (E + NCH - 1) / NCH;
    int s0 = b * per, s1 = s0 + per; if (s1 > E) s1 = E;
    int t = threadIdx.x;
    if (t < NR) lds[t] = 0;
    __syncthreads();
    for (int e = s0 + t; e < s1; e += 256)
        atomicAdd(&lds[p2c[e] >> 8], 1);
    __syncthreads();
    if (t < NR) cnt1[(size_t)b * NR + t] = lds[t];
}

__global__ __launch_bounds__(256) void scan_chunks_kernel(
    int* __restrict__ cnt1, int* __restrict__ bstart, int NR, int E)
{
    __shared__ int tt[256];
    int t = threadIdx.x;
    int tot = 0;
    if (t < NR)
        for (int b = 0; b < NCH; b++) tot += cnt1[(size_t)b * NR + t];
    tt[t] = (t < NR) ? tot : 0;
    __syncthreads();
    for (int d = 1; d < 256; d <<= 1) {
        int v = (t >= d) ? tt[t - d] : 0;
        __syncthreads();
        tt[t] += v;
        __syncthreads();
    }
    if (t < NR) {
        int run = (t == 0) ? 0 : tt[t - 1];
        bstart[t] = run;
        for (int b = 0; b < NCH; b++) {
            int v = cnt1[(size_t)b * NR + t];
            cnt1[(size_t)b * NR + t] = run;
            run += v;
        }
        if (t == NR - 1) bstart[NR] = E;
    }
}

__global__ __launch_bounds__(256) void binfill_kernel(
    const int* __restrict__ p2c, const int* __restrict__ cnt1,
    int2* __restrict__ ebuf, int E, int NR)
{
    __shared__ int cur[256];
    int b = blockIdx.x;
    int per = (E + NCH - 1) / NCH;
    int s0 = b * per, s1 = s0 + per; if (s1 > E) s1 = E;
    int t = threadIdx.x;
    if (t < NR) cur[t] = cnt1[(size_t)b * NR + t];
    __syncthreads();
    for (int e = s0 + t; e < s1; e += 256) {
        int ch = p2c[e];
        int slot = atomicAdd(&cur[ch >> 8], 1);
        ebuf[slot] = make_int2(e >> 3, ch);   // (path id, channel); KNB == 8
    }
}

__global__ __launch_bounds__(256) void buckcount_kernel(
    const int2* __restrict__ ebuf, const int* __restrict__ bstart,
    int* __restrict__ counts, int C)
{
    __shared__ int h[256];
    int r = blockIdx.x;
    int t = threadIdx.x;
    h[t] = 0;
    __syncthreads();
    int s0 = bstart[r], s1 = bstart[r + 1];
    for (int i = s0 + t; i < s1; i += 256)
        atomicAdd(&h[ebuf[i].y & 255], 1);
    __syncthreads();
    int c = (r << 8) + t;
    if (c < C) counts[c] = h[t];
}

__global__ __launch_bounds__(1024) void scan_offsets_kernel(
    const int* __restrict__ counts, int* __restrict__ offsets, int C)
{
    __shared__ int part[1024];
    int t = threadIdx.x;
    int chunk = (C + 1023) >> 10;
    int base = t * chunk;
    int end = base + chunk; if (end > C) end = C;
    int s = 0;
    for (int i = base; i < end; i++) s += counts[i];
    part[t] = s;
    __syncthreads();
    for (int d = 1; d < 1024; d <<= 1) {
        int v = (t >= d) ? part[t - d] : 0;
        __syncthreads();
        part[t] += v;
        __syncthreads();
    }
    int run = (t == 0) ? 0 : part[t - 1];
    for (int i = base; i < end; i++) {
        offsets[i] = run;
        run += counts[i];
    }
    if (t == 1023) offsets[C] = part[1023];
}

__global__ __launch_bounds__(256) void buckfill_kernel(
    const int2* __restrict__ ebuf, const int* __restrict__ bstart,
    const int* __restrict__ offsets, int* __restrict__ elist, int C)
{
    __shared__ int cur[256];
    int r = blockIdx.x;
    int t = threadIdx.x;
    int c = (r << 8) + t;
    cur[t] = (c < C) ? offsets[c] : 0;
    __syncthreads();
    int s0 = bstart[r], s1 = bstart[r + 1];
    for (int i = s0 + t; i < s1; i += 256) {
        int2 v = ebuf[i];
        int slot = atomicAdd(&cur[v.y & 255], 1);
        elist[slot] = v.x;
    }
}

// ---------------- init: h_c copy + bf16 shadow in one pass ------------------

__global__ __launch_bounds__(256) void hc_init_kernel(
    const float* __restrict__ src, float* __restrict__ h_c,
    __bf16* __restrict__ dst, int n8)
{
    int i = blockIdx.x * blockDim.x + threadIdx.x;
    if (i >= n8) return;
    const float4* s = (const float4*)(src + (size_t)i * 8);
    float4 u = s[0], v = s[1];
    float4* d = (float4*)(h_c + (size_t)i * 8);
    d[0] = u; d[1] = v;
    bf16x8 o;
    o[0]=(__bf16)u.x; o[1]=(__bf16)u.y; o[2]=(__bf16)u.z; o[3]=(__bf16)u.w;
    o[4]=(__bf16)v.x; o[5]=(__bf16)v.y; o[6]=(__bf16)v.z; o[7]=(__bf16)v.w;
    ((bf16x8*)dst)[i] = o;
}

// ---------------- fused path kernel v2 --------------------------------------
// 4 waves/block, 16 paths/wave, no barriers (hl is wave-private by row range).
// h state: f32 in REGISTERS (D-layout: lane (c,kg) holds rows 4kg+q, cols
// c,c+16) + bf16 copy in LDS (A-layout source). Per step: 1 ds_read_b128
// (A-frag, already bf16), 12 MFMA (bias-seeded accumulators), gate math with
// HW rcp/exp2, 8 cvt + 8 ds_write_b16.
#define HLP 40   // bf16 row pitch: 80 B, 16B-aligned, 2-way-max bank aliasing
__global__ __launch_bounds__(256) void path_fused_kernel(
    float* __restrict__ h_p, const int* __restrict__ p2c,
    const __bf16* __restrict__ hcb,
    const float* __restrict__ Wih, const float* __restrict__ Whh,
    const float* __restrict__ bih, const float* __restrict__ bhh,
    __bf16* __restrict__ hpb)
{
    __shared__ __bf16 hl[64][HLP];
    const int tid  = threadIdx.x;
    const int wid  = tid >> 6;
    const int lane = tid & 63;
    const int c    = lane & 15;
    const int kg   = lane >> 4;
    const int blk0 = blockIdx.x * 64;

    // B fragments: lane holds W[16t+c][8kg..8kg+7] (bf16)
    bf16x8 Bx[6], Bh[6];
    #pragma unroll
    for (int t = 0; t < 6; t++) {
        const float* wi = Wih + (size_t)(16*t + c) * FD + 8*kg;
        const float* wh = Whh + (size_t)(16*t + c) * FD + 8*kg;
        #pragma unroll
        for (int j = 0; j < 8; j++) {
            Bx[t][j] = (__bf16)wi[j];
            Bh[t][j] = (__bf16)wh[j];
        }
    }
    // bias-seeded accumulator C-ins (bias depends on output col = c only)
    f32x4 cin_rz[4], cin_xn[2], cin_hn[2];
    #pragma unroll
    for (int t = 0; t < 4; t++) {
        float b = bih[16*t + c] + bhh[16*t + c];
        cin_rz[t] = (f32x4){b, b, b, b};
    }
    #pragma unroll
    for (int fi = 0; fi < 2; fi++) {
        float bi = bih[64 + 16*fi + c];
        float bh = bhh[64 + 16*fi + c];
        cin_xn[fi] = (f32x4){bi, bi, bi, bi};
        cin_hn[fi] = (f32x4){bh, bh, bh, bh};
    }

    // init h: f32 regs in D-layout + bf16 LDS copy (wave-private rows)
    const int rbase = blk0 + wid*16 + 4*kg;
    float hD[8];   // [q][fi] -> hD[2q+fi] = h[4kg+q][c+16fi]
    #pragma unroll
    for (int q = 0; q < 4; q++)
        #pragma unroll
        for (int fi = 0; fi < 2; fi++) {
            float v = h_p[(size_t)(rbase + q) * FD + c + 16*fi];
            hD[2*q + fi] = v;
            hl[wid*16 + 4*kg + q][c + 16*fi] = (__bf16)v;
        }

    // prefetch all 8 steps' x-fragments (h_c frozen during the path sweep)
    const int pA = blk0 + wid*16 + c;
    const int4* pp = (const int4*)(p2c + (size_t)pA * KNB);
    int4 ia = pp[0], ib = pp[1];
    int idxA[KNB] = {ia.x, ia.y, ia.z, ia.w, ib.x, ib.y, ib.z, ib.w};
    bf16x8 Ax[KNB];
    #pragma unroll
    for (int k = 0; k < KNB; k++)
        Ax[k] = *(const bf16x8*)(hcb + (size_t)idxA[k] * FD + 8*kg);

    const int rowA = wid*16 + c;
    #pragma unroll
    for (int k = 0; k < KNB; k++) {
        bf16x8 Ah = *(const bf16x8*)&hl[rowA][8*kg];

        f32x4 arz[4], xn[2], hn[2];
        #pragma unroll
        for (int t = 0; t < 4; t++) {
            arz[t] = __builtin_amdgcn_mfma_f32_16x16x32_bf16(Ax[k], Bx[t], cin_rz[t], 0, 0, 0);
            arz[t] = __builtin_amdgcn_mfma_f32_16x16x32_bf16(Ah,    Bh[t], arz[t],   0, 0, 0);
        }
        #pragma unroll
        for (int fi = 0; fi < 2; fi++) {
            xn[fi] = __builtin_amdgcn_mfma_f32_16x16x32_bf16(Ax[k], Bx[4+fi], cin_xn[fi], 0, 0, 0);
            hn[fi] = __builtin_amdgcn_mfma_f32_16x16x32_bf16(Ah,    Bh[4+fi], cin_hn[fi], 0, 0, 0);
        }

        #pragma unroll
        for (int q = 0; q < 4; q++)
            #pragma unroll
            for (int fi = 0; fi < 2; fi++) {
                float r = sigmoidf_(arz[fi][q]);
                float z = sigmoidf_(arz[2+fi][q]);
                float n = tanhf_(fmaf(r, hn[fi][q], xn[fi][q]));
                float ho = hD[2*q + fi];
                float hv = fmaf(z, ho - n, n);      // (1-z)*n + z*ho
                hD[2*q + fi] = hv;
                hl[wid*16 + 4*kg + q][c + 16*fi] = (__bf16)hv;
            }
    }

    // epilogue: f32 h_p from regs (64B-coalesced per 16-lane group)
    #pragma unroll
    for (int q = 0; q < 4; q++)
        #pragma unroll
        for (int fi = 0; fi < 2; fi++)
            h_p[(size_t)(rbase + q) * FD + c + 16*fi] = hD[2*q + fi];
    // bf16 shadow from LDS (fully coalesced 16B stores)
    {
        int r  = tid >> 2;
        int c0 = (tid & 3) * 8;
        bf16x8 o = *(const bf16x8*)&hl[r][c0];
        *(bf16x8*)(hpb + ((size_t)(blk0 + r)) * FD + c0) = o;
    }
}

// ---------------- wide gather: 32 lanes per channel, f32 agg out ------------
__global__ __launch_bounds__(256) void gather_agg_kernel(
    const __bf16* __restrict__ hpb, const int* __restrict__ offsets,
    const int* __restrict__ elist, float* __restrict__ agg, int C)
{
    int tid = blockIdx.x * blockDim.x + threadIdx.x;
    int c = tid >> 5;
    int f = tid & 31;
    if (c >= C) return;
    int s = offsets[c], e = offsets[c + 1];
    float a0 = 0.f, a1 = 0.f;
    int i = s;
    for (; i + 2 <= e; i += 2) {
        a0 += (float)hpb[(size_t)elist[i]     * FD + f];
        a1 += (float)hpb[(size_t)elist[i + 1] * FD + f];
    }
    if (i < e) a0 += (float)hpb[(size_t)elist[i] * FD + f];
    agg[(size_t)c * FD + f] = a0 + a1;
}

// ---------------- channel GRU2 (1 thread/channel, scalar f32) ---------------
__global__ __launch_bounds__(256) void channel_gru2_kernel(
    const float* __restrict__ agg, float* __restrict__ h_c,
    const float* __restrict__ Wih, const float* __restrict__ Whh,
    const float* __restrict__ bih, const float* __restrict__ bhh,
    __bf16* __restrict__ hcb, int C)
{
    int c = blockIdx.x * blockDim.x + threadIdx.x;
    if (c >= C) return;

    float h[FD], x[FD];
    const float4* hr = (const float4*)(h_c + (size_t)c * FD);
    const float4* xr = (const float4*)(agg + (size_t)c * FD);
    #pragma unroll
    for (int i = 0; i < FD / 4; i++) {
        float4 v = hr[i];
        h[4*i] = v.x; h[4*i+1] = v.y; h[4*i+2] = v.z; h[4*i+3] = v.w;
        float4 w = xr[i];
        x[4*i] = w.x; x[4*i+1] = w.y; x[4*i+2] = w.z; x[4*i+3] = w.w;
    }

    float hn[FD];
    #pragma unroll 4
    for (int j = 0; j < FD; j++) {
        float air = bih[j],        ahr = bhh[j];
        float aiz = bih[FD + j],   ahz = bhh[FD + j];
        float ain = bih[2*FD + j], ahn = bhh[2*FD + j];
        #pragma unroll
        for (int i = 0; i < FD; i++) {
            air = fmaf(Wih[j*FD + i],          x[i], air);
            ahr = fmaf(Whh[j*FD + i],          h[i], ahr);
            aiz = fmaf(Wih[(FD + j)*FD + i],   x[i], aiz);
            ahz = fmaf(Whh[(FD + j)*FD + i],   h[i], ahz);
            ain = fmaf(Wih[(2*FD + j)*FD + i], x[i], ain);
            ahn = fmaf(Whh[(2*FD + j)*FD + i], h[i], ahn);
        }
        float r = sigmoidf_(air + ahr);
        float z = sigmoidf_(aiz + ahz);
        float n = tanhf_(ain + r * ahn);
        hn[j] = (1.0f - z) * n + z * h[j];
    }

    float4* hw = (float4*)(h_c + (size_t)c * FD);
    #pragma unroll
    for (int i = 0; i < FD / 4; i++) {
        float4 v;
        v.x = hn[4*i]; v.y = hn[4*i+1]; v.z = hn[4*i+2]; v.w = hn[4*i+3];
        hw[i] = v;
    }
    #pragma unroll
    for (int g = 0; g < 4; g++) {
        bf16x8 o;
        #pragma unroll
        for (int j = 0; j < 8; j++) o[j] = (__bf16)hn[8*g + j];
        *(bf16x8*)(hcb + (size_t)c * FD + 8*g) = o;
    }
}

// ---------------- tier-2 fallback kernels (atomic path) ---------------------

__global__ __launch_bounds__(256) void path_update_kernel(
    const float* __restrict__ h_c, float* __restrict__ h_p,
    const int* __restrict__ p2c,
    const float* __restrict__ Wih, const float* __restrict__ Whh,
    const float* __restrict__ bih, const float* __restrict__ bhh, int P)
{
    int p = blockIdx.x * blockDim.x + threadIdx.x;
    if (p >= P) return;

    float h[FD];
    const float4* hp4 = (const float4*)(h_p + (size_t)p * FD);
    #pragma unroll
    for (int i = 0; i < FD / 4; i++) {
        float4 v = hp4[i];
        h[4*i] = v.x; h[4*i+1] = v.y; h[4*i+2] = v.z; h[4*i+3] = v.w;
    }

    int idx[KNB];
    const int4* pi = (const int4*)(p2c + (size_t)p * KNB);
    int4 i0 = pi[0], i1 = pi[1];
    idx[0]=i0.x; idx[1]=i0.y; idx[2]=i0.z; idx[3]=i0.w;
    idx[4]=i1.x; idx[5]=i1.y; idx[6]=i1.z; idx[7]=i1.w;

    for (int k = 0; k < KNB; k++) {
        float x[FD];
        const float4* xr = (const float4*)(h_c + (size_t)idx[k] * FD);
        #pragma unroll
        for (int i = 0; i < FD / 4; i++) {
            float4 v = xr[i];
            x[4*i] = v.x; x[4*i+1] = v.y; x[4*i+2] = v.z; x[4*i+3] = v.w;
        }

        float hn[FD];
        #pragma unroll 4
        for (int j = 0; j < FD; j++) {
            float air = bih[j],        ahr = bhh[j];
            float aiz = bih[FD + j],   ahz = bhh[FD + j];
            float ain = bih[2*FD + j], ahn = bhh[2*FD + j];
            #pragma unroll
            for (int i = 0; i < FD; i++) {
                air = fmaf(Wih[j*FD + i],          x[i], air);
                ahr = fmaf(Whh[j*FD + i],          h[i], ahr);
                aiz = fmaf(Wih[(FD + j)*FD + i],   x[i], aiz);
                ahz = fmaf(Whh[(FD + j)*FD + i],   h[i], ahz);
                ain = fmaf(Wih[(2*FD + j)*FD + i], x[i], ain);
                ahn = fmaf(Whh[(2*FD + j)*FD + i], h[i], ahn);
            }
            float r = sigmoidf_(air + ahr);
            float z = sigmoidf_(aiz + ahz);
            float n = tanhf_(ain + r * ahn);
            hn[j] = (1.0f - z) * n + z * h[j];
        }
        #pragma unroll
        for (int j = 0; j < FD; j++) h[j] = hn[j];
    }

    float4* hpw = (float4*)(h_p + (size_t)p * FD);
    #pragma unroll
    for (int i = 0; i < FD / 4; i++) {
        float4 v;
        v.x = h[4*i]; v.y = h[4*i+1]; v.z = h[4*i+2]; v.w = h[4*i+3];
        hpw[i] = v;
    }
}

__global__ __launch_bounds__(256) void scatter_agg_atomic_kernel(
    const float* __restrict__ h_p, const int* __restrict__ p2c,
    float* __restrict__ agg, int P)
{
    int p = blockIdx.x * blockDim.x + threadIdx.x;
    if (p >= P) return;
    const float* hr = h_p + (size_t)p * FD;
    #pragma unroll
    for (int k = 0; k < KNB; k++) {
        int c = p2c[(size_t)p * KNB + k];
        float* ar = agg + (size_t)c * FD;
        #pragma unroll
        for (int i = 0; i < FD; i++) atomicAdd(ar + i, hr[i]);
    }
}

__global__ __launch_bounds__(256) void channel_update_kernel(
    const float* __restrict__ agg, float* __restrict__ h_c,
    const float* __restrict__ Wih, const float* __restrict__ Whh,
    const float* __restrict__ bih, const float* __restrict__ bhh, int C)
{
    int c = blockIdx.x * blockDim.x + threadIdx.x;
    if (c >= C) return;

    float h[FD], x[FD];
    const float4* hr = (const float4*)(h_c + (size_t)c * FD);
    const float4* xr = (const float4*)(agg + (size_t)c * FD);
    #pragma unroll
    for (int i = 0; i < FD / 4; i++) {
        float4 v = hr[i];
        h[4*i] = v.x; h[4*i+1] = v.y; h[4*i+2] = v.z; h[4*i+3] = v.w;
        float4 w = xr[i];
        x[4*i] = w.x; x[4*i+1] = w.y; x[4*i+2] = w.z; x[4*i+3] = w.w;
    }

    float hn[FD];
    #pragma unroll 4
    for (int j = 0; j < FD; j++) {
        float air = bih[j],        ahr = bhh[j];
        float aiz = bih[FD + j],   ahz = bhh[FD + j];
        float ain = bih[2*FD + j], ahn = bhh[2*FD + j];
        #pragma unroll
        for (int i = 0; i < FD; i++) {
            air = fmaf(Wih[j*FD + i],          x[i], air);
            ahr = fmaf(Whh[j*FD + i],          h[i], ahr);
            aiz = fmaf(Wih[(FD + j)*FD + i],   x[i], aiz);
            ahz = fmaf(Whh[(FD + j)*FD + i],   h[i], ahz);
            ain = fmaf(Wih[(2*FD + j)*FD + i], x[i], ain);
            ahn = fmaf(Whh[(2*FD + j)*FD + i], h[i], ahn);
        }
        float r = sigmoidf_(air + ahr);
        float z = sigmoidf_(aiz + ahz);
        float n = tanhf_(ain + r * ahn);
        hn[j] = (1.0f - z) * n + z * h[j];
    }

    float4* hw = (float4*)(h_c + (size_t)c * FD);
    #pragma unroll
    for (int i = 0; i < FD / 4; i++) {
        float4 v;
        v.x = hn[4*i]; v.y = hn[4*i+1]; v.z = hn[4*i+2]; v.w = hn[4*i+3];
        hw[i] = v;
    }
}

extern "C" void kernel_launch(void* const* d_in, const int* in_sizes, int n_in,
                              void* d_out, int out_size, void* d_ws, size_t ws_size,
                              hipStream_t stream) {
    const float* paths    = (const float*)d_in[0];
    const float* channels = (const float*)d_in[1];
    const int*   p2c      = (const int*)d_in[2];
    const float* Wih1 = (const float*)d_in[3];
    const float* Whh1 = (const float*)d_in[4];
    const float* bih1 = (const float*)d_in[5];
    const float* bhh1 = (const float*)d_in[6];
    const float* Wih2 = (const float*)d_in[7];
    const float* Whh2 = (const float*)d_in[8];
    const float* bih2 = (const float*)d_in[9];
    const float* bhh2 = (const float*)d_in[10];

    const int P = in_sizes[0] / FD;     // 200000
    const int C = in_sizes[1] / FD;     // 50000
    const int E = P * KNB;              // 1.6M edges
    const int NR = (C + 255) >> 8;      // 196 buckets

    float* h_p = (float*)d_out;                  // [P*FD]
    float* h_c = h_p + (size_t)P * FD;           // [C*FD]

    // ws: counts[C] | offsets[C+1] | bstart[NR+1] | elist[E] | hcb |
    //     UNION{ build: ebuf[E](int2) + cnt1[NCH*NR] | iter: hpb[P*FD] + agg[C*FD] }
    char* ws = (char*)d_ws;
    size_t cnt_off = 0;
    size_t ofs_off = (cnt_off + (size_t)C * 4 + 255) & ~(size_t)255;
    size_t bst_off = (ofs_off + (size_t)(C + 1) * 4 + 255) & ~(size_t)255;
    size_t el_off  = (bst_off + (size_t)(NR + 1) * 4 + 255) & ~(size_t)255;
    size_t hcb_off = (el_off + (size_t)E * 4 + 255) & ~(size_t)255;
    size_t uni_off = (hcb_off + (size_t)C * FD * 2 + 255) & ~(size_t)255;
    size_t ebuf_b  = (size_t)E * 8;
    size_t cnt1_b  = (size_t)NCH * NR * 4;
    size_t hpb_b   = (size_t)P * FD * 2;
    size_t agg_b   = (size_t)C * FD * 4;
    size_t iter_b  = hpb_b + agg_b;
    size_t bld_b   = ebuf_b + cnt1_b;
    size_t uni_b   = (iter_b > bld_b) ? iter_b : bld_b;

    int*    counts  = (int*)(ws + cnt_off);
    int*    offsets = (int*)(ws + ofs_off);
    int*    bstart  = (int*)(ws + bst_off);
    int*    elist   = (int*)(ws + el_off);
    __bf16* hcb     = (__bf16*)(ws + hcb_off);
    int2*   ebuf    = (int2*)(ws + uni_off);
    int*    cnt1    = (int*)(ws + uni_off + ebuf_b);
    __bf16* hpb     = (__bf16*)(ws + uni_off);             // time-disjoint w/ ebuf
    float*  agg     = (float*)(ws + uni_off + hpb_b);      // time-disjoint w/ cnt1

    const bool mfma_ok = (P % 64 == 0) && (C <= 65536);
    const bool tier1 = mfma_ok && (ws_size >= uni_off + uni_b);

    dim3 pb(256), pg((P + 255) / 256);
    dim3 cb(256), cg((C + 255) / 256);

    if (tier1) {
        hipMemcpyAsync(h_p, paths, (size_t)P * FD * sizeof(float),
                       hipMemcpyDeviceToDevice, stream);
        int n8 = C * FD / 8;
        hc_init_kernel<<<(n8 + 255) / 256, 256, 0, stream>>>(channels, h_c, hcb, n8);

        bincount_kernel<<<NCH, 256, 0, stream>>>(p2c, cnt1, E, NR);
        scan_chunks_kernel<<<1, 256, 0, stream>>>(cnt1, bstart, NR, E);
        binfill_kernel<<<NCH, 256, 0, stream>>>(p2c, cnt1, ebuf, E, NR);
        buckcount_kernel<<<NR, 256, 0, stream>>>(ebuf, bstart, counts, C);
        scan_offsets_kernel<<<1, 1024, 0, stream>>>(counts, offsets, C);
        buckfill_kernel<<<NR, 256, 0, stream>>>(ebuf, bstart, offsets, elist, C);

        dim3 mg(P / 64), mb(256);
        dim3 gg((C * 32 + 255) / 256), gb(256);
        for (int it = 0; it < NITER; it++) {
            path_fused_kernel<<<mg, mb, 0, stream>>>(h_p, p2c, hcb,
                                                     Wih1, Whh1, bih1, bhh1, hpb);
            gather_agg_kernel<<<gg, gb, 0, stream>>>(hpb, offsets, elist, agg, C);
            channel_gru2_kernel<<<cg, cb, 0, stream>>>(agg, h_c,
                                                       Wih2, Whh2, bih2, bhh2, hcb, C);
        }
    } else {
        float* agg0 = (float*)d_ws;
        size_t aggf_b = (size_t)C * FD * sizeof(float);
        hipMemcpyAsync(h_p, paths, (size_t)P * FD * sizeof(float),
                       hipMemcpyDeviceToDevice, stream);
        hipMemcpyAsync(h_c, channels, (size_t)C * FD * sizeof(float),
                       hipMemcpyDeviceToDevice, stream);
        for (int it = 0; it < NITER; it++) {
            path_update_kernel<<<pg, pb, 0, stream>>>(h_c, h_p, p2c,
                                                      Wih1, Whh1, bih1, bhh1, P);
            hipMemsetAsync(agg0, 0, aggf_b, stream);
            scatter_agg_atomic_kernel<<<pg, pb, 0, stream>>>(h_p, p2c, agg0, P);
            channel_update_kernel<<<cg, cb, 0, stream>>>(agg0, h_c,
                                                         Wih2, Whh2, bih2, bhh2, C);
        }
    }
}

// Round 8
// 791.272 us; speedup vs baseline: 5.2432x; 1.4004x over previous
//
#include <hip/hip_runtime.h>

#define FD 32
#define KNB 8
#define NITER 5
#define NCH 256   // edge chunks for the binning passes

typedef __bf16 bf16x8 __attribute__((ext_vector_type(8)));
typedef float  f32x4  __attribute__((ext_vector_type(4)));

// Fast HW transcendentals: v_rcp_f32 / v_exp_f32 instead of IEEE div expansion.
__device__ __forceinline__ float frcp_(float a) { return __builtin_amdgcn_rcpf(a); }
__device__ __forceinline__ float fexp2_(float a) { return __builtin_amdgcn_exp2f(a); }
__device__ __forceinline__ float sigmoidf_(float a) {
    return frcp_(1.0f + fexp2_(a * -1.44269504f));
}
__device__ __forceinline__ float tanhf_(float a) {
    return 1.0f - 2.0f * frcp_(fexp2_(a * 2.88539009f) + 1.0f);
}

// ---------------- atomic-free CSR build (two-level counting sort) -----------
// bucket r = channel >> 8; NR = ceil(C/256) buckets. ~17 us total (round 6).

__global__ __launch_bounds__(256) void bincount_kernel(
    const int* __restrict__ p2c, int* __restrict__ cnt1, int E, int NR)
{
    __shared__ int lds[256];
    int b = blockIdx.x;
    int per = (E + NCH - 1) / NCH;
    int s0 = b * per, s1 = s0 + per; if (s1 > E) s1 = E;
    int t = threadIdx.x;
    if (t < NR) lds[t] = 0;
    __syncthreads();
    for (int e = s0 + t; e < s1; e += 256)
        atomicAdd(&lds[p2c[e] >> 8], 1);
    __syncthreads();
    if (t < NR) cnt1[(size_t)b * NR + t] = lds[t];
}

__global__ __launch_bounds__(256) void scan_chunks_kernel(
    int* __restrict__ cnt1, int* __restrict__ bstart, int NR, int E)
{
    __shared__ int tt[256];
    int t = threadIdx.x;
    int tot = 0;
    if (t < NR)
        for (int b = 0; b < NCH; b++) tot += cnt1[(size_t)b * NR + t];
    tt[t] = (t < NR) ? tot : 0;
    __syncthreads();
    for (int d = 1; d < 256; d <<= 1) {
        int v = (t >= d) ? tt[t - d] : 0;
        __syncthreads();
        tt[t] += v;
        __syncthreads();
    }
    if (t < NR) {
        int run = (t == 0) ? 0 : tt[t - 1];
        bstart[t] = run;
        for (int b = 0; b < NCH; b++) {
            int v = cnt1[(size_t)b * NR + t];
            cnt1[(size_t)b * NR + t] = run;
            run += v;
        }
        if (t == NR - 1) bstart[NR] = E;
    }
}

__global__ __launch_bounds__(256) void binfill_kernel(
    const int* __restrict__ p2c, const int* __restrict__ cnt1,
    int2* __restrict__ ebuf, int E, int NR)
{
    __shared__ int cur[256];
    int b = blockIdx.x;
    int per = (E + NCH - 1) / NCH;
    int s0 = b * per, s1 = s0 + per; if (s1 > E) s1 = E;
    int t = threadIdx.x;
    if (t < NR) cur[t] = cnt1[(size_t)b * NR + t];
    __syncthreads();
    for (int e = s0 + t; e < s1; e += 256) {
        int ch = p2c[e];
        int slot = atomicAdd(&cur[ch >> 8], 1);
        ebuf[slot] = make_int2(e >> 3, ch);   // (path id, channel); KNB == 8
    }
}

__global__ __launch_bounds__(256) void buckcount_kernel(
    const int2* __restrict__ ebuf, const int* __restrict__ bstart,
    int* __restrict__ counts, int C)
{
    __shared__ int h[256];
    int r = blockIdx.x;
    int t = threadIdx.x;
    h[t] = 0;
    __syncthreads();
    int s0 = bstart[r], s1 = bstart[r + 1];
    for (int i = s0 + t; i < s1; i += 256)
        atomicAdd(&h[ebuf[i].y & 255], 1);
    __syncthreads();
    int c = (r << 8) + t;
    if (c < C) counts[c] = h[t];
}

__global__ __launch_bounds__(1024) void scan_offsets_kernel(
    const int* __restrict__ counts, int* __restrict__ offsets, int C)
{
    __shared__ int part[1024];
    int t = threadIdx.x;
    int chunk = (C + 1023) >> 10;
    int base = t * chunk;
    int end = base + chunk; if (end > C) end = C;
    int s = 0;
    for (int i = base; i < end; i++) s += counts[i];
    part[t] = s;
    __syncthreads();
    for (int d = 1; d < 1024; d <<= 1) {
        int v = (t >= d) ? part[t - d] : 0;
        __syncthreads();
        part[t] += v;
        __syncthreads();
    }
    int run = (t == 0) ? 0 : part[t - 1];
    for (int i = base; i < end; i++) {
        offsets[i] = run;
        run += counts[i];
    }
    if (t == 1023) offsets[C] = part[1023];
}

__global__ __launch_bounds__(256) void buckfill_kernel(
    const int2* __restrict__ ebuf, const int* __restrict__ bstart,
    const int* __restrict__ offsets, int* __restrict__ elist, int C)
{
    __shared__ int cur[256];
    int r = blockIdx.x;
    int t = threadIdx.x;
    int c = (r << 8) + t;
    cur[t] = (c < C) ? offsets[c] : 0;
    __syncthreads();
    int s0 = bstart[r], s1 = bstart[r + 1];
    for (int i = s0 + t; i < s1; i += 256) {
        int2 v = ebuf[i];
        int slot = atomicAdd(&cur[v.y & 255], 1);
        elist[slot] = v.x;
    }
}

// ---------------- init: h_c copy + bf16 shadow in one pass ------------------

__global__ __launch_bounds__(256) void hc_init_kernel(
    const float* __restrict__ src, float* __restrict__ h_c,
    __bf16* __restrict__ dst, int n8)
{
    int i = blockIdx.x * blockDim.x + threadIdx.x;
    if (i >= n8) return;
    const float4* s = (const float4*)(src + (size_t)i * 8);
    float4 u = s[0], v = s[1];
    float4* d = (float4*)(h_c + (size_t)i * 8);
    d[0] = u; d[1] = v;
    bf16x8 o;
    o[0]=(__bf16)u.x; o[1]=(__bf16)u.y; o[2]=(__bf16)u.z; o[3]=(__bf16)u.w;
    o[4]=(__bf16)v.x; o[5]=(__bf16)v.y; o[6]=(__bf16)v.z; o[7]=(__bf16)v.w;
    ((bf16x8*)dst)[i] = o;
}

// ---------------- fused path kernel v2 --------------------------------------
#define HLP 40   // bf16 row pitch: 80 B, 16B-aligned
__global__ __launch_bounds__(256) void path_fused_kernel(
    float* __restrict__ h_p, const int* __restrict__ p2c,
    const __bf16* __restrict__ hcb,
    const float* __restrict__ Wih, const float* __restrict__ Whh,
    const float* __restrict__ bih, const float* __restrict__ bhh,
    __bf16* __restrict__ hpb)
{
    __shared__ __bf16 hl[64][HLP];
    const int tid  = threadIdx.x;
    const int wid  = tid >> 6;
    const int lane = tid & 63;
    const int c    = lane & 15;
    const int kg   = lane >> 4;
    const int blk0 = blockIdx.x * 64;

    bf16x8 Bx[6], Bh[6];
    #pragma unroll
    for (int t = 0; t < 6; t++) {
        const float* wi = Wih + (size_t)(16*t + c) * FD + 8*kg;
        const float* wh = Whh + (size_t)(16*t + c) * FD + 8*kg;
        #pragma unroll
        for (int j = 0; j < 8; j++) {
            Bx[t][j] = (__bf16)wi[j];
            Bh[t][j] = (__bf16)wh[j];
        }
    }
    f32x4 cin_rz[4], cin_xn[2], cin_hn[2];
    #pragma unroll
    for (int t = 0; t < 4; t++) {
        float b = bih[16*t + c] + bhh[16*t + c];
        cin_rz[t] = (f32x4){b, b, b, b};
    }
    #pragma unroll
    for (int fi = 0; fi < 2; fi++) {
        float bi = bih[64 + 16*fi + c];
        float bh = bhh[64 + 16*fi + c];
        cin_xn[fi] = (f32x4){bi, bi, bi, bi};
        cin_hn[fi] = (f32x4){bh, bh, bh, bh};
    }

    const int rbase = blk0 + wid*16 + 4*kg;
    float hD[8];
    #pragma unroll
    for (int q = 0; q < 4; q++)
        #pragma unroll
        for (int fi = 0; fi < 2; fi++) {
            float v = h_p[(size_t)(rbase + q) * FD + c + 16*fi];
            hD[2*q + fi] = v;
            hl[wid*16 + 4*kg + q][c + 16*fi] = (__bf16)v;
        }

    const int pA = blk0 + wid*16 + c;
    const int4* pp = (const int4*)(p2c + (size_t)pA * KNB);
    int4 ia = pp[0], ib = pp[1];
    int idxA[KNB] = {ia.x, ia.y, ia.z, ia.w, ib.x, ib.y, ib.z, ib.w};
    bf16x8 Ax[KNB];
    #pragma unroll
    for (int k = 0; k < KNB; k++)
        Ax[k] = *(const bf16x8*)(hcb + (size_t)idxA[k] * FD + 8*kg);

    const int rowA = wid*16 + c;
    #pragma unroll
    for (int k = 0; k < KNB; k++) {
        bf16x8 Ah = *(const bf16x8*)&hl[rowA][8*kg];

        f32x4 arz[4], xn[2], hn[2];
        #pragma unroll
        for (int t = 0; t < 4; t++) {
            arz[t] = __builtin_amdgcn_mfma_f32_16x16x32_bf16(Ax[k], Bx[t], cin_rz[t], 0, 0, 0);
            arz[t] = __builtin_amdgcn_mfma_f32_16x16x32_bf16(Ah,    Bh[t], arz[t],   0, 0, 0);
        }
        #pragma unroll
        for (int fi = 0; fi < 2; fi++) {
            xn[fi] = __builtin_amdgcn_mfma_f32_16x16x32_bf16(Ax[k], Bx[4+fi], cin_xn[fi], 0, 0, 0);
            hn[fi] = __builtin_amdgcn_mfma_f32_16x16x32_bf16(Ah,    Bh[4+fi], cin_hn[fi], 0, 0, 0);
        }

        #pragma unroll
        for (int q = 0; q < 4; q++)
            #pragma unroll
            for (int fi = 0; fi < 2; fi++) {
                float r = sigmoidf_(arz[fi][q]);
                float z = sigmoidf_(arz[2+fi][q]);
                float n = tanhf_(fmaf(r, hn[fi][q], xn[fi][q]));
                float ho = hD[2*q + fi];
                float hv = fmaf(z, ho - n, n);
                hD[2*q + fi] = hv;
                hl[wid*16 + 4*kg + q][c + 16*fi] = (__bf16)hv;
            }
    }

    #pragma unroll
    for (int q = 0; q < 4; q++)
        #pragma unroll
        for (int fi = 0; fi < 2; fi++)
            h_p[(size_t)(rbase + q) * FD + c + 16*fi] = hD[2*q + fi];
    {
        int r  = tid >> 2;
        int c0 = (tid & 3) * 8;
        bf16x8 o = *(const bf16x8*)&hl[r][c0];
        *(bf16x8*)(hpb + ((size_t)(blk0 + r)) * FD + c0) = o;
    }
}

// ---------------- wide gather: 32 lanes/channel, 4-deep MLP -----------------
__global__ __launch_bounds__(256) void gather_agg_kernel(
    const __bf16* __restrict__ hpb, const int* __restrict__ offsets,
    const int* __restrict__ elist, float* __restrict__ agg, int C)
{
    int tid = blockIdx.x * blockDim.x + threadIdx.x;
    int c = tid >> 5;
    int f = tid & 31;
    if (c >= C) return;
    int s = offsets[c], e = offsets[c + 1];
    float a0 = 0.f, a1 = 0.f, a2 = 0.f, a3 = 0.f;
    int i = s;
    for (; i + 4 <= e; i += 4) {
        int e0 = elist[i], e1 = elist[i+1], e2 = elist[i+2], e3 = elist[i+3];
        a0 += (float)hpb[(size_t)e0 * FD + f];
        a1 += (float)hpb[(size_t)e1 * FD + f];
        a2 += (float)hpb[(size_t)e2 * FD + f];
        a3 += (float)hpb[(size_t)e3 * FD + f];
    }
    for (; i < e; i++) a0 += (float)hpb[(size_t)elist[i] * FD + f];
    agg[(size_t)c * FD + f] = (a0 + a1) + (a2 + a3);
}

// ---------------- channel GRU2 via split-precision MFMA ---------------------
// 64 channels/block, 4 waves, 16 channels/wave, no barriers, no LDS.
// A (agg, h_c) and B (W) split hi/lo bf16; D = AhBh + AhBl + AlBh ~ f32-exact
// (drops only AlBl ~ 2^-18 relative). Gate math identical to path kernel.
__global__ __launch_bounds__(256) void channel_mfma_kernel(
    const float* __restrict__ agg, float* __restrict__ h_c,
    const float* __restrict__ Wih, const float* __restrict__ Whh,
    const float* __restrict__ bih, const float* __restrict__ bhh,
    __bf16* __restrict__ hcb, int C)
{
    const int tid  = threadIdx.x;
    const int wid  = tid >> 6;
    const int lane = tid & 63;
    const int c    = lane & 15;
    const int kg   = lane >> 4;
    const int blk0 = blockIdx.x * 64;

    // A fragments hi/lo: row = blk0 + wid*16 + c, k-chunk 8*kg
    const int chA = blk0 + wid*16 + c;
    float xr[8], hr[8];
    if (chA < C) {
        const float4* xa = (const float4*)(agg + (size_t)chA * FD + 8*kg);
        const float4* ha = (const float4*)(h_c + (size_t)chA * FD + 8*kg);
        float4 x0 = xa[0], x1 = xa[1], h0 = ha[0], h1 = ha[1];
        xr[0]=x0.x; xr[1]=x0.y; xr[2]=x0.z; xr[3]=x0.w;
        xr[4]=x1.x; xr[5]=x1.y; xr[6]=x1.z; xr[7]=x1.w;
        hr[0]=h0.x; hr[1]=h0.y; hr[2]=h0.z; hr[3]=h0.w;
        hr[4]=h1.x; hr[5]=h1.y; hr[6]=h1.z; hr[7]=h1.w;
    } else {
        #pragma unroll
        for (int j = 0; j < 8; j++) { xr[j] = 0.f; hr[j] = 0.f; }
    }
    bf16x8 AxH, AxL, AhH, AhL;
    #pragma unroll
    for (int j = 0; j < 8; j++) {
        __bf16 xh = (__bf16)xr[j]; AxH[j] = xh; AxL[j] = (__bf16)(xr[j] - (float)xh);
        __bf16 hh = (__bf16)hr[j]; AhH[j] = hh; AhL[j] = (__bf16)(hr[j] - (float)hh);
    }

    f32x4 cin_rz[4], cin_xn[2], cin_hn[2];
    #pragma unroll
    for (int t = 0; t < 4; t++) {
        float b = bih[16*t + c] + bhh[16*t + c];
        cin_rz[t] = (f32x4){b, b, b, b};
    }
    #pragma unroll
    for (int fi = 0; fi < 2; fi++) {
        float bi = bih[64 + 16*fi + c];
        float bh = bhh[64 + 16*fi + c];
        cin_xn[fi] = (f32x4){bi, bi, bi, bi};
        cin_hn[fi] = (f32x4){bh, bh, bh, bh};
    }

    f32x4 arz[4], xn[2], hn[2];
    #pragma unroll
    for (int t = 0; t < 4; t++) {
        bf16x8 BxH_, BxL_, BhH_, BhL_;
        const float* wi = Wih + (size_t)(16*t + c) * FD + 8*kg;
        const float* wh = Whh + (size_t)(16*t + c) * FD + 8*kg;
        #pragma unroll
        for (int j = 0; j < 8; j++) {
            float w = wi[j]; __bf16 wH = (__bf16)w;
            BxH_[j] = wH; BxL_[j] = (__bf16)(w - (float)wH);
            float v = wh[j]; __bf16 vH = (__bf16)v;
            BhH_[j] = vH; BhL_[j] = (__bf16)(v - (float)vH);
        }
        f32x4 a = cin_rz[t];
        a = __builtin_amdgcn_mfma_f32_16x16x32_bf16(AxH, BxH_, a, 0, 0, 0);
        a = __builtin_amdgcn_mfma_f32_16x16x32_bf16(AxH, BxL_, a, 0, 0, 0);
        a = __builtin_amdgcn_mfma_f32_16x16x32_bf16(AxL, BxH_, a, 0, 0, 0);
        a = __builtin_amdgcn_mfma_f32_16x16x32_bf16(AhH, BhH_, a, 0, 0, 0);
        a = __builtin_amdgcn_mfma_f32_16x16x32_bf16(AhH, BhL_, a, 0, 0, 0);
        a = __builtin_amdgcn_mfma_f32_16x16x32_bf16(AhL, BhH_, a, 0, 0, 0);
        arz[t] = a;
    }
    #pragma unroll
    for (int fi = 0; fi < 2; fi++) {
        bf16x8 BxH_, BxL_, BhH_, BhL_;
        const float* wi = Wih + (size_t)(16*(4+fi) + c) * FD + 8*kg;
        const float* wh = Whh + (size_t)(16*(4+fi) + c) * FD + 8*kg;
        #pragma unroll
        for (int j = 0; j < 8; j++) {
            float w = wi[j]; __bf16 wH = (__bf16)w;
            BxH_[j] = wH; BxL_[j] = (__bf16)(w - (float)wH);
            float v = wh[j]; __bf16 vH = (__bf16)v;
            BhH_[j] = vH; BhL_[j] = (__bf16)(v - (float)vH);
        }
        f32x4 a = cin_xn[fi];
        a = __builtin_amdgcn_mfma_f32_16x16x32_bf16(AxH, BxH_, a, 0, 0, 0);
        a = __builtin_amdgcn_mfma_f32_16x16x32_bf16(AxH, BxL_, a, 0, 0, 0);
        a = __builtin_amdgcn_mfma_f32_16x16x32_bf16(AxL, BxH_, a, 0, 0, 0);
        xn[fi] = a;
        f32x4 b = cin_hn[fi];
        b = __builtin_amdgcn_mfma_f32_16x16x32_bf16(AhH, BhH_, b, 0, 0, 0);
        b = __builtin_amdgcn_mfma_f32_16x16x32_bf16(AhH, BhL_, b, 0, 0, 0);
        b = __builtin_amdgcn_mfma_f32_16x16x32_bf16(AhL, BhH_, b, 0, 0, 0);
        hn[fi] = b;
    }

    // gate math; D rows = blk0 + wid*16 + 4*kg + q. All reads of h_c precede
    // all writes within the wave's private 16-row tile (lockstep) -> safe.
    #pragma unroll
    for (int q = 0; q < 4; q++) {
        int row = blk0 + wid*16 + 4*kg + q;
        if (row < C) {
            #pragma unroll
            for (int fi = 0; fi < 2; fi++) {
                float r = sigmoidf_(arz[fi][q]);
                float z = sigmoidf_(arz[2+fi][q]);
                float n = tanhf_(fmaf(r, hn[fi][q], xn[fi][q]));
                float ho = h_c[(size_t)row * FD + c + 16*fi];
                float hv = fmaf(z, ho - n, n);
                h_c[(size_t)row * FD + c + 16*fi] = hv;
                hcb[(size_t)row * FD + c + 16*fi] = (__bf16)hv;
            }
        }
    }
}

// ---------------- fallback kernels (atomic path) ----------------------------

__global__ __launch_bounds__(256) void path_update_kernel(
    const float* __restrict__ h_c, float* __restrict__ h_p,
    const int* __restrict__ p2c,
    const float* __restrict__ Wih, const float* __restrict__ Whh,
    const float* __restrict__ bih, const float* __restrict__ bhh, int P)
{
    int p = blockIdx.x * blockDim.x + threadIdx.x;
    if (p >= P) return;

    float h[FD];
    const float4* hp4 = (const float4*)(h_p + (size_t)p * FD);
    #pragma unroll
    for (int i = 0; i < FD / 4; i++) {
        float4 v = hp4[i];
        h[4*i] = v.x; h[4*i+1] = v.y; h[4*i+2] = v.z; h[4*i+3] = v.w;
    }

    int idx[KNB];
    const int4* pi = (const int4*)(p2c + (size_t)p * KNB);
    int4 i0 = pi[0], i1 = pi[1];
    idx[0]=i0.x; idx[1]=i0.y; idx[2]=i0.z; idx[3]=i0.w;
    idx[4]=i1.x; idx[5]=i1.y; idx[6]=i1.z; idx[7]=i1.w;

    for (int k = 0; k < KNB; k++) {
        float x[FD];
        const float4* xr = (const float4*)(h_c + (size_t)idx[k] * FD);
        #pragma unroll
        for (int i = 0; i < FD / 4; i++) {
            float4 v = xr[i];
            x[4*i] = v.x; x[4*i+1] = v.y; x[4*i+2] = v.z; x[4*i+3] = v.w;
        }

        float hn[FD];
        #pragma unroll 4
        for (int j = 0; j < FD; j++) {
            float air = bih[j],        ahr = bhh[j];
            float aiz = bih[FD + j],   ahz = bhh[FD + j];
            float ain = bih[2*FD + j], ahn = bhh[2*FD + j];
            #pragma unroll
            for (int i = 0; i < FD; i++) {
                air = fmaf(Wih[j*FD + i],          x[i], air);
                ahr = fmaf(Whh[j*FD + i],          h[i], ahr);
                aiz = fmaf(Wih[(FD + j)*FD + i],   x[i], aiz);
                ahz = fmaf(Whh[(FD + j)*FD + i],   h[i], ahz);
                ain = fmaf(Wih[(2*FD + j)*FD + i], x[i], ain);
                ahn = fmaf(Whh[(2*FD + j)*FD + i], h[i], ahn);
            }
            float r = sigmoidf_(air + ahr);
            float z = sigmoidf_(aiz + ahz);
            float n = tanhf_(ain + r * ahn);
            hn[j] = (1.0f - z) * n + z * h[j];
        }
        #pragma unroll
        for (int j = 0; j < FD; j++) h[j] = hn[j];
    }

    float4* hpw = (float4*)(h_p + (size_t)p * FD);
    #pragma unroll
    for (int i = 0; i < FD / 4; i++) {
        float4 v;
        v.x = h[4*i]; v.y = h[4*i+1]; v.z = h[4*i+2]; v.w = h[4*i+3];
        hpw[i] = v;
    }
}

__global__ __launch_bounds__(256) void scatter_agg_atomic_kernel(
    const float* __restrict__ h_p, const int* __restrict__ p2c,
    float* __restrict__ agg, int P)
{
    int p = blockIdx.x * blockDim.x + threadIdx.x;
    if (p >= P) return;
    const float* hr = h_p + (size_t)p * FD;
    #pragma unroll
    for (int k = 0; k < KNB; k++) {
        int c = p2c[(size_t)p * KNB + k];
        float* ar = agg + (size_t)c * FD;
        #pragma unroll
        for (int i = 0; i < FD; i++) atomicAdd(ar + i, hr[i]);
    }
}

__global__ __launch_bounds__(256) void channel_update_kernel(
    const float* __restrict__ agg, float* __restrict__ h_c,
    const float* __restrict__ Wih, const float* __restrict__ Whh,
    const float* __restrict__ bih, const float* __restrict__ bhh, int C)
{
    int c = blockIdx.x * blockDim.x + threadIdx.x;
    if (c >= C) return;

    float h[FD], x[FD];
    const float4* hr = (const float4*)(h_c + (size_t)c * FD);
    const float4* xr = (const float4*)(agg + (size_t)c * FD);
    #pragma unroll
    for (int i = 0; i < FD / 4; i++) {
        float4 v = hr[i];
        h[4*i] = v.x; h[4*i+1] = v.y; h[4*i+2] = v.z; h[4*i+3] = v.w;
        float4 w = xr[i];
        x[4*i] = w.x; x[4*i+1] = w.y; x[4*i+2] = w.z; x[4*i+3] = w.w;
    }

    float hn[FD];
    #pragma unroll 4
    for (int j = 0; j < FD; j++) {
        float air = bih[j],        ahr = bhh[j];
        float aiz = bih[FD + j],   ahz = bhh[FD + j];
        float ain = bih[2*FD + j], ahn = bhh[2*FD + j];
        #pragma unroll
        for (int i = 0; i < FD; i++) {
            air = fmaf(Wih[j*FD + i],          x[i], air);
            ahr = fmaf(Whh[j*FD + i],          h[i], ahr);
            aiz = fmaf(Wih[(FD + j)*FD + i],   x[i], aiz);
            ahz = fmaf(Whh[(FD + j)*FD + i],   h[i], ahz);
            ain = fmaf(Wih[(2*FD + j)*FD + i], x[i], ain);
            ahn = fmaf(Whh[(2*FD + j)*FD + i], h[i], ahn);
        }
        float r = sigmoidf_(air + ahr);
        float z = sigmoidf_(aiz + ahz);
        float n = tanhf_(ain + r * ahn);
        hn[j] = (1.0f - z) * n + z * h[j];
    }

    float4* hw = (float4*)(h_c + (size_t)c * FD);
    #pragma unroll
    for (int i = 0; i < FD / 4; i++) {
        float4 v;
        v.x = hn[4*i]; v.y = hn[4*i+1]; v.z = hn[4*i+2]; v.w = hn[4*i+3];
        hw[i] = v;
    }
}

extern "C" void kernel_launch(void* const* d_in, const int* in_sizes, int n_in,
                              void* d_out, int out_size, void* d_ws, size_t ws_size,
                              hipStream_t stream) {
    const float* paths    = (const float*)d_in[0];
    const float* channels = (const float*)d_in[1];
    const int*   p2c      = (const int*)d_in[2];
    const float* Wih1 = (const float*)d_in[3];
    const float* Whh1 = (const float*)d_in[4];
    const float* bih1 = (const float*)d_in[5];
    const float* bhh1 = (const float*)d_in[6];
    const float* Wih2 = (const float*)d_in[7];
    const float* Whh2 = (const float*)d_in[8];
    const float* bih2 = (const float*)d_in[9];
    const float* bhh2 = (const float*)d_in[10];

    const int P = in_sizes[0] / FD;     // 200000
    const int C = in_sizes[1] / FD;     // 50000
    const int E = P * KNB;              // 1.6M edges
    const int NR = (C + 255) >> 8;      // 196 buckets

    float* h_p = (float*)d_out;                  // [P*FD]
    float* h_c = h_p + (size_t)P * FD;           // [C*FD]

    // ws: counts[C] | offsets[C+1] | bstart[NR+1] | elist[E] | hcb |
    //     UNION{ build: ebuf[E](int2)+cnt1[NCH*NR] | iter: hpb[P*FD]+agg[C*FD] }
    char* ws = (char*)d_ws;
    size_t cnt_off = 0;
    size_t ofs_off = (cnt_off + (size_t)C * 4 + 255) & ~(size_t)255;
    size_t bst_off = (ofs_off + (size_t)(C + 1) * 4 + 255) & ~(size_t)255;
    size_t el_off  = (bst_off + (size_t)(NR + 1) * 4 + 255) & ~(size_t)255;
    size_t hcb_off = (el_off + (size_t)E * 4 + 255) & ~(size_t)255;
    size_t uni_off = (hcb_off + (size_t)C * FD * 2 + 255) & ~(size_t)255;
    size_t ebuf_b  = (size_t)E * 8;
    size_t cnt1_b  = (size_t)NCH * NR * 4;
    size_t hpb_b   = (size_t)P * FD * 2;
    size_t agg_b   = (size_t)C * FD * 4;
    size_t iter_b  = hpb_b + agg_b;
    size_t bld_b   = ebuf_b + cnt1_b;
    size_t uni_b   = (iter_b > bld_b) ? iter_b : bld_b;

    int*    counts  = (int*)(ws + cnt_off);
    int*    offsets = (int*)(ws + ofs_off);
    int*    bstart  = (int*)(ws + bst_off);
    int*    elist   = (int*)(ws + el_off);
    __bf16* hcb     = (__bf16*)(ws + hcb_off);
    int2*   ebuf    = (int2*)(ws + uni_off);
    int*    cnt1    = (int*)(ws + uni_off + ebuf_b);
    __bf16* hpb     = (__bf16*)(ws + uni_off);             // time-disjoint w/ ebuf
    float*  agg     = (float*)(ws + uni_off + hpb_b);      // time-disjoint w/ cnt1

    const bool mfma_ok = (P % 64 == 0) && (C <= 65536);
    const bool tier1 = mfma_ok && (ws_size >= uni_off + uni_b);

    dim3 pb(256), pg((P + 255) / 256);
    dim3 cb(256), cg((C + 255) / 256);

    if (tier1) {
        hipMemcpyAsync(h_p, paths, (size_t)P * FD * sizeof(float),
                       hipMemcpyDeviceToDevice, stream);
        int n8 = C * FD / 8;
        hc_init_kernel<<<(n8 + 255) / 256, 256, 0, stream>>>(channels, h_c, hcb, n8);

        bincount_kernel<<<NCH, 256, 0, stream>>>(p2c, cnt1, E, NR);
        scan_chunks_kernel<<<1, 256, 0, stream>>>(cnt1, bstart, NR, E);
        binfill_kernel<<<NCH, 256, 0, stream>>>(p2c, cnt1, ebuf, E, NR);
        buckcount_kernel<<<NR, 256, 0, stream>>>(ebuf, bstart, counts, C);
        scan_offsets_kernel<<<1, 1024, 0, stream>>>(counts, offsets, C);
        buckfill_kernel<<<NR, 256, 0, stream>>>(ebuf, bstart, offsets, elist, C);

        dim3 mg(P / 64), mb(256);
        dim3 gg((C * 32 + 255) / 256), gb(256);
        dim3 xg((C + 63) / 64), xb(256);
        for (int it = 0; it < NITER; it++) {
            path_fused_kernel<<<mg, mb, 0, stream>>>(h_p, p2c, hcb,
                                                     Wih1, Whh1, bih1, bhh1, hpb);
            gather_agg_kernel<<<gg, gb, 0, stream>>>(hpb, offsets, elist, agg, C);
            channel_mfma_kernel<<<xg, xb, 0, stream>>>(agg, h_c,
                                                       Wih2, Whh2, bih2, bhh2, hcb, C);
        }
    } else {
        float* agg0 = (float*)d_ws;
        size_t aggf_b = (size_t)C * FD * sizeof(float);
        hipMemcpyAsync(h_p, paths, (size_t)P * FD * sizeof(float),
                       hipMemcpyDeviceToDevice, stream);
        hipMemcpyAsync(h_c, channels, (size_t)C * FD * sizeof(float),
                       hipMemcpyDeviceToDevice, stream);
        for (int it = 0; it < NITER; it++) {
            path_update_kernel<<<pg, pb, 0, stream>>>(h_c, h_p, p2c,
                                                      Wih1, Whh1, bih1, bhh1, P);
            hipMemsetAsync(agg0, 0, aggf_b, stream);
            scatter_agg_atomic_kernel<<<pg, pb, 0, stream>>>(h_p, p2c, agg0, P);
            channel_update_kernel<<<cg, cb, 0, stream>>>(agg0, h_c,
                                                         Wih2, Whh2, bih2, bhh2, C);
        }
    }
}

// Round 9
// 714.505 us; speedup vs baseline: 5.8065x; 1.1074x over previous
//
#include <hip/hip_runtime.h>

#define FD 32
#define KNB 8
#define NITER 5
#define NCH 256   // edge chunks for the binning passes

typedef __bf16 bf16x8 __attribute__((ext_vector_type(8)));
typedef float  f32x4  __attribute__((ext_vector_type(4)));

// Fast HW transcendentals: v_rcp_f32 / v_exp_f32 instead of IEEE div expansion.
__device__ __forceinline__ float frcp_(float a) { return __builtin_amdgcn_rcpf(a); }
__device__ __forceinline__ float fexp2_(float a) { return __builtin_amdgcn_exp2f(a); }
__device__ __forceinline__ float sigmoidf_(float a) {
    return frcp_(1.0f + fexp2_(a * -1.44269504f));
}
__device__ __forceinline__ float tanhf_(float a) {
    return 1.0f - 2.0f * frcp_(fexp2_(a * 2.88539009f) + 1.0f);
}

// ---------------- atomic-free CSR build (two-level counting sort) -----------
// bucket r = channel >> 8; NR = ceil(C/256) buckets. ~17 us total (round 6).

__global__ __launch_bounds__(256) void bincount_kernel(
    const int* __restrict__ p2c, int* __restrict__ cnt1, int E, int NR)
{
    __shared__ int lds[256];
    int b = blockIdx.x;
    int per = (E + NCH - 1) / NCH;
    int s0 = b * per, s1 = s0 + per; if (s1 > E) s1 = E;
    int t = threadIdx.x;
    if (t < NR) lds[t] = 0;
    __syncthreads();
    for (int e = s0 + t; e < s1; e += 256)
        atomicAdd(&lds[p2c[e] >> 8], 1);
    __syncthreads();
    if (t < NR) cnt1[(size_t)b * NR + t] = lds[t];
}

__global__ __launch_bounds__(256) void scan_chunks_kernel(
    int* __restrict__ cnt1, int* __restrict__ bstart, int NR, int E)
{
    __shared__ int tt[256];
    int t = threadIdx.x;
    int tot = 0;
    if (t < NR)
        for (int b = 0; b < NCH; b++) tot += cnt1[(size_t)b * NR + t];
    tt[t] = (t < NR) ? tot : 0;
    __syncthreads();
    for (int d = 1; d < 256; d <<= 1) {
        int v = (t >= d) ? tt[t - d] : 0;
        __syncthreads();
        tt[t] += v;
        __syncthreads();
    }
    if (t < NR) {
        int run = (t == 0) ? 0 : tt[t - 1];
        bstart[t] = run;
        for (int b = 0; b < NCH; b++) {
            int v = cnt1[(size_t)b * NR + t];
            cnt1[(size_t)b * NR + t] = run;
            run += v;
        }
        if (t == NR - 1) bstart[NR] = E;
    }
}

__global__ __launch_bounds__(256) void binfill_kernel(
    const int* __restrict__ p2c, const int* __restrict__ cnt1,
    int2* __restrict__ ebuf, int E, int NR)
{
    __shared__ int cur[256];
    int b = blockIdx.x;
    int per = (E + NCH - 1) / NCH;
    int s0 = b * per, s1 = s0 + per; if (s1 > E) s1 = E;
    int t = threadIdx.x;
    if (t < NR) cur[t] = cnt1[(size_t)b * NR + t];
    __syncthreads();
    for (int e = s0 + t; e < s1; e += 256) {
        int ch = p2c[e];
        int slot = atomicAdd(&cur[ch >> 8], 1);
        ebuf[slot] = make_int2(e >> 3, ch);   // (path id, channel); KNB == 8
    }
}

__global__ __launch_bounds__(256) void buckcount_kernel(
    const int2* __restrict__ ebuf, const int* __restrict__ bstart,
    int* __restrict__ counts, int C)
{
    __shared__ int h[256];
    int r = blockIdx.x;
    int t = threadIdx.x;
    h[t] = 0;
    __syncthreads();
    int s0 = bstart[r], s1 = bstart[r + 1];
    for (int i = s0 + t; i < s1; i += 256)
        atomicAdd(&h[ebuf[i].y & 255], 1);
    __syncthreads();
    int c = (r << 8) + t;
    if (c < C) counts[c] = h[t];
}

__global__ __launch_bounds__(1024) void scan_offsets_kernel(
    const int* __restrict__ counts, int* __restrict__ offsets, int C)
{
    __shared__ int part[1024];
    int t = threadIdx.x;
    int chunk = (C + 1023) >> 10;
    int base = t * chunk;
    int end = base + chunk; if (end > C) end = C;
    int s = 0;
    for (int i = base; i < end; i++) s += counts[i];
    part[t] = s;
    __syncthreads();
    for (int d = 1; d < 1024; d <<= 1) {
        int v = (t >= d) ? part[t - d] : 0;
        __syncthreads();
        part[t] += v;
        __syncthreads();
    }
    int run = (t == 0) ? 0 : part[t - 1];
    for (int i = base; i < end; i++) {
        offsets[i] = run;
        run += counts[i];
    }
    if (t == 1023) offsets[C] = part[1023];
}

__global__ __launch_bounds__(256) void buckfill_kernel(
    const int2* __restrict__ ebuf, const int* __restrict__ bstart,
    const int* __restrict__ offsets, int* __restrict__ elist, int C)
{
    __shared__ int cur[256];
    int r = blockIdx.x;
    int t = threadIdx.x;
    int c = (r << 8) + t;
    cur[t] = (c < C) ? offsets[c] : 0;
    __syncthreads();
    int s0 = bstart[r], s1 = bstart[r + 1];
    for (int i = s0 + t; i < s1; i += 256) {
        int2 v = ebuf[i];
        int slot = atomicAdd(&cur[v.y & 255], 1);
        elist[slot] = v.x;
    }
}

// ---------------- init: h_c copy + bf16 shadow in one pass ------------------

__global__ __launch_bounds__(256) void hc_init_kernel(
    const float* __restrict__ src, float* __restrict__ h_c,
    __bf16* __restrict__ dst, int n8)
{
    int i = blockIdx.x * blockDim.x + threadIdx.x;
    if (i >= n8) return;
    const float4* s = (const float4*)(src + (size_t)i * 8);
    float4 u = s[0], v = s[1];
    float4* d = (float4*)(h_c + (size_t)i * 8);
    d[0] = u; d[1] = v;
    bf16x8 o;
    o[0]=(__bf16)u.x; o[1]=(__bf16)u.y; o[2]=(__bf16)u.z; o[3]=(__bf16)u.w;
    o[4]=(__bf16)v.x; o[5]=(__bf16)v.y; o[6]=(__bf16)v.z; o[7]=(__bf16)v.w;
    ((bf16x8*)dst)[i] = o;
}

// ---------------- fused path kernel v2 (unchanged from round 8) -------------
#define HLP 40   // bf16 row pitch: 80 B, 16B-aligned
__global__ __launch_bounds__(256) void path_fused_kernel(
    float* __restrict__ h_p, const int* __restrict__ p2c,
    const __bf16* __restrict__ hcb,
    const float* __restrict__ Wih, const float* __restrict__ Whh,
    const float* __restrict__ bih, const float* __restrict__ bhh,
    __bf16* __restrict__ hpb)
{
    __shared__ __bf16 hl[64][HLP];
    const int tid  = threadIdx.x;
    const int wid  = tid >> 6;
    const int lane = tid & 63;
    const int c    = lane & 15;
    const int kg   = lane >> 4;
    const int blk0 = blockIdx.x * 64;

    bf16x8 Bx[6], Bh[6];
    #pragma unroll
    for (int t = 0; t < 6; t++) {
        const float* wi = Wih + (size_t)(16*t + c) * FD + 8*kg;
        const float* wh = Whh + (size_t)(16*t + c) * FD + 8*kg;
        #pragma unroll
        for (int j = 0; j < 8; j++) {
            Bx[t][j] = (__bf16)wi[j];
            Bh[t][j] = (__bf16)wh[j];
        }
    }
    f32x4 cin_rz[4], cin_xn[2], cin_hn[2];
    #pragma unroll
    for (int t = 0; t < 4; t++) {
        float b = bih[16*t + c] + bhh[16*t + c];
        cin_rz[t] = (f32x4){b, b, b, b};
    }
    #pragma unroll
    for (int fi = 0; fi < 2; fi++) {
        float bi = bih[64 + 16*fi + c];
        float bh = bhh[64 + 16*fi + c];
        cin_xn[fi] = (f32x4){bi, bi, bi, bi};
        cin_hn[fi] = (f32x4){bh, bh, bh, bh};
    }

    const int rbase = blk0 + wid*16 + 4*kg;
    float hD[8];
    #pragma unroll
    for (int q = 0; q < 4; q++)
        #pragma unroll
        for (int fi = 0; fi < 2; fi++) {
            float v = h_p[(size_t)(rbase + q) * FD + c + 16*fi];
            hD[2*q + fi] = v;
            hl[wid*16 + 4*kg + q][c + 16*fi] = (__bf16)v;
        }

    const int pA = blk0 + wid*16 + c;
    const int4* pp = (const int4*)(p2c + (size_t)pA * KNB);
    int4 ia = pp[0], ib = pp[1];
    int idxA[KNB] = {ia.x, ia.y, ia.z, ia.w, ib.x, ib.y, ib.z, ib.w};
    bf16x8 Ax[KNB];
    #pragma unroll
    for (int k = 0; k < KNB; k++)
        Ax[k] = *(const bf16x8*)(hcb + (size_t)idxA[k] * FD + 8*kg);

    const int rowA = wid*16 + c;
    #pragma unroll
    for (int k = 0; k < KNB; k++) {
        bf16x8 Ah = *(const bf16x8*)&hl[rowA][8*kg];

        f32x4 arz[4], xn[2], hn[2];
        #pragma unroll
        for (int t = 0; t < 4; t++) {
            arz[t] = __builtin_amdgcn_mfma_f32_16x16x32_bf16(Ax[k], Bx[t], cin_rz[t], 0, 0, 0);
            arz[t] = __builtin_amdgcn_mfma_f32_16x16x32_bf16(Ah,    Bh[t], arz[t],   0, 0, 0);
        }
        #pragma unroll
        for (int fi = 0; fi < 2; fi++) {
            xn[fi] = __builtin_amdgcn_mfma_f32_16x16x32_bf16(Ax[k], Bx[4+fi], cin_xn[fi], 0, 0, 0);
            hn[fi] = __builtin_amdgcn_mfma_f32_16x16x32_bf16(Ah,    Bh[4+fi], cin_hn[fi], 0, 0, 0);
        }

        #pragma unroll
        for (int q = 0; q < 4; q++)
            #pragma unroll
            for (int fi = 0; fi < 2; fi++) {
                float r = sigmoidf_(arz[fi][q]);
                float z = sigmoidf_(arz[2+fi][q]);
                float n = tanhf_(fmaf(r, hn[fi][q], xn[fi][q]));
                float ho = hD[2*q + fi];
                float hv = fmaf(z, ho - n, n);
                hD[2*q + fi] = hv;
                hl[wid*16 + 4*kg + q][c + 16*fi] = (__bf16)hv;
            }
    }

    #pragma unroll
    for (int q = 0; q < 4; q++)
        #pragma unroll
        for (int fi = 0; fi < 2; fi++)
            h_p[(size_t)(rbase + q) * FD + c + 16*fi] = hD[2*q + fi];
    {
        int r  = tid >> 2;
        int c0 = (tid & 3) * 8;
        bf16x8 o = *(const bf16x8*)&hl[r][c0];
        *(bf16x8*)(hpb + ((size_t)(blk0 + r)) * FD + c0) = o;
    }
}

// ---------------- fused gather + channel GRU2 (MFMA) ------------------------
// 64 channels/block, 4 waves, 16 channels/wave, no barriers, no LDS, no agg.
// Gather: lane (c,kg) accumulates its channel's edge rows DIRECTLY into the
// MFMA A-fragment slice agg[ch][8kg..8kg+7] via 16B bf16x8 loads — 4 lanes
// cover each 64B row, 8x fewer load instructions than the 2B-lane gather.
// Then split-precision MFMA (AhBh+AhBl+AlBh ~ f32-exact) + gate math.
__global__ __launch_bounds__(256) void gchannel_kernel(
    const __bf16* __restrict__ hpb, const int* __restrict__ offsets,
    const int* __restrict__ elist, float* __restrict__ h_c,
    const float* __restrict__ Wih, const float* __restrict__ Whh,
    const float* __restrict__ bih, const float* __restrict__ bhh,
    __bf16* __restrict__ hcb, int C)
{
    const int tid  = threadIdx.x;
    const int wid  = tid >> 6;
    const int lane = tid & 63;
    const int c    = lane & 15;
    const int kg   = lane >> 4;
    const int blk0 = blockIdx.x * 64;
    const int chA  = blk0 + wid*16 + c;

    // ---- gather phase: xr[8] = sum of incident bf16 path rows (f32 accum)
    float xr[8];
    #pragma unroll
    for (int j = 0; j < 8; j++) xr[j] = 0.f;
    int s = 0, e = 0;
    if (chA < C) { s = offsets[chA]; e = offsets[chA + 1]; }
    int i = s;
    for (; i + 2 <= e; i += 2) {
        int e0 = elist[i], e1 = elist[i + 1];
        bf16x8 v0 = *(const bf16x8*)(hpb + (size_t)e0 * FD + 8*kg);
        bf16x8 v1 = *(const bf16x8*)(hpb + (size_t)e1 * FD + 8*kg);
        #pragma unroll
        for (int j = 0; j < 8; j++) xr[j] += (float)v0[j] + (float)v1[j];
    }
    if (i < e) {
        bf16x8 v0 = *(const bf16x8*)(hpb + (size_t)elist[i] * FD + 8*kg);
        #pragma unroll
        for (int j = 0; j < 8; j++) xr[j] += (float)v0[j];
    }

    // ---- h_c A-fragment
    float hr[8];
    if (chA < C) {
        const float4* ha = (const float4*)(h_c + (size_t)chA * FD + 8*kg);
        float4 h0 = ha[0], h1 = ha[1];
        hr[0]=h0.x; hr[1]=h0.y; hr[2]=h0.z; hr[3]=h0.w;
        hr[4]=h1.x; hr[5]=h1.y; hr[6]=h1.z; hr[7]=h1.w;
    } else {
        #pragma unroll
        for (int j = 0; j < 8; j++) hr[j] = 0.f;
    }
    bf16x8 AxH, AxL, AhH, AhL;
    #pragma unroll
    for (int j = 0; j < 8; j++) {
        __bf16 xh = (__bf16)xr[j]; AxH[j] = xh; AxL[j] = (__bf16)(xr[j] - (float)xh);
        __bf16 hh = (__bf16)hr[j]; AhH[j] = hh; AhL[j] = (__bf16)(hr[j] - (float)hh);
    }

    f32x4 cin_rz[4], cin_xn[2], cin_hn[2];
    #pragma unroll
    for (int t = 0; t < 4; t++) {
        float b = bih[16*t + c] + bhh[16*t + c];
        cin_rz[t] = (f32x4){b, b, b, b};
    }
    #pragma unroll
    for (int fi = 0; fi < 2; fi++) {
        float bi = bih[64 + 16*fi + c];
        float bh = bhh[64 + 16*fi + c];
        cin_xn[fi] = (f32x4){bi, bi, bi, bi};
        cin_hn[fi] = (f32x4){bh, bh, bh, bh};
    }

    f32x4 arz[4], xn[2], hn[2];
    #pragma unroll
    for (int t = 0; t < 4; t++) {
        bf16x8 BxH_, BxL_, BhH_, BhL_;
        const float* wi = Wih + (size_t)(16*t + c) * FD + 8*kg;
        const float* wh = Whh + (size_t)(16*t + c) * FD + 8*kg;
        #pragma unroll
        for (int j = 0; j < 8; j++) {
            float w = wi[j]; __bf16 wH = (__bf16)w;
            BxH_[j] = wH; BxL_[j] = (__bf16)(w - (float)wH);
            float v = wh[j]; __bf16 vH = (__bf16)v;
            BhH_[j] = vH; BhL_[j] = (__bf16)(v - (float)vH);
        }
        f32x4 a = cin_rz[t];
        a = __builtin_amdgcn_mfma_f32_16x16x32_bf16(AxH, BxH_, a, 0, 0, 0);
        a = __builtin_amdgcn_mfma_f32_16x16x32_bf16(AxH, BxL_, a, 0, 0, 0);
        a = __builtin_amdgcn_mfma_f32_16x16x32_bf16(AxL, BxH_, a, 0, 0, 0);
        a = __builtin_amdgcn_mfma_f32_16x16x32_bf16(AhH, BhH_, a, 0, 0, 0);
        a = __builtin_amdgcn_mfma_f32_16x16x32_bf16(AhH, BhL_, a, 0, 0, 0);
        a = __builtin_amdgcn_mfma_f32_16x16x32_bf16(AhL, BhH_, a, 0, 0, 0);
        arz[t] = a;
    }
    #pragma unroll
    for (int fi = 0; fi < 2; fi++) {
        bf16x8 BxH_, BxL_, BhH_, BhL_;
        const float* wi = Wih + (size_t)(16*(4+fi) + c) * FD + 8*kg;
        const float* wh = Whh + (size_t)(16*(4+fi) + c) * FD + 8*kg;
        #pragma unroll
        for (int j = 0; j < 8; j++) {
            float w = wi[j]; __bf16 wH = (__bf16)w;
            BxH_[j] = wH; BxL_[j] = (__bf16)(w - (float)wH);
            float v = wh[j]; __bf16 vH = (__bf16)v;
            BhH_[j] = vH; BhL_[j] = (__bf16)(v - (float)vH);
        }
        f32x4 a = cin_xn[fi];
        a = __builtin_amdgcn_mfma_f32_16x16x32_bf16(AxH, BxH_, a, 0, 0, 0);
        a = __builtin_amdgcn_mfma_f32_16x16x32_bf16(AxH, BxL_, a, 0, 0, 0);
        a = __builtin_amdgcn_mfma_f32_16x16x32_bf16(AxL, BxH_, a, 0, 0, 0);
        xn[fi] = a;
        f32x4 b = cin_hn[fi];
        b = __builtin_amdgcn_mfma_f32_16x16x32_bf16(AhH, BhH_, b, 0, 0, 0);
        b = __builtin_amdgcn_mfma_f32_16x16x32_bf16(AhH, BhL_, b, 0, 0, 0);
        b = __builtin_amdgcn_mfma_f32_16x16x32_bf16(AhL, BhH_, b, 0, 0, 0);
        hn[fi] = b;
    }

    // gate math; within-wave lockstep: all h_c reads (A-frag above + ho here)
    // precede the writes in program order -> no intra-wave race; tiles are
    // wave/block-private -> no inter-wave race.
    #pragma unroll
    for (int q = 0; q < 4; q++) {
        int row = blk0 + wid*16 + 4*kg + q;
        if (row < C) {
            #pragma unroll
            for (int fi = 0; fi < 2; fi++) {
                float r = sigmoidf_(arz[fi][q]);
                float z = sigmoidf_(arz[2+fi][q]);
                float n = tanhf_(fmaf(r, hn[fi][q], xn[fi][q]));
                float ho = h_c[(size_t)row * FD + c + 16*fi];
                float hv = fmaf(z, ho - n, n);
                h_c[(size_t)row * FD + c + 16*fi] = hv;
                hcb[(size_t)row * FD + c + 16*fi] = (__bf16)hv;
            }
        }
    }
}

// ---------------- fallback kernels (atomic path) ----------------------------

__global__ __launch_bounds__(256) void path_update_kernel(
    const float* __restrict__ h_c, float* __restrict__ h_p,
    const int* __restrict__ p2c,
    const float* __restrict__ Wih, const float* __restrict__ Whh,
    const float* __restrict__ bih, const float* __restrict__ bhh, int P)
{
    int p = blockIdx.x * blockDim.x + threadIdx.x;
    if (p >= P) return;

    float h[FD];
    const float4* hp4 = (const float4*)(h_p + (size_t)p * FD);
    #pragma unroll
    for (int i = 0; i < FD / 4; i++) {
        float4 v = hp4[i];
        h[4*i] = v.x; h[4*i+1] = v.y; h[4*i+2] = v.z; h[4*i+3] = v.w;
    }

    int idx[KNB];
    const int4* pi = (const int4*)(p2c + (size_t)p * KNB);
    int4 i0 = pi[0], i1 = pi[1];
    idx[0]=i0.x; idx[1]=i0.y; idx[2]=i0.z; idx[3]=i0.w;
    idx[4]=i1.x; idx[5]=i1.y; idx[6]=i1.z; idx[7]=i1.w;

    for (int k = 0; k < KNB; k++) {
        float x[FD];
        const float4* xr = (const float4*)(h_c + (size_t)idx[k] * FD);
        #pragma unroll
        for (int i = 0; i < FD / 4; i++) {
            float4 v = xr[i];
            x[4*i] = v.x; x[4*i+1] = v.y; x[4*i+2] = v.z; x[4*i+3] = v.w;
        }

        float hn[FD];
        #pragma unroll 4
        for (int j = 0; j < FD; j++) {
            float air = bih[j],        ahr = bhh[j];
            float aiz = bih[FD + j],   ahz = bhh[FD + j];
            float ain = bih[2*FD + j], ahn = bhh[2*FD + j];
            #pragma unroll
            for (int i = 0; i < FD; i++) {
                air = fmaf(Wih[j*FD + i],          x[i], air);
                ahr = fmaf(Whh[j*FD + i],          h[i], ahr);
                aiz = fmaf(Wih[(FD + j)*FD + i],   x[i], aiz);
                ahz = fmaf(Whh[(FD + j)*FD + i],   h[i], ahz);
                ain = fmaf(Wih[(2*FD + j)*FD + i], x[i], ain);
                ahn = fmaf(Whh[(2*FD + j)*FD + i], h[i], ahn);
            }
            float r = sigmoidf_(air + ahr);
            float z = sigmoidf_(aiz + ahz);
            float n = tanhf_(ain + r * ahn);
            hn[j] = (1.0f - z) * n + z * h[j];
        }
        #pragma unroll
        for (int j = 0; j < FD; j++) h[j] = hn[j];
    }

    float4* hpw = (float4*)(h_p + (size_t)p * FD);
    #pragma unroll
    for (int i = 0; i < FD / 4; i++) {
        float4 v;
        v.x = h[4*i]; v.y = h[4*i+1]; v.z = h[4*i+2]; v.w = h[4*i+3];
        hpw[i] = v;
    }
}

__global__ __launch_bounds__(256) void scatter_agg_atomic_kernel(
    const float* __restrict__ h_p, const int* __restrict__ p2c,
    float* __restrict__ agg, int P)
{
    int p = blockIdx.x * blockDim.x + threadIdx.x;
    if (p >= P) return;
    const float* hr = h_p + (size_t)p * FD;
    #pragma unroll
    for (int k = 0; k < KNB; k++) {
        int c = p2c[(size_t)p * KNB + k];
        float* ar = agg + (size_t)c * FD;
        #pragma unroll
        for (int i = 0; i < FD; i++) atomicAdd(ar + i, hr[i]);
    }
}

__global__ __launch_bounds__(256) void channel_update_kernel(
    const float* __restrict__ agg, float* __restrict__ h_c,
    const float* __restrict__ Wih, const float* __restrict__ Whh,
    const float* __restrict__ bih, const float* __restrict__ bhh, int C)
{
    int c = blockIdx.x * blockDim.x + threadIdx.x;
    if (c >= C) return;

    float h[FD], x[FD];
    const float4* hr = (const float4*)(h_c + (size_t)c * FD);
    const float4* xr = (const float4*)(agg + (size_t)c * FD);
    #pragma unroll
    for (int i = 0; i < FD / 4; i++) {
        float4 v = hr[i];
        h[4*i] = v.x; h[4*i+1] = v.y; h[4*i+2] = v.z; h[4*i+3] = v.w;
        float4 w = xr[i];
        x[4*i] = w.x; x[4*i+1] = w.y; x[4*i+2] = w.z; x[4*i+3] = w.w;
    }

    float hn[FD];
    #pragma unroll 4
    for (int j = 0; j < FD; j++) {
        float air = bih[j],        ahr = bhh[j];
        float aiz = bih[FD + j],   ahz = bhh[FD + j];
        float ain = bih[2*FD + j], ahn = bhh[2*FD + j];
        #pragma unroll
        for (int i = 0; i < FD; i++) {
            air = fmaf(Wih[j*FD + i],          x[i], air);
            ahr = fmaf(Whh[j*FD + i],          h[i], ahr);
            aiz = fmaf(Wih[(FD + j)*FD + i],   x[i], aiz);
            ahz = fmaf(Whh[(FD + j)*FD + i],   h[i], ahz);
            ain = fmaf(Wih[(2*FD + j)*FD + i], x[i], ain);
            ahn = fmaf(Whh[(2*FD + j)*FD + i], h[i], ahn);
        }
        float r = sigmoidf_(air + ahr);
        float z = sigmoidf_(aiz + ahz);
        float n = tanhf_(ain + r * ahn);
        hn[j] = (1.0f - z) * n + z * h[j];
    }

    float4* hw = (float4*)(h_c + (size_t)c * FD);
    #pragma unroll
    for (int i = 0; i < FD / 4; i++) {
        float4 v;
        v.x = hn[4*i]; v.y = hn[4*i+1]; v.z = hn[4*i+2]; v.w = hn[4*i+3];
        hw[i] = v;
    }
}

extern "C" void kernel_launch(void* const* d_in, const int* in_sizes, int n_in,
                              void* d_out, int out_size, void* d_ws, size_t ws_size,
                              hipStream_t stream) {
    const float* paths    = (const float*)d_in[0];
    const float* channels = (const float*)d_in[1];
    const int*   p2c      = (const int*)d_in[2];
    const float* Wih1 = (const float*)d_in[3];
    const float* Whh1 = (const float*)d_in[4];
    const float* bih1 = (const float*)d_in[5];
    const float* bhh1 = (const float*)d_in[6];
    const float* Wih2 = (const float*)d_in[7];
    const float* Whh2 = (const float*)d_in[8];
    const float* bih2 = (const float*)d_in[9];
    const float* bhh2 = (const float*)d_in[10];

    const int P = in_sizes[0] / FD;     // 200000
    const int C = in_sizes[1] / FD;     // 50000
    const int E = P * KNB;              // 1.6M edges
    const int NR = (C + 255) >> 8;      // 196 buckets

    float* h_p = (float*)d_out;                  // [P*FD]
    float* h_c = h_p + (size_t)P * FD;           // [C*FD]

    // ws: counts[C] | offsets[C+1] | bstart[NR+1] | elist[E] | hcb |
    //     UNION{ build: ebuf[E](int2)+cnt1[NCH*NR] | iter: hpb[P*FD] }
    char* ws = (char*)d_ws;
    size_t cnt_off = 0;
    size_t ofs_off = (cnt_off + (size_t)C * 4 + 255) & ~(size_t)255;
    size_t bst_off = (ofs_off + (size_t)(C + 1) * 4 + 255) & ~(size_t)255;
    size_t el_off  = (bst_off + (size_t)(NR + 1) * 4 + 255) & ~(size_t)255;
    size_t hcb_off = (el_off + (size_t)E * 4 + 255) & ~(size_t)255;
    size_t uni_off = (hcb_off + (size_t)C * FD * 2 + 255) & ~(size_t)255;
    size_t ebuf_b  = (size_t)E * 8;
    size_t cnt1_b  = (size_t)NCH * NR * 4;
    size_t hpb_b   = (size_t)P * FD * 2;
    size_t bld_b   = ebuf_b + cnt1_b;
    size_t uni_b   = (hpb_b > bld_b) ? hpb_b : bld_b;

    int*    counts  = (int*)(ws + cnt_off);
    int*    offsets = (int*)(ws + ofs_off);
    int*    bstart  = (int*)(ws + bst_off);
    int*    elist   = (int*)(ws + el_off);
    __bf16* hcb     = (__bf16*)(ws + hcb_off);
    int2*   ebuf    = (int2*)(ws + uni_off);
    int*    cnt1    = (int*)(ws + uni_off + ebuf_b);
    __bf16* hpb     = (__bf16*)(ws + uni_off);   // time-disjoint w/ ebuf/cnt1

    const bool mfma_ok = (P % 64 == 0) && (C <= 65536);
    const bool tier1 = mfma_ok && (ws_size >= uni_off + uni_b);

    dim3 pb(256), pg((P + 255) / 256);
    dim3 cb(256), cg((C + 255) / 256);

    if (tier1) {
        hipMemcpyAsync(h_p, paths, (size_t)P * FD * sizeof(float),
                       hipMemcpyDeviceToDevice, stream);
        int n8 = C * FD / 8;
        hc_init_kernel<<<(n8 + 255) / 256, 256, 0, stream>>>(channels, h_c, hcb, n8);

        bincount_kernel<<<NCH, 256, 0, stream>>>(p2c, cnt1, E, NR);
        scan_chunks_kernel<<<1, 256, 0, stream>>>(cnt1, bstart, NR, E);
        binfill_kernel<<<NCH, 256, 0, stream>>>(p2c, cnt1, ebuf, E, NR);
        buckcount_kernel<<<NR, 256, 0, stream>>>(ebuf, bstart, counts, C);
        scan_offsets_kernel<<<1, 1024, 0, stream>>>(counts, offsets, C);
        buckfill_kernel<<<NR, 256, 0, stream>>>(ebuf, bstart, offsets, elist, C);

        dim3 mg(P / 64), mb(256);
        dim3 xg((C + 63) / 64), xb(256);
        for (int it = 0; it < NITER; it++) {
            path_fused_kernel<<<mg, mb, 0, stream>>>(h_p, p2c, hcb,
                                                     Wih1, Whh1, bih1, bhh1, hpb);
            gchannel_kernel<<<xg, xb, 0, stream>>>(hpb, offsets, elist, h_c,
                                                   Wih2, Whh2, bih2, bhh2, hcb, C);
        }
    } else {
        float* agg0 = (float*)d_ws;
        size_t aggf_b = (size_t)C * FD * sizeof(float);
        hipMemcpyAsync(h_p, paths, (size_t)P * FD * sizeof(float),
                       hipMemcpyDeviceToDevice, stream);
        hipMemcpyAsync(h_c, channels, (size_t)C * FD * sizeof(float),
                       hipMemcpyDeviceToDevice, stream);
        for (int it = 0; it < NITER; it++) {
            path_update_kernel<<<pg, pb, 0, stream>>>(h_c, h_p, p2c,
                                                      Wih1, Whh1, bih1, bhh1, P);
            hipMemsetAsync(agg0, 0, aggf_b, stream);
            scatter_agg_atomic_kernel<<<pg, pb, 0, stream>>>(h_p, p2c, agg0, P);
            channel_update_kernel<<<cg, cb, 0, stream>>>(agg0, h_c,
                                                         Wih2, Whh2, bih2, bhh2, C);
        }
    }
}

// Round 10
// 630.552 us; speedup vs baseline: 6.5796x; 1.1331x over previous
//
#include <hip/hip_runtime.h>

#define FD 32
#define KNB 8
#define NITER 5
#define NCH 256   // edge chunks for the binning passes

typedef __bf16 bf16x8 __attribute__((ext_vector_type(8)));
typedef float  f32x4  __attribute__((ext_vector_type(4)));

// Fast HW transcendentals: v_rcp_f32 / v_exp_f32 instead of IEEE div expansion.
__device__ __forceinline__ float frcp_(float a) { return __builtin_amdgcn_rcpf(a); }
__device__ __forceinline__ float fexp2_(float a) { return __builtin_amdgcn_exp2f(a); }
__device__ __forceinline__ float sigmoidf_(float a) {
    return frcp_(1.0f + fexp2_(a * -1.44269504f));
}
__device__ __forceinline__ float tanhf_(float a) {
    return 1.0f - 2.0f * frcp_(fexp2_(a * 2.88539009f) + 1.0f);
}

// ---------------- atomic-free CSR build (two-level counting sort) -----------

__global__ __launch_bounds__(256) void bincount_kernel(
    const int* __restrict__ p2c, int* __restrict__ cnt1, int E, int NR)
{
    __shared__ int lds[256];
    int b = blockIdx.x;
    int per = (E + NCH - 1) / NCH;
    int s0 = b * per, s1 = s0 + per; if (s1 > E) s1 = E;
    int t = threadIdx.x;
    if (t < NR) lds[t] = 0;
    __syncthreads();
    for (int e = s0 + t; e < s1; e += 256)
        atomicAdd(&lds[p2c[e] >> 8], 1);
    __syncthreads();
    if (t < NR) cnt1[(size_t)b * NR + t] = lds[t];
}

__global__ __launch_bounds__(256) void scan_chunks_kernel(
    int* __restrict__ cnt1, int* __restrict__ bstart, int NR, int E)
{
    __shared__ int tt[256];
    int t = threadIdx.x;
    int tot = 0;
    if (t < NR)
        for (int b = 0; b < NCH; b++) tot += cnt1[(size_t)b * NR + t];
    tt[t] = (t < NR) ? tot : 0;
    __syncthreads();
    for (int d = 1; d < 256; d <<= 1) {
        int v = (t >= d) ? tt[t - d] : 0;
        __syncthreads();
        tt[t] += v;
        __syncthreads();
    }
    if (t < NR) {
        int run = (t == 0) ? 0 : tt[t - 1];
        bstart[t] = run;
        for (int b = 0; b < NCH; b++) {
            int v = cnt1[(size_t)b * NR + t];
            cnt1[(size_t)b * NR + t] = run;
            run += v;
        }
        if (t == NR - 1) bstart[NR] = E;
    }
}

__global__ __launch_bounds__(256) void binfill_kernel(
    const int* __restrict__ p2c, const int* __restrict__ cnt1,
    int2* __restrict__ ebuf, int E, int NR)
{
    __shared__ int cur[256];
    int b = blockIdx.x;
    int per = (E + NCH - 1) / NCH;
    int s0 = b * per, s1 = s0 + per; if (s1 > E) s1 = E;
    int t = threadIdx.x;
    if (t < NR) cur[t] = cnt1[(size_t)b * NR + t];
    __syncthreads();
    for (int e = s0 + t; e < s1; e += 256) {
        int ch = p2c[e];
        int slot = atomicAdd(&cur[ch >> 8], 1);
        ebuf[slot] = make_int2(e >> 3, ch);   // (path id, channel); KNB == 8
    }
}

__global__ __launch_bounds__(256) void buckcount_kernel(
    const int2* __restrict__ ebuf, const int* __restrict__ bstart,
    int* __restrict__ counts, int C)
{
    __shared__ int h[256];
    int r = blockIdx.x;
    int t = threadIdx.x;
    h[t] = 0;
    __syncthreads();
    int s0 = bstart[r], s1 = bstart[r + 1];
    for (int i = s0 + t; i < s1; i += 256)
        atomicAdd(&h[ebuf[i].y & 255], 1);
    __syncthreads();
    int c = (r << 8) + t;
    if (c < C) counts[c] = h[t];
}

__global__ __launch_bounds__(1024) void scan_offsets_kernel(
    const int* __restrict__ counts, int* __restrict__ offsets, int C)
{
    __shared__ int part[1024];
    int t = threadIdx.x;
    int chunk = (C + 1023) >> 10;
    int base = t * chunk;
    int end = base + chunk; if (end > C) end = C;
    int s = 0;
    for (int i = base; i < end; i++) s += counts[i];
    part[t] = s;
    __syncthreads();
    for (int d = 1; d < 1024; d <<= 1) {
        int v = (t >= d) ? part[t - d] : 0;
        __syncthreads();
        part[t] += v;
        __syncthreads();
    }
    int run = (t == 0) ? 0 : part[t - 1];
    for (int i = base; i < end; i++) {
        offsets[i] = run;
        run += counts[i];
    }
    if (t == 1023) offsets[C] = part[1023];
}

__global__ __launch_bounds__(256) void buckfill_kernel(
    const int2* __restrict__ ebuf, const int* __restrict__ bstart,
    const int* __restrict__ offsets, int* __restrict__ elist, int C)
{
    __shared__ int cur[256];
    int r = blockIdx.x;
    int t = threadIdx.x;
    int c = (r << 8) + t;
    cur[t] = (c < C) ? offsets[c] : 0;
    __syncthreads();
    int s0 = bstart[r], s1 = bstart[r + 1];
    for (int i = s0 + t; i < s1; i += 256) {
        int2 v = ebuf[i];
        int slot = atomicAdd(&cur[v.y & 255], 1);
        elist[slot] = v.x;
    }
}

// ---------------- init: h_c copy + bf16 shadow in one pass ------------------

__global__ __launch_bounds__(256) void hc_init_kernel(
    const float* __restrict__ src, float* __restrict__ h_c,
    __bf16* __restrict__ dst, int n8)
{
    int i = blockIdx.x * blockDim.x + threadIdx.x;
    if (i >= n8) return;
    const float4* s = (const float4*)(src + (size_t)i * 8);
    float4 u = s[0], v = s[1];
    float4* d = (float4*)(h_c + (size_t)i * 8);
    d[0] = u; d[1] = v;
    bf16x8 o;
    o[0]=(__bf16)u.x; o[1]=(__bf16)u.y; o[2]=(__bf16)u.z; o[3]=(__bf16)u.w;
    o[4]=(__bf16)v.x; o[5]=(__bf16)v.y; o[6]=(__bf16)v.z; o[7]=(__bf16)v.w;
    ((bf16x8*)dst)[i] = o;
}

// ---------------- weight pre-conversion (once per launch) -------------------
// W1 -> bf16; W2 -> hi/lo bf16 split (for the split-precision channel MFMA).
__global__ __launch_bounds__(256) void wconv_kernel(
    const float* __restrict__ W1i, const float* __restrict__ W1h,
    const float* __restrict__ W2i, const float* __restrict__ W2h,
    __bf16* __restrict__ w1x, __bf16* __restrict__ w1h,
    __bf16* __restrict__ w2xH, __bf16* __restrict__ w2xL,
    __bf16* __restrict__ w2hH, __bf16* __restrict__ w2hL)
{
    int i = blockIdx.x * blockDim.x + threadIdx.x;
    if (i >= 96 * FD) return;
    w1x[i] = (__bf16)W1i[i];
    w1h[i] = (__bf16)W1h[i];
    float c = W2i[i]; __bf16 ch = (__bf16)c;
    w2xH[i] = ch; w2xL[i] = (__bf16)(c - (float)ch);
    float d = W2h[i]; __bf16 dh = (__bf16)d;
    w2hH[i] = dh; w2hL[i] = (__bf16)(d - (float)dh);
}

// ---------------- fused path kernel v3 (grid-stride, preconv weights) -------
#define HLP 40   // bf16 row pitch: 80 B, 16B-aligned
__global__ __launch_bounds__(256) void path_fused_kernel(
    float* __restrict__ h_p, const int* __restrict__ p2c,
    const __bf16* __restrict__ hcb,
    const __bf16* __restrict__ w1x, const __bf16* __restrict__ w1h,
    const float* __restrict__ bih, const float* __restrict__ bhh,
    __bf16* __restrict__ hpb, int ntiles)
{
    __shared__ __bf16 hl[64][HLP];
    const int tid  = threadIdx.x;
    const int wid  = tid >> 6;
    const int lane = tid & 63;
    const int c    = lane & 15;
    const int kg   = lane >> 4;

    // B fragments + biases: ONCE per wave (pre-converted bf16, 16B loads)
    bf16x8 Bx[6], Bh[6];
    #pragma unroll
    for (int t = 0; t < 6; t++) {
        Bx[t] = *(const bf16x8*)(w1x + (size_t)(16*t + c) * FD + 8*kg);
        Bh[t] = *(const bf16x8*)(w1h + (size_t)(16*t + c) * FD + 8*kg);
    }
    f32x4 cin_rz[4], cin_xn[2], cin_hn[2];
    #pragma unroll
    for (int t = 0; t < 4; t++) {
        float b = bih[16*t + c] + bhh[16*t + c];
        cin_rz[t] = (f32x4){b, b, b, b};
    }
    #pragma unroll
    for (int fi = 0; fi < 2; fi++) {
        float bi = bih[64 + 16*fi + c];
        float bh = bhh[64 + 16*fi + c];
        cin_xn[fi] = (f32x4){bi, bi, bi, bi};
        cin_hn[fi] = (f32x4){bh, bh, bh, bh};
    }

    for (int tile = blockIdx.x; tile < ntiles; tile += gridDim.x) {
        const int blk0 = tile * 64;
        const int rbase = blk0 + wid*16 + 4*kg;

        // load h: f32 regs (D-layout) + bf16 LDS copy (wave-local rows)
        float hD[8];
        #pragma unroll
        for (int q = 0; q < 4; q++)
            #pragma unroll
            for (int fi = 0; fi < 2; fi++) {
                float v = h_p[(size_t)(rbase + q) * FD + c + 16*fi];
                hD[2*q + fi] = v;
                hl[wid*16 + 4*kg + q][c + 16*fi] = (__bf16)v;
            }

        // prefetch all 8 steps' x-fragments
        const int pA = blk0 + wid*16 + c;
        const int4* pp = (const int4*)(p2c + (size_t)pA * KNB);
        int4 ia = pp[0], ib = pp[1];
        int idxA[KNB] = {ia.x, ia.y, ia.z, ia.w, ib.x, ib.y, ib.z, ib.w};
        bf16x8 Ax[KNB];
        #pragma unroll
        for (int k = 0; k < KNB; k++)
            Ax[k] = *(const bf16x8*)(hcb + (size_t)idxA[k] * FD + 8*kg);

        const int rowA = wid*16 + c;
        #pragma unroll
        for (int k = 0; k < KNB; k++) {
            bf16x8 Ah = *(const bf16x8*)&hl[rowA][8*kg];

            f32x4 arz[4], xn[2], hn[2];
            #pragma unroll
            for (int t = 0; t < 4; t++) {
                arz[t] = __builtin_amdgcn_mfma_f32_16x16x32_bf16(Ax[k], Bx[t], cin_rz[t], 0, 0, 0);
                arz[t] = __builtin_amdgcn_mfma_f32_16x16x32_bf16(Ah,    Bh[t], arz[t],   0, 0, 0);
            }
            #pragma unroll
            for (int fi = 0; fi < 2; fi++) {
                xn[fi] = __builtin_amdgcn_mfma_f32_16x16x32_bf16(Ax[k], Bx[4+fi], cin_xn[fi], 0, 0, 0);
                hn[fi] = __builtin_amdgcn_mfma_f32_16x16x32_bf16(Ah,    Bh[4+fi], cin_hn[fi], 0, 0, 0);
            }

            #pragma unroll
            for (int q = 0; q < 4; q++)
                #pragma unroll
                for (int fi = 0; fi < 2; fi++) {
                    float r = sigmoidf_(arz[fi][q]);
                    float z = sigmoidf_(arz[2+fi][q]);
                    float n = tanhf_(fmaf(r, hn[fi][q], xn[fi][q]));
                    float ho = hD[2*q + fi];
                    float hv = fmaf(z, ho - n, n);
                    hD[2*q + fi] = hv;
                    hl[wid*16 + 4*kg + q][c + 16*fi] = (__bf16)hv;
                }
        }

        // f32 h_p from own regs (no cross-wave data)
        #pragma unroll
        for (int q = 0; q < 4; q++)
            #pragma unroll
            for (int fi = 0; fi < 2; fi++)
                h_p[(size_t)(rbase + q) * FD + c + 16*fi] = hD[2*q + fi];

        // bf16 shadow from LDS reads ALL 64 rows -> needs all waves done
        __syncthreads();
        {
            int r  = tid >> 2;
            int c0 = (tid & 3) * 8;
            bf16x8 o = *(const bf16x8*)&hl[r][c0];
            *(bf16x8*)(hpb + ((size_t)(blk0 + r)) * FD + c0) = o;
        }
        __syncthreads();   // protect hl before next tile overwrites it
    }
}

// ---------------- fused gather + channel GRU2 (MFMA, preconv weights) -------
__global__ __launch_bounds__(256) void gchannel_kernel(
    const __bf16* __restrict__ hpb, const int* __restrict__ offsets,
    const int* __restrict__ elist, float* __restrict__ h_c,
    const __bf16* __restrict__ w2xH, const __bf16* __restrict__ w2xL,
    const __bf16* __restrict__ w2hH, const __bf16* __restrict__ w2hL,
    const float* __restrict__ bih, const float* __restrict__ bhh,
    __bf16* __restrict__ hcb, int C)
{
    const int tid  = threadIdx.x;
    const int wid  = tid >> 6;
    const int lane = tid & 63;
    const int c    = lane & 15;
    const int kg   = lane >> 4;
    const int blk0 = blockIdx.x * 64;
    const int chA  = blk0 + wid*16 + c;

    // gather: xr[8] = sum of incident bf16 path rows (f32 accum)
    float xr[8];
    #pragma unroll
    for (int j = 0; j < 8; j++) xr[j] = 0.f;
    int s = 0, e = 0;
    if (chA < C) { s = offsets[chA]; e = offsets[chA + 1]; }
    int i = s;
    for (; i + 2 <= e; i += 2) {
        int e0 = elist[i], e1 = elist[i + 1];
        bf16x8 v0 = *(const bf16x8*)(hpb + (size_t)e0 * FD + 8*kg);
        bf16x8 v1 = *(const bf16x8*)(hpb + (size_t)e1 * FD + 8*kg);
        #pragma unroll
        for (int j = 0; j < 8; j++) xr[j] += (float)v0[j] + (float)v1[j];
    }
    if (i < e) {
        bf16x8 v0 = *(const bf16x8*)(hpb + (size_t)elist[i] * FD + 8*kg);
        #pragma unroll
        for (int j = 0; j < 8; j++) xr[j] += (float)v0[j];
    }

    float hr[8];
    if (chA < C) {
        const float4* ha = (const float4*)(h_c + (size_t)chA * FD + 8*kg);
        float4 h0 = ha[0], h1 = ha[1];
        hr[0]=h0.x; hr[1]=h0.y; hr[2]=h0.z; hr[3]=h0.w;
        hr[4]=h1.x; hr[5]=h1.y; hr[6]=h1.z; hr[7]=h1.w;
    } else {
        #pragma unroll
        for (int j = 0; j < 8; j++) hr[j] = 0.f;
    }
    bf16x8 AxH, AxL, AhH, AhL;
    #pragma unroll
    for (int j = 0; j < 8; j++) {
        __bf16 xh = (__bf16)xr[j]; AxH[j] = xh; AxL[j] = (__bf16)(xr[j] - (float)xh);
        __bf16 hh = (__bf16)hr[j]; AhH[j] = hh; AhL[j] = (__bf16)(hr[j] - (float)hh);
    }

    f32x4 cin_rz[4], cin_xn[2], cin_hn[2];
    #pragma unroll
    for (int t = 0; t < 4; t++) {
        float b = bih[16*t + c] + bhh[16*t + c];
        cin_rz[t] = (f32x4){b, b, b, b};
    }
    #pragma unroll
    for (int fi = 0; fi < 2; fi++) {
        float bi = bih[64 + 16*fi + c];
        float bh = bhh[64 + 16*fi + c];
        cin_xn[fi] = (f32x4){bi, bi, bi, bi};
        cin_hn[fi] = (f32x4){bh, bh, bh, bh};
    }

    f32x4 arz[4], xn[2], hn[2];
    #pragma unroll
    for (int t = 0; t < 4; t++) {
        size_t wo = (size_t)(16*t + c) * FD + 8*kg;
        bf16x8 BxH_ = *(const bf16x8*)(w2xH + wo);
        bf16x8 BxL_ = *(const bf16x8*)(w2xL + wo);
        bf16x8 BhH_ = *(const bf16x8*)(w2hH + wo);
        bf16x8 BhL_ = *(const bf16x8*)(w2hL + wo);
        f32x4 a = cin_rz[t];
        a = __builtin_amdgcn_mfma_f32_16x16x32_bf16(AxH, BxH_, a, 0, 0, 0);
        a = __builtin_amdgcn_mfma_f32_16x16x32_bf16(AxH, BxL_, a, 0, 0, 0);
        a = __builtin_amdgcn_mfma_f32_16x16x32_bf16(AxL, BxH_, a, 0, 0, 0);
        a = __builtin_amdgcn_mfma_f32_16x16x32_bf16(AhH, BhH_, a, 0, 0, 0);
        a = __builtin_amdgcn_mfma_f32_16x16x32_bf16(AhH, BhL_, a, 0, 0, 0);
        a = __builtin_amdgcn_mfma_f32_16x16x32_bf16(AhL, BhH_, a, 0, 0, 0);
        arz[t] = a;
    }
    #pragma unroll
    for (int fi = 0; fi < 2; fi++) {
        size_t wo = (size_t)(16*(4+fi) + c) * FD + 8*kg;
        bf16x8 BxH_ = *(const bf16x8*)(w2xH + wo);
        bf16x8 BxL_ = *(const bf16x8*)(w2xL + wo);
        bf16x8 BhH_ = *(const bf16x8*)(w2hH + wo);
        bf16x8 BhL_ = *(const bf16x8*)(w2hL + wo);
        f32x4 a = cin_xn[fi];
        a = __builtin_amdgcn_mfma_f32_16x16x32_bf16(AxH, BxH_, a, 0, 0, 0);
        a = __builtin_amdgcn_mfma_f32_16x16x32_bf16(AxH, BxL_, a, 0, 0, 0);
        a = __builtin_amdgcn_mfma_f32_16x16x32_bf16(AxL, BxH_, a, 0, 0, 0);
        xn[fi] = a;
        f32x4 b = cin_hn[fi];
        b = __builtin_amdgcn_mfma_f32_16x16x32_bf16(AhH, BhH_, b, 0, 0, 0);
        b = __builtin_amdgcn_mfma_f32_16x16x32_bf16(AhH, BhL_, b, 0, 0, 0);
        b = __builtin_amdgcn_mfma_f32_16x16x32_bf16(AhL, BhH_, b, 0, 0, 0);
        hn[fi] = b;
    }

    #pragma unroll
    for (int q = 0; q < 4; q++) {
        int row = blk0 + wid*16 + 4*kg + q;
        if (row < C) {
            #pragma unroll
            for (int fi = 0; fi < 2; fi++) {
                float r = sigmoidf_(arz[fi][q]);
                float z = sigmoidf_(arz[2+fi][q]);
                float n = tanhf_(fmaf(r, hn[fi][q], xn[fi][q]));
                float ho = h_c[(size_t)row * FD + c + 16*fi];
                float hv = fmaf(z, ho - n, n);
                h_c[(size_t)row * FD + c + 16*fi] = hv;
                hcb[(size_t)row * FD + c + 16*fi] = (__bf16)hv;
            }
        }
    }
}

// ---------------- fallback kernels (atomic path) ----------------------------

__global__ __launch_bounds__(256) void path_update_kernel(
    const float* __restrict__ h_c, float* __restrict__ h_p,
    const int* __restrict__ p2c,
    const float* __restrict__ Wih, const float* __restrict__ Whh,
    const float* __restrict__ bih, const float* __restrict__ bhh, int P)
{
    int p = blockIdx.x * blockDim.x + threadIdx.x;
    if (p >= P) return;

    float h[FD];
    const float4* hp4 = (const float4*)(h_p + (size_t)p * FD);
    #pragma unroll
    for (int i = 0; i < FD / 4; i++) {
        float4 v = hp4[i];
        h[4*i] = v.x; h[4*i+1] = v.y; h[4*i+2] = v.z; h[4*i+3] = v.w;
    }

    int idx[KNB];
    const int4* pi = (const int4*)(p2c + (size_t)p * KNB);
    int4 i0 = pi[0], i1 = pi[1];
    idx[0]=i0.x; idx[1]=i0.y; idx[2]=i0.z; idx[3]=i0.w;
    idx[4]=i1.x; idx[5]=i1.y; idx[6]=i1.z; idx[7]=i1.w;

    for (int k = 0; k < KNB; k++) {
        float x[FD];
        const float4* xr = (const float4*)(h_c + (size_t)idx[k] * FD);
        #pragma unroll
        for (int i = 0; i < FD / 4; i++) {
            float4 v = xr[i];
            x[4*i] = v.x; x[4*i+1] = v.y; x[4*i+2] = v.z; x[4*i+3] = v.w;
        }

        float hn[FD];
        #pragma unroll 4
        for (int j = 0; j < FD; j++) {
            float air = bih[j],        ahr = bhh[j];
            float aiz = bih[FD + j],   ahz = bhh[FD + j];
            float ain = bih[2*FD + j], ahn = bhh[2*FD + j];
            #pragma unroll
            for (int i = 0; i < FD; i++) {
                air = fmaf(Wih[j*FD + i],          x[i], air);
                ahr = fmaf(Whh[j*FD + i],          h[i], ahr);
                aiz = fmaf(Wih[(FD + j)*FD + i],   x[i], aiz);
                ahz = fmaf(Whh[(FD + j)*FD + i],   h[i], ahz);
                ain = fmaf(Wih[(2*FD + j)*FD + i], x[i], ain);
                ahn = fmaf(Whh[(2*FD + j)*FD + i], h[i], ahn);
            }
            float r = sigmoidf_(air + ahr);
            float z = sigmoidf_(aiz + ahz);
            float n = tanhf_(ain + r * ahn);
            hn[j] = (1.0f - z) * n + z * h[j];
        }
        #pragma unroll
        for (int j = 0; j < FD; j++) h[j] = hn[j];
    }

    float4* hpw = (float4*)(h_p + (size_t)p * FD);
    #pragma unroll
    for (int i = 0; i < FD / 4; i++) {
        float4 v;
        v.x = h[4*i]; v.y = h[4*i+1]; v.z = h[4*i+2]; v.w = h[4*i+3];
        hpw[i] = v;
    }
}

__global__ __launch_bounds__(256) void scatter_agg_atomic_kernel(
    const float* __restrict__ h_p, const int* __restrict__ p2c,
    float* __restrict__ agg, int P)
{
    int p = blockIdx.x * blockDim.x + threadIdx.x;
    if (p >= P) return;
    const float* hr = h_p + (size_t)p * FD;
    #pragma unroll
    for (int k = 0; k < KNB; k++) {
        int c = p2c[(size_t)p * KNB + k];
        float* ar = agg + (size_t)c * FD;
        #pragma unroll
        for (int i = 0; i < FD; i++) atomicAdd(ar + i, hr[i]);
    }
}

__global__ __launch_bounds__(256) void channel_update_kernel(
    const float* __restrict__ agg, float* __restrict__ h_c,
    const float* __restrict__ Wih, const float* __restrict__ Whh,
    const float* __restrict__ bih, const float* __restrict__ bhh, int C)
{
    int c = blockIdx.x * blockDim.x + threadIdx.x;
    if (c >= C) return;

    float h[FD], x[FD];
    const float4* hr = (const float4*)(h_c + (size_t)c * FD);
    const float4* xr = (const float4*)(agg + (size_t)c * FD);
    #pragma unroll
    for (int i = 0; i < FD / 4; i++) {
        float4 v = hr[i];
        h[4*i] = v.x; h[4*i+1] = v.y; h[4*i+2] = v.z; h[4*i+3] = v.w;
        float4 w = xr[i];
        x[4*i] = w.x; x[4*i+1] = w.y; x[4*i+2] = w.z; x[4*i+3] = w.w;
    }

    float hn[FD];
    #pragma unroll 4
    for (int j = 0; j < FD; j++) {
        float air = bih[j],        ahr = bhh[j];
        float aiz = bih[FD + j],   ahz = bhh[FD + j];
        float ain = bih[2*FD + j], ahn = bhh[2*FD + j];
        #pragma unroll
        for (int i = 0; i < FD; i++) {
            air = fmaf(Wih[j*FD + i],          x[i], air);
            ahr = fmaf(Whh[j*FD + i],          h[i], ahr);
            aiz = fmaf(Wih[(FD + j)*FD + i],   x[i], aiz);
            ahz = fmaf(Whh[(FD + j)*FD + i],   h[i], ahz);
            ain = fmaf(Wih[(2*FD + j)*FD + i], x[i], ain);
            ahn = fmaf(Whh[(2*FD + j)*FD + i], h[i], ahn);
        }
        float r = sigmoidf_(air + ahr);
        float z = sigmoidf_(aiz + ahz);
        float n = tanhf_(ain + r * ahn);
        hn[j] = (1.0f - z) * n + z * h[j];
    }

    float4* hw = (float4*)(h_c + (size_t)c * FD);
    #pragma unroll
    for (int i = 0; i < FD / 4; i++) {
        float4 v;
        v.x = hn[4*i]; v.y = hn[4*i+1]; v.z = hn[4*i+2]; v.w = hn[4*i+3];
        hw[i] = v;
    }
}

extern "C" void kernel_launch(void* const* d_in, const int* in_sizes, int n_in,
                              void* d_out, int out_size, void* d_ws, size_t ws_size,
                              hipStream_t stream) {
    const float* paths    = (const float*)d_in[0];
    const float* channels = (const float*)d_in[1];
    const int*   p2c      = (const int*)d_in[2];
    const float* Wih1 = (const float*)d_in[3];
    const float* Whh1 = (const float*)d_in[4];
    const float* bih1 = (const float*)d_in[5];
    const float* bhh1 = (const float*)d_in[6];
    const float* Wih2 = (const float*)d_in[7];
    const float* Whh2 = (const float*)d_in[8];
    const float* bih2 = (const float*)d_in[9];
    const float* bhh2 = (const float*)d_in[10];

    const int P = in_sizes[0] / FD;     // 200000
    const int C = in_sizes[1] / FD;     // 50000
    const int E = P * KNB;              // 1.6M edges
    const int NR = (C + 255) >> 8;      // 196 buckets

    float* h_p = (float*)d_out;                  // [P*FD]
    float* h_c = h_p + (size_t)P * FD;           // [C*FD]

    // ws: counts[C] | offsets[C+1] | bstart[NR+1] | elist[E] | hcb | wbufs(6) |
    //     UNION{ build: ebuf[E](int2)+cnt1[NCH*NR] | iter: hpb[P*FD] }
    char* ws = (char*)d_ws;
    size_t cnt_off = 0;
    size_t ofs_off = (cnt_off + (size_t)C * 4 + 255) & ~(size_t)255;
    size_t bst_off = (ofs_off + (size_t)(C + 1) * 4 + 255) & ~(size_t)255;
    size_t el_off  = (bst_off + (size_t)(NR + 1) * 4 + 255) & ~(size_t)255;
    size_t hcb_off = (el_off + (size_t)E * 4 + 255) & ~(size_t)255;
    size_t wb_off  = (hcb_off + (size_t)C * FD * 2 + 255) & ~(size_t)255;
    size_t wmat_b  = (size_t)96 * FD * 2;                 // 6 KB per matrix
    size_t uni_off = (wb_off + 6 * wmat_b + 255) & ~(size_t)255;
    size_t ebuf_b  = (size_t)E * 8;
    size_t cnt1_b  = (size_t)NCH * NR * 4;
    size_t hpb_b   = (size_t)P * FD * 2;
    size_t bld_b   = ebuf_b + cnt1_b;
    size_t uni_b   = (hpb_b > bld_b) ? hpb_b : bld_b;

    int*    counts  = (int*)(ws + cnt_off);
    int*    offsets = (int*)(ws + ofs_off);
    int*    bstart  = (int*)(ws + bst_off);
    int*    elist   = (int*)(ws + el_off);
    __bf16* hcb     = (__bf16*)(ws + hcb_off);
    __bf16* w1x     = (__bf16*)(ws + wb_off);
    __bf16* w1h     = (__bf16*)(ws + wb_off + 1 * wmat_b);
    __bf16* w2xH    = (__bf16*)(ws + wb_off + 2 * wmat_b);
    __bf16* w2xL    = (__bf16*)(ws + wb_off + 3 * wmat_b);
    __bf16* w2hH    = (__bf16*)(ws + wb_off + 4 * wmat_b);
    __bf16* w2hL    = (__bf16*)(ws + wb_off + 5 * wmat_b);
    int2*   ebuf    = (int2*)(ws + uni_off);
    int*    cnt1    = (int*)(ws + uni_off + ebuf_b);
    __bf16* hpb     = (__bf16*)(ws + uni_off);   // time-disjoint w/ ebuf/cnt1

    const bool mfma_ok = (P % 64 == 0) && (C <= 65536);
    const bool tier1 = mfma_ok && (ws_size >= uni_off + uni_b);

    dim3 pb(256), pg((P + 255) / 256);
    dim3 cb(256), cg((C + 255) / 256);

    if (tier1) {
        hipMemcpyAsync(h_p, paths, (size_t)P * FD * sizeof(float),
                       hipMemcpyDeviceToDevice, stream);
        int n8 = C * FD / 8;
        hc_init_kernel<<<(n8 + 255) / 256, 256, 0, stream>>>(channels, h_c, hcb, n8);
        wconv_kernel<<<(96 * FD + 255) / 256, 256, 0, stream>>>(
            Wih1, Whh1, Wih2, Whh2, w1x, w1h, w2xH, w2xL, w2hH, w2hL);

        bincount_kernel<<<NCH, 256, 0, stream>>>(p2c, cnt1, E, NR);
        scan_chunks_kernel<<<1, 256, 0, stream>>>(cnt1, bstart, NR, E);
        binfill_kernel<<<NCH, 256, 0, stream>>>(p2c, cnt1, ebuf, E, NR);
        buckcount_kernel<<<NR, 256, 0, stream>>>(ebuf, bstart, counts, C);
        scan_offsets_kernel<<<1, 1024, 0, stream>>>(counts, offsets, C);
        buckfill_kernel<<<NR, 256, 0, stream>>>(ebuf, bstart, offsets, elist, C);

        const int ntiles = P / 64;                 // 3125
        int pgrid = ntiles < 1024 ? ntiles : 1024; // 4096 waves = residency fill
        dim3 xg((C + 63) / 64), xb(256);
        for (int it = 0; it < NITER; it++) {
            path_fused_kernel<<<pgrid, 256, 0, stream>>>(h_p, p2c, hcb,
                                                         w1x, w1h, bih1, bhh1,
                                                         hpb, ntiles);
            gchannel_kernel<<<xg, xb, 0, stream>>>(hpb, offsets, elist, h_c,
                                                   w2xH, w2xL, w2hH, w2hL,
                                                   bih2, bhh2, hcb, C);
        }
    } else {
        float* agg0 = (float*)d_ws;
        size_t aggf_b = (size_t)C * FD * sizeof(float);
        hipMemcpyAsync(h_p, paths, (size_t)P * FD * sizeof(float),
                       hipMemcpyDeviceToDevice, stream);
        hipMemcpyAsync(h_c, channels, (size_t)C * FD * sizeof(float),
                       hipMemcpyDeviceToDevice, stream);
        for (int it = 0; it < NITER; it++) {
            path_update_kernel<<<pg, pb, 0, stream>>>(h_c, h_p, p2c,
                                                      Wih1, Whh1, bih1, bhh1, P);
            hipMemsetAsync(agg0, 0, aggf_b, stream);
            scatter_agg_atomic_kernel<<<pg, pb, 0, stream>>>(h_p, p2c, agg0, P);
            channel_update_kernel<<<cg, cb, 0, stream>>>(agg0, h_c,
                                                         Wih2, Whh2, bih2, bhh2, C);
        }
    }
}

// Round 11
// 557.989 us; speedup vs baseline: 7.4353x; 1.1300x over previous
//
#include <hip/hip_runtime.h>

#define FD 32
#define KNB 8
#define NITER 5
#define NCH 256   // edge chunks for the binning passes

typedef __bf16 bf16x8 __attribute__((ext_vector_type(8)));
typedef float  f32x4  __attribute__((ext_vector_type(4)));

// Fast HW transcendentals: v_rcp_f32 / v_exp_f32 instead of IEEE div expansion.
__device__ __forceinline__ float frcp_(float a) { return __builtin_amdgcn_rcpf(a); }
__device__ __forceinline__ float fexp2_(float a) { return __builtin_amdgcn_exp2f(a); }
__device__ __forceinline__ float sigmoidf_(float a) {
    return frcp_(1.0f + fexp2_(a * -1.44269504f));
}
__device__ __forceinline__ float tanhf_(float a) {
    return 1.0f - 2.0f * frcp_(fexp2_(a * 2.88539009f) + 1.0f);
}

// ---------------- atomic-free CSR build (two-level counting sort) -----------
// bucket r = channel >> 8; NR = ceil(C/256) buckets.

__global__ __launch_bounds__(256) void bincount_kernel(
    const int* __restrict__ p2c, int* __restrict__ cnt1, int E, int NR)
{
    __shared__ int lds[256];
    int b = blockIdx.x;
    int per = (E + NCH - 1) / NCH;
    int s0 = b * per, s1 = s0 + per; if (s1 > E) s1 = E;
    int t = threadIdx.x;
    if (t < NR) lds[t] = 0;
    __syncthreads();
    for (int e = s0 + t; e < s1; e += 256)
        atomicAdd(&lds[p2c[e] >> 8], 1);
    __syncthreads();
    if (t < NR) cnt1[(size_t)b * NR + t] = lds[t];
}

__global__ __launch_bounds__(256) void scan_chunks_kernel(
    int* __restrict__ cnt1, int* __restrict__ bstart, int NR, int E)
{
    __shared__ int tt[256];
    int t = threadIdx.x;
    int tot = 0;
    if (t < NR)
        for (int b = 0; b < NCH; b++) tot += cnt1[(size_t)b * NR + t];
    tt[t] = (t < NR) ? tot : 0;
    __syncthreads();
    for (int d = 1; d < 256; d <<= 1) {
        int v = (t >= d) ? tt[t - d] : 0;
        __syncthreads();
        tt[t] += v;
        __syncthreads();
    }
    if (t < NR) {
        int run = (t == 0) ? 0 : tt[t - 1];
        bstart[t] = run;
        for (int b = 0; b < NCH; b++) {
            int v = cnt1[(size_t)b * NR + t];
            cnt1[(size_t)b * NR + t] = run;
            run += v;
        }
        if (t == NR - 1) bstart[NR] = E;
    }
}

__global__ __launch_bounds__(256) void binfill_kernel(
    const int* __restrict__ p2c, const int* __restrict__ cnt1,
    int2* __restrict__ ebuf, int E, int NR)
{
    __shared__ int cur[256];
    int b = blockIdx.x;
    int per = (E + NCH - 1) / NCH;
    int s0 = b * per, s1 = s0 + per; if (s1 > E) s1 = E;
    int t = threadIdx.x;
    if (t < NR) cur[t] = cnt1[(size_t)b * NR + t];
    __syncthreads();
    for (int e = s0 + t; e < s1; e += 256) {
        int ch = p2c[e];
        int slot = atomicAdd(&cur[ch >> 8], 1);
        ebuf[slot] = make_int2(e >> 3, ch);   // (path id, channel); KNB == 8
    }
}

// buckscan: per-bucket channel histogram + in-LDS exclusive scan.
// offsets[c] = rank base within bucket (bucket-global base added by addback);
// bsum[r] = bucket total. All global accesses coalesced.
__global__ __launch_bounds__(256) void buckscan_kernel(
    const int2* __restrict__ ebuf, const int* __restrict__ bstart,
    int* __restrict__ offsets, int* __restrict__ bsum, int C)
{
    __shared__ int h[256];
    __shared__ int sc[256];
    int r = blockIdx.x;
    int t = threadIdx.x;
    h[t] = 0;
    __syncthreads();
    int s0 = bstart[r], s1 = bstart[r + 1];
    for (int i = s0 + t; i < s1; i += 256)
        atomicAdd(&h[ebuf[i].y & 255], 1);
    __syncthreads();
    int mine = h[t];
    sc[t] = mine;
    __syncthreads();
    #pragma unroll
    for (int d = 1; d < 256; d <<= 1) {
        int v = (t >= d) ? sc[t - d] : 0;
        __syncthreads();
        sc[t] += v;
        __syncthreads();
    }
    int c = (r << 8) + t;
    if (c < C) offsets[c] = sc[t] - mine;   // exclusive within bucket
    if (t == 255) bsum[r] = sc[255];
}

// scan_bsums: single tiny block; NR <= 256 elements, all in LDS.
__global__ __launch_bounds__(256) void scan_bsums_kernel(
    const int* __restrict__ bsum, int* __restrict__ bbase,
    int* __restrict__ offsets, int NR, int C, int E)
{
    __shared__ int sc[256];
    int t = threadIdx.x;
    int mine = (t < NR) ? bsum[t] : 0;
    sc[t] = mine;
    __syncthreads();
    #pragma unroll
    for (int d = 1; d < 256; d <<= 1) {
        int v = (t >= d) ? sc[t - d] : 0;
        __syncthreads();
        sc[t] += v;
        __syncthreads();
    }
    if (t < NR) bbase[t] = sc[t] - mine;
    if (t == 0) offsets[C] = E;
}

// addback: offsets[c] += bucket base (coalesced).
__global__ __launch_bounds__(256) void addback_kernel(
    int* __restrict__ offsets, const int* __restrict__ bbase, int C)
{
    int c = blockIdx.x * blockDim.x + threadIdx.x;
    if (c < C) offsets[c] += bbase[c >> 8];
}

__global__ __launch_bounds__(256) void buckfill_kernel(
    const int2* __restrict__ ebuf, const int* __restrict__ bstart,
    const int* __restrict__ offsets, int* __restrict__ elist, int C)
{
    __shared__ int cur[256];
    int r = blockIdx.x;
    int t = threadIdx.x;
    int c = (r << 8) + t;
    cur[t] = (c < C) ? offsets[c] : 0;
    __syncthreads();
    int s0 = bstart[r], s1 = bstart[r + 1];
    for (int i = s0 + t; i < s1; i += 256) {
        int2 v = ebuf[i];
        int slot = atomicAdd(&cur[v.y & 255], 1);
        elist[slot] = v.x;
    }
}

// ---------------- init: h_c copy + bf16 shadow in one pass ------------------

__global__ __launch_bounds__(256) void hc_init_kernel(
    const float* __restrict__ src, float* __restrict__ h_c,
    __bf16* __restrict__ dst, int n8)
{
    int i = blockIdx.x * blockDim.x + threadIdx.x;
    if (i >= n8) return;
    const float4* s = (const float4*)(src + (size_t)i * 8);
    float4 u = s[0], v = s[1];
    float4* d = (float4*)(h_c + (size_t)i * 8);
    d[0] = u; d[1] = v;
    bf16x8 o;
    o[0]=(__bf16)u.x; o[1]=(__bf16)u.y; o[2]=(__bf16)u.z; o[3]=(__bf16)u.w;
    o[4]=(__bf16)v.x; o[5]=(__bf16)v.y; o[6]=(__bf16)v.z; o[7]=(__bf16)v.w;
    ((bf16x8*)dst)[i] = o;
}

// ---------------- weight pre-conversion (once per launch) -------------------
__global__ __launch_bounds__(256) void wconv_kernel(
    const float* __restrict__ W1i, const float* __restrict__ W1h,
    const float* __restrict__ W2i, const float* __restrict__ W2h,
    __bf16* __restrict__ w1x, __bf16* __restrict__ w1h,
    __bf16* __restrict__ w2xH, __bf16* __restrict__ w2xL,
    __bf16* __restrict__ w2hH, __bf16* __restrict__ w2hL)
{
    int i = blockIdx.x * blockDim.x + threadIdx.x;
    if (i >= 96 * FD) return;
    w1x[i] = (__bf16)W1i[i];
    w1h[i] = (__bf16)W1h[i];
    float c = W2i[i]; __bf16 ch = (__bf16)c;
    w2xH[i] = ch; w2xL[i] = (__bf16)(c - (float)ch);
    float d = W2h[i]; __bf16 dh = (__bf16)d;
    w2hH[i] = dh; w2hL[i] = (__bf16)(d - (float)dh);
}

// ---------------- fused path kernel v3 (grid-stride, preconv weights) -------
#define HLP 40   // bf16 row pitch: 80 B, 16B-aligned
__global__ __launch_bounds__(256) void path_fused_kernel(
    float* __restrict__ h_p, const int* __restrict__ p2c,
    const __bf16* __restrict__ hcb,
    const __bf16* __restrict__ w1x, const __bf16* __restrict__ w1h,
    const float* __restrict__ bih, const float* __restrict__ bhh,
    __bf16* __restrict__ hpb, int ntiles)
{
    __shared__ __bf16 hl[64][HLP];
    const int tid  = threadIdx.x;
    const int wid  = tid >> 6;
    const int lane = tid & 63;
    const int c    = lane & 15;
    const int kg   = lane >> 4;

    bf16x8 Bx[6], Bh[6];
    #pragma unroll
    for (int t = 0; t < 6; t++) {
        Bx[t] = *(const bf16x8*)(w1x + (size_t)(16*t + c) * FD + 8*kg);
        Bh[t] = *(const bf16x8*)(w1h + (size_t)(16*t + c) * FD + 8*kg);
    }
    f32x4 cin_rz[4], cin_xn[2], cin_hn[2];
    #pragma unroll
    for (int t = 0; t < 4; t++) {
        float b = bih[16*t + c] + bhh[16*t + c];
        cin_rz[t] = (f32x4){b, b, b, b};
    }
    #pragma unroll
    for (int fi = 0; fi < 2; fi++) {
        float bi = bih[64 + 16*fi + c];
        float bh = bhh[64 + 16*fi + c];
        cin_xn[fi] = (f32x4){bi, bi, bi, bi};
        cin_hn[fi] = (f32x4){bh, bh, bh, bh};
    }

    for (int tile = blockIdx.x; tile < ntiles; tile += gridDim.x) {
        const int blk0 = tile * 64;
        const int rbase = blk0 + wid*16 + 4*kg;

        float hD[8];
        #pragma unroll
        for (int q = 0; q < 4; q++)
            #pragma unroll
            for (int fi = 0; fi < 2; fi++) {
                float v = h_p[(size_t)(rbase + q) * FD + c + 16*fi];
                hD[2*q + fi] = v;
                hl[wid*16 + 4*kg + q][c + 16*fi] = (__bf16)v;
            }

        const int pA = blk0 + wid*16 + c;
        const int4* pp = (const int4*)(p2c + (size_t)pA * KNB);
        int4 ia = pp[0], ib = pp[1];
        int idxA[KNB] = {ia.x, ia.y, ia.z, ia.w, ib.x, ib.y, ib.z, ib.w};
        bf16x8 Ax[KNB];
        #pragma unroll
        for (int k = 0; k < KNB; k++)
            Ax[k] = *(const bf16x8*)(hcb + (size_t)idxA[k] * FD + 8*kg);

        const int rowA = wid*16 + c;
        #pragma unroll
        for (int k = 0; k < KNB; k++) {
            bf16x8 Ah = *(const bf16x8*)&hl[rowA][8*kg];

            f32x4 arz[4], xn[2], hn[2];
            #pragma unroll
            for (int t = 0; t < 4; t++) {
                arz[t] = __builtin_amdgcn_mfma_f32_16x16x32_bf16(Ax[k], Bx[t], cin_rz[t], 0, 0, 0);
                arz[t] = __builtin_amdgcn_mfma_f32_16x16x32_bf16(Ah,    Bh[t], arz[t],   0, 0, 0);
            }
            #pragma unroll
            for (int fi = 0; fi < 2; fi++) {
                xn[fi] = __builtin_amdgcn_mfma_f32_16x16x32_bf16(Ax[k], Bx[4+fi], cin_xn[fi], 0, 0, 0);
                hn[fi] = __builtin_amdgcn_mfma_f32_16x16x32_bf16(Ah,    Bh[4+fi], cin_hn[fi], 0, 0, 0);
            }

            #pragma unroll
            for (int q = 0; q < 4; q++)
                #pragma unroll
                for (int fi = 0; fi < 2; fi++) {
                    float r = sigmoidf_(arz[fi][q]);
                    float z = sigmoidf_(arz[2+fi][q]);
                    float n = tanhf_(fmaf(r, hn[fi][q], xn[fi][q]));
                    float ho = hD[2*q + fi];
                    float hv = fmaf(z, ho - n, n);
                    hD[2*q + fi] = hv;
                    hl[wid*16 + 4*kg + q][c + 16*fi] = (__bf16)hv;
                }
        }

        #pragma unroll
        for (int q = 0; q < 4; q++)
            #pragma unroll
            for (int fi = 0; fi < 2; fi++)
                h_p[(size_t)(rbase + q) * FD + c + 16*fi] = hD[2*q + fi];

        __syncthreads();
        {
            int r  = tid >> 2;
            int c0 = (tid & 3) * 8;
            bf16x8 o = *(const bf16x8*)&hl[r][c0];
            *(bf16x8*)(hpb + ((size_t)(blk0 + r)) * FD + c0) = o;
        }
        __syncthreads();
    }
}

// ---------------- fused gather + channel GRU2 (MFMA, preconv weights) -------
__global__ __launch_bounds__(256) void gchannel_kernel(
    const __bf16* __restrict__ hpb, const int* __restrict__ offsets,
    const int* __restrict__ elist, float* __restrict__ h_c,
    const __bf16* __restrict__ w2xH, const __bf16* __restrict__ w2xL,
    const __bf16* __restrict__ w2hH, const __bf16* __restrict__ w2hL,
    const float* __restrict__ bih, const float* __restrict__ bhh,
    __bf16* __restrict__ hcb, int C)
{
    const int tid  = threadIdx.x;
    const int wid  = tid >> 6;
    const int lane = tid & 63;
    const int c    = lane & 15;
    const int kg   = lane >> 4;
    const int blk0 = blockIdx.x * 64;
    const int chA  = blk0 + wid*16 + c;

    float xr[8];
    #pragma unroll
    for (int j = 0; j < 8; j++) xr[j] = 0.f;
    int s = 0, e = 0;
    if (chA < C) { s = offsets[chA]; e = offsets[chA + 1]; }
    int i = s;
    for (; i + 2 <= e; i += 2) {
        int e0 = elist[i], e1 = elist[i + 1];
        bf16x8 v0 = *(const bf16x8*)(hpb + (size_t)e0 * FD + 8*kg);
        bf16x8 v1 = *(const bf16x8*)(hpb + (size_t)e1 * FD + 8*kg);
        #pragma unroll
        for (int j = 0; j < 8; j++) xr[j] += (float)v0[j] + (float)v1[j];
    }
    if (i < e) {
        bf16x8 v0 = *(const bf16x8*)(hpb + (size_t)elist[i] * FD + 8*kg);
        #pragma unroll
        for (int j = 0; j < 8; j++) xr[j] += (float)v0[j];
    }

    float hr[8];
    if (chA < C) {
        const float4* ha = (const float4*)(h_c + (size_t)chA * FD + 8*kg);
        float4 h0 = ha[0], h1 = ha[1];
        hr[0]=h0.x; hr[1]=h0.y; hr[2]=h0.z; hr[3]=h0.w;
        hr[4]=h1.x; hr[5]=h1.y; hr[6]=h1.z; hr[7]=h1.w;
    } else {
        #pragma unroll
        for (int j = 0; j < 8; j++) hr[j] = 0.f;
    }
    bf16x8 AxH, AxL, AhH, AhL;
    #pragma unroll
    for (int j = 0; j < 8; j++) {
        __bf16 xh = (__bf16)xr[j]; AxH[j] = xh; AxL[j] = (__bf16)(xr[j] - (float)xh);
        __bf16 hh = (__bf16)hr[j]; AhH[j] = hh; AhL[j] = (__bf16)(hr[j] - (float)hh);
    }

    f32x4 cin_rz[4], cin_xn[2], cin_hn[2];
    #pragma unroll
    for (int t = 0; t < 4; t++) {
        float b = bih[16*t + c] + bhh[16*t + c];
        cin_rz[t] = (f32x4){b, b, b, b};
    }
    #pragma unroll
    for (int fi = 0; fi < 2; fi++) {
        float bi = bih[64 + 16*fi + c];
        float bh = bhh[64 + 16*fi + c];
        cin_xn[fi] = (f32x4){bi, bi, bi, bi};
        cin_hn[fi] = (f32x4){bh, bh, bh, bh};
    }

    f32x4 arz[4], xn[2], hn[2];
    #pragma unroll
    for (int t = 0; t < 4; t++) {
        size_t wo = (size_t)(16*t + c) * FD + 8*kg;
        bf16x8 BxH_ = *(const bf16x8*)(w2xH + wo);
        bf16x8 BxL_ = *(const bf16x8*)(w2xL + wo);
        bf16x8 BhH_ = *(const bf16x8*)(w2hH + wo);
        bf16x8 BhL_ = *(const bf16x8*)(w2hL + wo);
        f32x4 a = cin_rz[t];
        a = __builtin_amdgcn_mfma_f32_16x16x32_bf16(AxH, BxH_, a, 0, 0, 0);
        a = __builtin_amdgcn_mfma_f32_16x16x32_bf16(AxH, BxL_, a, 0, 0, 0);
        a = __builtin_amdgcn_mfma_f32_16x16x32_bf16(AxL, BxH_, a, 0, 0, 0);
        a = __builtin_amdgcn_mfma_f32_16x16x32_bf16(AhH, BhH_, a, 0, 0, 0);
        a = __builtin_amdgcn_mfma_f32_16x16x32_bf16(AhH, BhL_, a, 0, 0, 0);
        a = __builtin_amdgcn_mfma_f32_16x16x32_bf16(AhL, BhH_, a, 0, 0, 0);
        arz[t] = a;
    }
    #pragma unroll
    for (int fi = 0; fi < 2; fi++) {
        size_t wo = (size_t)(16*(4+fi) + c) * FD + 8*kg;
        bf16x8 BxH_ = *(const bf16x8*)(w2xH + wo);
        bf16x8 BxL_ = *(const bf16x8*)(w2xL + wo);
        bf16x8 BhH_ = *(const bf16x8*)(w2hH + wo);
        bf16x8 BhL_ = *(const bf16x8*)(w2hL + wo);
        f32x4 a = cin_xn[fi];
        a = __builtin_amdgcn_mfma_f32_16x16x32_bf16(AxH, BxH_, a, 0, 0, 0);
        a = __builtin_amdgcn_mfma_f32_16x16x32_bf16(AxH, BxL_, a, 0, 0, 0);
        a = __builtin_amdgcn_mfma_f32_16x16x32_bf16(AxL, BxH_, a, 0, 0, 0);
        xn[fi] = a;
        f32x4 b = cin_hn[fi];
        b = __builtin_amdgcn_mfma_f32_16x16x32_bf16(AhH, BhH_, b, 0, 0, 0);
        b = __builtin_amdgcn_mfma_f32_16x16x32_bf16(AhH, BhL_, b, 0, 0, 0);
        b = __builtin_amdgcn_mfma_f32_16x16x32_bf16(AhL, BhH_, b, 0, 0, 0);
        hn[fi] = b;
    }

    #pragma unroll
    for (int q = 0; q < 4; q++) {
        int row = blk0 + wid*16 + 4*kg + q;
        if (row < C) {
            #pragma unroll
            for (int fi = 0; fi < 2; fi++) {
                float r = sigmoidf_(arz[fi][q]);
                float z = sigmoidf_(arz[2+fi][q]);
                float n = tanhf_(fmaf(r, hn[fi][q], xn[fi][q]));
                float ho = h_c[(size_t)row * FD + c + 16*fi];
                float hv = fmaf(z, ho - n, n);
                h_c[(size_t)row * FD + c + 16*fi] = hv;
                hcb[(size_t)row * FD + c + 16*fi] = (__bf16)hv;
            }
        }
    }
}

// ---------------- fallback kernels (atomic path) ----------------------------

__global__ __launch_bounds__(256) void path_update_kernel(
    const float* __restrict__ h_c, float* __restrict__ h_p,
    const int* __restrict__ p2c,
    const float* __restrict__ Wih, const float* __restrict__ Whh,
    const float* __restrict__ bih, const float* __restrict__ bhh, int P)
{
    int p = blockIdx.x * blockDim.x + threadIdx.x;
    if (p >= P) return;

    float h[FD];
    const float4* hp4 = (const float4*)(h_p + (size_t)p * FD);
    #pragma unroll
    for (int i = 0; i < FD / 4; i++) {
        float4 v = hp4[i];
        h[4*i] = v.x; h[4*i+1] = v.y; h[4*i+2] = v.z; h[4*i+3] = v.w;
    }

    int idx[KNB];
    const int4* pi = (const int4*)(p2c + (size_t)p * KNB);
    int4 i0 = pi[0], i1 = pi[1];
    idx[0]=i0.x; idx[1]=i0.y; idx[2]=i0.z; idx[3]=i0.w;
    idx[4]=i1.x; idx[5]=i1.y; idx[6]=i1.z; idx[7]=i1.w;

    for (int k = 0; k < KNB; k++) {
        float x[FD];
        const float4* xr = (const float4*)(h_c + (size_t)idx[k] * FD);
        #pragma unroll
        for (int i = 0; i < FD / 4; i++) {
            float4 v = xr[i];
            x[4*i] = v.x; x[4*i+1] = v.y; x[4*i+2] = v.z; x[4*i+3] = v.w;
        }

        float hn[FD];
        #pragma unroll 4
        for (int j = 0; j < FD; j++) {
            float air = bih[j],        ahr = bhh[j];
            float aiz = bih[FD + j],   ahz = bhh[FD + j];
            float ain = bih[2*FD + j], ahn = bhh[2*FD + j];
            #pragma unroll
            for (int i = 0; i < FD; i++) {
                air = fmaf(Wih[j*FD + i],          x[i], air);
                ahr = fmaf(Whh[j*FD + i],          h[i], ahr);
                aiz = fmaf(Wih[(FD + j)*FD + i],   x[i], aiz);
                ahz = fmaf(Whh[(FD + j)*FD + i],   h[i], ahz);
                ain = fmaf(Wih[(2*FD + j)*FD + i], x[i], ain);
                ahn = fmaf(Whh[(2*FD + j)*FD + i], h[i], ahn);
            }
            float r = sigmoidf_(air + ahr);
            float z = sigmoidf_(aiz + ahz);
            float n = tanhf_(ain + r * ahn);
            hn[j] = (1.0f - z) * n + z * h[j];
        }
        #pragma unroll
        for (int j = 0; j < FD; j++) h[j] = hn[j];
    }

    float4* hpw = (float4*)(h_p + (size_t)p * FD);
    #pragma unroll
    for (int i = 0; i < FD / 4; i++) {
        float4 v;
        v.x = h[4*i]; v.y = h[4*i+1]; v.z = h[4*i+2]; v.w = h[4*i+3];
        hpw[i] = v;
    }
}

__global__ __launch_bounds__(256) void scatter_agg_atomic_kernel(
    const float* __restrict__ h_p, const int* __restrict__ p2c,
    float* __restrict__ agg, int P)
{
    int p = blockIdx.x * blockDim.x + threadIdx.x;
    if (p >= P) return;
    const float* hr = h_p + (size_t)p * FD;
    #pragma unroll
    for (int k = 0; k < KNB; k++) {
        int c = p2c[(size_t)p * KNB + k];
        float* ar = agg + (size_t)c * FD;
        #pragma unroll
        for (int i = 0; i < FD; i++) atomicAdd(ar + i, hr[i]);
    }
}

__global__ __launch_bounds__(256) void channel_update_kernel(
    const float* __restrict__ agg, float* __restrict__ h_c,
    const float* __restrict__ Wih, const float* __restrict__ Whh,
    const float* __restrict__ bih, const float* __restrict__ bhh, int C)
{
    int c = blockIdx.x * blockDim.x + threadIdx.x;
    if (c >= C) return;

    float h[FD], x[FD];
    const float4* hr = (const float4*)(h_c + (size_t)c * FD);
    const float4* xr = (const float4*)(agg + (size_t)c * FD);
    #pragma unroll
    for (int i = 0; i < FD / 4; i++) {
        float4 v = hr[i];
        h[4*i] = v.x; h[4*i+1] = v.y; h[4*i+2] = v.z; h[4*i+3] = v.w;
        float4 w = xr[i];
        x[4*i] = w.x; x[4*i+1] = w.y; x[4*i+2] = w.z; x[4*i+3] = w.w;
    }

    float hn[FD];
    #pragma unroll 4
    for (int j = 0; j < FD; j++) {
        float air = bih[j],        ahr = bhh[j];
        float aiz = bih[FD + j],   ahz = bhh[FD + j];
        float ain = bih[2*FD + j], ahn = bhh[2*FD + j];
        #pragma unroll
        for (int i = 0; i < FD; i++) {
            air = fmaf(Wih[j*FD + i],          x[i], air);
            ahr = fmaf(Whh[j*FD + i],          h[i], ahr);
            aiz = fmaf(Wih[(FD + j)*FD + i],   x[i], aiz);
            ahz = fmaf(Whh[(FD + j)*FD + i],   h[i], ahz);
            ain = fmaf(Wih[(2*FD + j)*FD + i], x[i], ain);
            ahn = fmaf(Whh[(2*FD + j)*FD + i], h[i], ahn);
        }
        float r = sigmoidf_(air + ahr);
        float z = sigmoidf_(aiz + ahz);
        float n = tanhf_(ain + r * ahn);
        hn[j] = (1.0f - z) * n + z * h[j];
    }

    float4* hw = (float4*)(h_c + (size_t)c * FD);
    #pragma unroll
    for (int i = 0; i < FD / 4; i++) {
        float4 v;
        v.x = hn[4*i]; v.y = hn[4*i+1]; v.z = hn[4*i+2]; v.w = hn[4*i+3];
        hw[i] = v;
    }
}

extern "C" void kernel_launch(void* const* d_in, const int* in_sizes, int n_in,
                              void* d_out, int out_size, void* d_ws, size_t ws_size,
                              hipStream_t stream) {
    const float* paths    = (const float*)d_in[0];
    const float* channels = (const float*)d_in[1];
    const int*   p2c      = (const int*)d_in[2];
    const float* Wih1 = (const float*)d_in[3];
    const float* Whh1 = (const float*)d_in[4];
    const float* bih1 = (const float*)d_in[5];
    const float* bhh1 = (const float*)d_in[6];
    const float* Wih2 = (const float*)d_in[7];
    const float* Whh2 = (const float*)d_in[8];
    const float* bih2 = (const float*)d_in[9];
    const float* bhh2 = (const float*)d_in[10];

    const int P = in_sizes[0] / FD;     // 200000
    const int C = in_sizes[1] / FD;     // 50000
    const int E = P * KNB;              // 1.6M edges
    const int NR = (C + 255) >> 8;      // 196 buckets

    float* h_p = (float*)d_out;                  // [P*FD]
    float* h_c = h_p + (size_t)P * FD;           // [C*FD]

    // ws: bsum[NR] bbase[NR] | offsets[C+1] | bstart[NR+1] | elist[E] | hcb |
    //     wbufs(6) | UNION{ build: ebuf[E](int2)+cnt1[NCH*NR] | iter: hpb }
    char* ws = (char*)d_ws;
    size_t bs_off  = 0;
    size_t ofs_off = (bs_off + (size_t)(2 * NR) * 4 + 255) & ~(size_t)255;
    size_t bst_off = (ofs_off + (size_t)(C + 1) * 4 + 255) & ~(size_t)255;
    size_t el_off  = (bst_off + (size_t)(NR + 1) * 4 + 255) & ~(size_t)255;
    size_t hcb_off = (el_off + (size_t)E * 4 + 255) & ~(size_t)255;
    size_t wb_off  = (hcb_off + (size_t)C * FD * 2 + 255) & ~(size_t)255;
    size_t wmat_b  = (size_t)96 * FD * 2;                 // 6 KB per matrix
    size_t uni_off = (wb_off + 6 * wmat_b + 255) & ~(size_t)255;
    size_t ebuf_b  = (size_t)E * 8;
    size_t cnt1_b  = (size_t)NCH * NR * 4;
    size_t hpb_b   = (size_t)P * FD * 2;
    size_t bld_b   = ebuf_b + cnt1_b;
    size_t uni_b   = (hpb_b > bld_b) ? hpb_b : bld_b;

    int*    bsum    = (int*)(ws + bs_off);
    int*    bbase   = bsum + NR;
    int*    offsets = (int*)(ws + ofs_off);
    int*    bstart  = (int*)(ws + bst_off);
    int*    elist   = (int*)(ws + el_off);
    __bf16* hcb     = (__bf16*)(ws + hcb_off);
    __bf16* w1x     = (__bf16*)(ws + wb_off);
    __bf16* w1h     = (__bf16*)(ws + wb_off + 1 * wmat_b);
    __bf16* w2xH    = (__bf16*)(ws + wb_off + 2 * wmat_b);
    __bf16* w2xL    = (__bf16*)(ws + wb_off + 3 * wmat_b);
    __bf16* w2hH    = (__bf16*)(ws + wb_off + 4 * wmat_b);
    __bf16* w2hL    = (__bf16*)(ws + wb_off + 5 * wmat_b);
    int2*   ebuf    = (int2*)(ws + uni_off);
    int*    cnt1    = (int*)(ws + uni_off + ebuf_b);
    __bf16* hpb     = (__bf16*)(ws + uni_off);   // time-disjoint w/ ebuf/cnt1

    const bool mfma_ok = (P % 64 == 0) && (C <= 65536);
    const bool tier1 = mfma_ok && (ws_size >= uni_off + uni_b);

    dim3 pb(256), pg((P + 255) / 256);
    dim3 cb(256), cg((C + 255) / 256);

    if (tier1) {
        hipMemcpyAsync(h_p, paths, (size_t)P * FD * sizeof(float),
                       hipMemcpyDeviceToDevice, stream);
        int n8 = C * FD / 8;
        hc_init_kernel<<<(n8 + 255) / 256, 256, 0, stream>>>(channels, h_c, hcb, n8);
        wconv_kernel<<<(96 * FD + 255) / 256, 256, 0, stream>>>(
            Wih1, Whh1, Wih2, Whh2, w1x, w1h, w2xH, w2xL, w2hH, w2hL);

        bincount_kernel<<<NCH, 256, 0, stream>>>(p2c, cnt1, E, NR);
        scan_chunks_kernel<<<1, 256, 0, stream>>>(cnt1, bstart, NR, E);
        binfill_kernel<<<NCH, 256, 0, stream>>>(p2c, cnt1, ebuf, E, NR);
        buckscan_kernel<<<NR, 256, 0, stream>>>(ebuf, bstart, offsets, bsum, C);
        scan_bsums_kernel<<<1, 256, 0, stream>>>(bsum, bbase, offsets, NR, C, E);
        addback_kernel<<<cg, cb, 0, stream>>>(offsets, bbase, C);
        buckfill_kernel<<<NR, 256, 0, stream>>>(ebuf, bstart, offsets, elist, C);

        const int ntiles = P / 64;                 // 3125
        int pgrid = ntiles < 1024 ? ntiles : 1024; // 4096 waves = residency fill
        dim3 xg((C + 63) / 64), xb(256);
        for (int it = 0; it < NITER; it++) {
            path_fused_kernel<<<pgrid, 256, 0, stream>>>(h_p, p2c, hcb,
                                                         w1x, w1h, bih1, bhh1,
                                                         hpb, ntiles);
            gchannel_kernel<<<xg, xb, 0, stream>>>(hpb, offsets, elist, h_c,
                                                   w2xH, w2xL, w2hH, w2hL,
                                                   bih2, bhh2, hcb, C);
        }
    } else {
        float* agg0 = (float*)d_ws;
        size_t aggf_b = (size_t)C * FD * sizeof(float);
        hipMemcpyAsync(h_p, paths, (size_t)P * FD * sizeof(float),
                       hipMemcpyDeviceToDevice, stream);
        hipMemcpyAsync(h_c, channels, (size_t)C * FD * sizeof(float),
                       hipMemcpyDeviceToDevice, stream);
        for (int it = 0; it < NITER; it++) {
            path_update_kernel<<<pg, pb, 0, stream>>>(h_c, h_p, p2c,
                                                      Wih1, Whh1, bih1, bhh1, P);
            hipMemsetAsync(agg0, 0, aggf_b, stream);
            scatter_agg_atomic_kernel<<<pg, pb, 0, stream>>>(h_p, p2c, agg0, P);
            channel_update_kernel<<<cg, cb, 0, stream>>>(agg0, h_c,
                                                         Wih2, Whh2, bih2, bhh2, C);
        }
    }
}

// Round 12
// 557.712 us; speedup vs baseline: 7.4390x; 1.0005x over previous
//
#include <hip/hip_runtime.h>

#define FD 32
#define KNB 8
#define NITER 5
#define NCH 256   // edge chunks for the binning passes

typedef __bf16 bf16x8 __attribute__((ext_vector_type(8)));
typedef float  f32x4  __attribute__((ext_vector_type(4)));

// Fast HW transcendentals: v_rcp_f32 / v_exp_f32 instead of IEEE div expansion.
__device__ __forceinline__ float frcp_(float a) { return __builtin_amdgcn_rcpf(a); }
__device__ __forceinline__ float fexp2_(float a) { return __builtin_amdgcn_exp2f(a); }
__device__ __forceinline__ float sigmoidf_(float a) {
    return frcp_(1.0f + fexp2_(a * -1.44269504f));
}
__device__ __forceinline__ float tanhf_(float a) {
    return 1.0f - 2.0f * frcp_(fexp2_(a * 2.88539009f) + 1.0f);
}

// ---------------- atomic-free CSR build (two-level counting sort) -----------
// bucket r = channel >> 8; NR = ceil(C/256) buckets.

__global__ __launch_bounds__(256) void bincount_kernel(
    const int* __restrict__ p2c, int* __restrict__ cnt1, int E, int NR)
{
    __shared__ int lds[256];
    int b = blockIdx.x;
    int per = (E + NCH - 1) / NCH;
    int s0 = b * per, s1 = s0 + per; if (s1 > E) s1 = E;
    int t = threadIdx.x;
    if (t < NR) lds[t] = 0;
    __syncthreads();
    for (int e = s0 + t; e < s1; e += 256)
        atomicAdd(&lds[p2c[e] >> 8], 1);
    __syncthreads();
    if (t < NR) cnt1[(size_t)b * NR + t] = lds[t];
}

__global__ __launch_bounds__(256) void scan_chunks_kernel(
    int* __restrict__ cnt1, int* __restrict__ bstart, int NR, int E)
{
    __shared__ int tt[256];
    int t = threadIdx.x;
    int tot = 0;
    if (t < NR)
        for (int b = 0; b < NCH; b++) tot += cnt1[(size_t)b * NR + t];
    tt[t] = (t < NR) ? tot : 0;
    __syncthreads();
    for (int d = 1; d < 256; d <<= 1) {
        int v = (t >= d) ? tt[t - d] : 0;
        __syncthreads();
        tt[t] += v;
        __syncthreads();
    }
    if (t < NR) {
        int run = (t == 0) ? 0 : tt[t - 1];
        bstart[t] = run;
        for (int b = 0; b < NCH; b++) {
            int v = cnt1[(size_t)b * NR + t];
            cnt1[(size_t)b * NR + t] = run;
            run += v;
        }
        if (t == NR - 1) bstart[NR] = E;
    }
}

__global__ __launch_bounds__(256) void binfill_kernel(
    const int* __restrict__ p2c, const int* __restrict__ cnt1,
    int2* __restrict__ ebuf, int E, int NR)
{
    __shared__ int cur[256];
    int b = blockIdx.x;
    int per = (E + NCH - 1) / NCH;
    int s0 = b * per, s1 = s0 + per; if (s1 > E) s1 = E;
    int t = threadIdx.x;
    if (t < NR) cur[t] = cnt1[(size_t)b * NR + t];
    __syncthreads();
    for (int e = s0 + t; e < s1; e += 256) {
        int ch = p2c[e];
        int slot = atomicAdd(&cur[ch >> 8], 1);
        ebuf[slot] = make_int2(e >> 3, ch);   // (path id, channel); KNB == 8
    }
}

// buckscan: per-bucket channel histogram + in-LDS exclusive scan.
__global__ __launch_bounds__(256) void buckscan_kernel(
    const int2* __restrict__ ebuf, const int* __restrict__ bstart,
    int* __restrict__ offsets, int* __restrict__ bsum, int C)
{
    __shared__ int h[256];
    __shared__ int sc[256];
    int r = blockIdx.x;
    int t = threadIdx.x;
    h[t] = 0;
    __syncthreads();
    int s0 = bstart[r], s1 = bstart[r + 1];
    for (int i = s0 + t; i < s1; i += 256)
        atomicAdd(&h[ebuf[i].y & 255], 1);
    __syncthreads();
    int mine = h[t];
    sc[t] = mine;
    __syncthreads();
    #pragma unroll
    for (int d = 1; d < 256; d <<= 1) {
        int v = (t >= d) ? sc[t - d] : 0;
        __syncthreads();
        sc[t] += v;
        __syncthreads();
    }
    int c = (r << 8) + t;
    if (c < C) offsets[c] = sc[t] - mine;   // exclusive within bucket
    if (t == 255) bsum[r] = sc[255];
}

__global__ __launch_bounds__(256) void scan_bsums_kernel(
    const int* __restrict__ bsum, int* __restrict__ bbase,
    int* __restrict__ offsets, int NR, int C, int E)
{
    __shared__ int sc[256];
    int t = threadIdx.x;
    int mine = (t < NR) ? bsum[t] : 0;
    sc[t] = mine;
    __syncthreads();
    #pragma unroll
    for (int d = 1; d < 256; d <<= 1) {
        int v = (t >= d) ? sc[t - d] : 0;
        __syncthreads();
        sc[t] += v;
        __syncthreads();
    }
    if (t < NR) bbase[t] = sc[t] - mine;
    if (t == 0) offsets[C] = E;
}

__global__ __launch_bounds__(256) void addback_kernel(
    int* __restrict__ offsets, const int* __restrict__ bbase, int C)
{
    int c = blockIdx.x * blockDim.x + threadIdx.x;
    if (c < C) offsets[c] += bbase[c >> 8];
}

__global__ __launch_bounds__(256) void buckfill_kernel(
    const int2* __restrict__ ebuf, const int* __restrict__ bstart,
    const int* __restrict__ offsets, int* __restrict__ elist, int C)
{
    __shared__ int cur[256];
    int r = blockIdx.x;
    int t = threadIdx.x;
    int c = (r << 8) + t;
    cur[t] = (c < C) ? offsets[c] : 0;
    __syncthreads();
    int s0 = bstart[r], s1 = bstart[r + 1];
    for (int i = s0 + t; i < s1; i += 256) {
        int2 v = ebuf[i];
        int slot = atomicAdd(&cur[v.y & 255], 1);
        elist[slot] = v.x;
    }
}

// ---------------- init: h_c copy + bf16 shadow in one pass ------------------

__global__ __launch_bounds__(256) void hc_init_kernel(
    const float* __restrict__ src, float* __restrict__ h_c,
    __bf16* __restrict__ dst, int n8)
{
    int i = blockIdx.x * blockDim.x + threadIdx.x;
    if (i >= n8) return;
    const float4* s = (const float4*)(src + (size_t)i * 8);
    float4 u = s[0], v = s[1];
    float4* d = (float4*)(h_c + (size_t)i * 8);
    d[0] = u; d[1] = v;
    bf16x8 o;
    o[0]=(__bf16)u.x; o[1]=(__bf16)u.y; o[2]=(__bf16)u.z; o[3]=(__bf16)u.w;
    o[4]=(__bf16)v.x; o[5]=(__bf16)v.y; o[6]=(__bf16)v.z; o[7]=(__bf16)v.w;
    ((bf16x8*)dst)[i] = o;
}

// ---------------- weight pre-conversion (once per launch) -------------------
__global__ __launch_bounds__(256) void wconv_kernel(
    const float* __restrict__ W1i, const float* __restrict__ W1h,
    const float* __restrict__ W2i, const float* __restrict__ W2h,
    __bf16* __restrict__ w1x, __bf16* __restrict__ w1h,
    __bf16* __restrict__ w2xH, __bf16* __restrict__ w2xL,
    __bf16* __restrict__ w2hH, __bf16* __restrict__ w2hL)
{
    int i = blockIdx.x * blockDim.x + threadIdx.x;
    if (i >= 96 * FD) return;
    w1x[i] = (__bf16)W1i[i];
    w1h[i] = (__bf16)W1h[i];
    float c = W2i[i]; __bf16 ch = (__bf16)c;
    w2xH[i] = ch; w2xL[i] = (__bf16)(c - (float)ch);
    float d = W2h[i]; __bf16 dh = (__bf16)d;
    w2hH[i] = dh; w2hL[i] = (__bf16)(d - (float)dh);
}

// ---------------- fused path kernel v4: DUAL-TILE software pipeline ---------
// Each block owns TWO 64-path tiles (A,B) with separate LDS buffers; the
// k-loop interleaves stepA(k); stepB(k) -> two independent dependency chains
// per wave hide each other's LDS/MFMA/transcendental latency.
#define HLP 40   // bf16 row pitch: 80 B, 16B-aligned

// one GRU step for one tile (all names static -> registers)
#define GRU_STEP(hl_, hD_, Axk_)                                               \
    {                                                                          \
        bf16x8 Ah = *(const bf16x8*)&hl_[rowA][8*kg];                          \
        f32x4 arz[4], xn[2], hn[2];                                            \
        _Pragma("unroll")                                                      \
        for (int t = 0; t < 4; t++) {                                          \
            arz[t] = __builtin_amdgcn_mfma_f32_16x16x32_bf16(Axk_, Bx[t], cin_rz[t], 0, 0, 0); \
            arz[t] = __builtin_amdgcn_mfma_f32_16x16x32_bf16(Ah,   Bh[t], arz[t],    0, 0, 0); \
        }                                                                      \
        _Pragma("unroll")                                                      \
        for (int fi = 0; fi < 2; fi++) {                                       \
            xn[fi] = __builtin_amdgcn_mfma_f32_16x16x32_bf16(Axk_, Bx[4+fi], cin_xn[fi], 0, 0, 0); \
            hn[fi] = __builtin_amdgcn_mfma_f32_16x16x32_bf16(Ah,   Bh[4+fi], cin_hn[fi], 0, 0, 0); \
        }                                                                      \
        _Pragma("unroll")                                                      \
        for (int q = 0; q < 4; q++)                                            \
            _Pragma("unroll")                                                  \
            for (int fi = 0; fi < 2; fi++) {                                   \
                float r = sigmoidf_(arz[fi][q]);                               \
                float z = sigmoidf_(arz[2+fi][q]);                             \
                float n = tanhf_(fmaf(r, hn[fi][q], xn[fi][q]));               \
                float ho = hD_[2*q + fi];                                      \
                float hv = fmaf(z, ho - n, n);                                 \
                hD_[2*q + fi] = hv;                                            \
                hl_[wid*16 + 4*kg + q][c + 16*fi] = (__bf16)hv;                \
            }                                                                  \
    }

__global__ __launch_bounds__(256) void path_fused_kernel(
    float* __restrict__ h_p, const int* __restrict__ p2c,
    const __bf16* __restrict__ hcb,
    const __bf16* __restrict__ w1x, const __bf16* __restrict__ w1h,
    const float* __restrict__ bih, const float* __restrict__ bhh,
    __bf16* __restrict__ hpb, int ntiles)
{
    __shared__ __bf16 hlA[64][HLP];
    __shared__ __bf16 hlB[64][HLP];
    const int tid  = threadIdx.x;
    const int wid  = tid >> 6;
    const int lane = tid & 63;
    const int c    = lane & 15;
    const int kg   = lane >> 4;

    bf16x8 Bx[6], Bh[6];
    #pragma unroll
    for (int t = 0; t < 6; t++) {
        Bx[t] = *(const bf16x8*)(w1x + (size_t)(16*t + c) * FD + 8*kg);
        Bh[t] = *(const bf16x8*)(w1h + (size_t)(16*t + c) * FD + 8*kg);
    }
    f32x4 cin_rz[4], cin_xn[2], cin_hn[2];
    #pragma unroll
    for (int t = 0; t < 4; t++) {
        float b = bih[16*t + c] + bhh[16*t + c];
        cin_rz[t] = (f32x4){b, b, b, b};
    }
    #pragma unroll
    for (int fi = 0; fi < 2; fi++) {
        float bi = bih[64 + 16*fi + c];
        float bh = bhh[64 + 16*fi + c];
        cin_xn[fi] = (f32x4){bi, bi, bi, bi};
        cin_hn[fi] = (f32x4){bh, bh, bh, bh};
    }

    const int tileA = blockIdx.x * 2;
    const int tileB = tileA + 1;
    const bool hasB = (tileB < ntiles);
    const int blk0A = tileA * 64;
    const int blk0B = tileB * 64;
    const int rbaseA = blk0A + wid*16 + 4*kg;
    const int rbaseB = blk0B + wid*16 + 4*kg;
    const int rowA = wid*16 + c;

    // tile A init
    float hDA[8];
    #pragma unroll
    for (int q = 0; q < 4; q++)
        #pragma unroll
        for (int fi = 0; fi < 2; fi++) {
            float v = h_p[(size_t)(rbaseA + q) * FD + c + 16*fi];
            hDA[2*q + fi] = v;
            hlA[wid*16 + 4*kg + q][c + 16*fi] = (__bf16)v;
        }
    const int pA = blk0A + wid*16 + c;
    const int4* ppA = (const int4*)(p2c + (size_t)pA * KNB);
    int4 iaA = ppA[0], ibA = ppA[1];
    int idxA[KNB] = {iaA.x, iaA.y, iaA.z, iaA.w, ibA.x, ibA.y, ibA.z, ibA.w};
    bf16x8 AxA[KNB];
    #pragma unroll
    for (int k = 0; k < KNB; k++)
        AxA[k] = *(const bf16x8*)(hcb + (size_t)idxA[k] * FD + 8*kg);

    // tile B init (block-uniform guard)
    float hDB[8];
    bf16x8 AxB[KNB];
    if (hasB) {
        #pragma unroll
        for (int q = 0; q < 4; q++)
            #pragma unroll
            for (int fi = 0; fi < 2; fi++) {
                float v = h_p[(size_t)(rbaseB + q) * FD + c + 16*fi];
                hDB[2*q + fi] = v;
                hlB[wid*16 + 4*kg + q][c + 16*fi] = (__bf16)v;
            }
        const int pB = blk0B + wid*16 + c;
        const int4* ppB = (const int4*)(p2c + (size_t)pB * KNB);
        int4 iaB = ppB[0], ibB = ppB[1];
        int idxB[KNB] = {iaB.x, iaB.y, iaB.z, iaB.w, ibB.x, ibB.y, ibB.z, ibB.w};
        #pragma unroll
        for (int k = 0; k < KNB; k++)
            AxB[k] = *(const bf16x8*)(hcb + (size_t)idxB[k] * FD + 8*kg);
    }

    #pragma unroll
    for (int k = 0; k < KNB; k++) {
        GRU_STEP(hlA, hDA, AxA[k]);
        if (hasB) GRU_STEP(hlB, hDB, AxB[k]);
    }

    // f32 h_p from own regs
    #pragma unroll
    for (int q = 0; q < 4; q++)
        #pragma unroll
        for (int fi = 0; fi < 2; fi++)
            h_p[(size_t)(rbaseA + q) * FD + c + 16*fi] = hDA[2*q + fi];
    if (hasB) {
        #pragma unroll
        for (int q = 0; q < 4; q++)
            #pragma unroll
            for (int fi = 0; fi < 2; fi++)
                h_p[(size_t)(rbaseB + q) * FD + c + 16*fi] = hDB[2*q + fi];
    }

    // bf16 shadow: epilogue reads all 64 rows -> one barrier
    __syncthreads();
    {
        int r  = tid >> 2;
        int c0 = (tid & 3) * 8;
        bf16x8 oA = *(const bf16x8*)&hlA[r][c0];
        *(bf16x8*)(hpb + ((size_t)(blk0A + r)) * FD + c0) = oA;
        if (hasB) {
            bf16x8 oB = *(const bf16x8*)&hlB[r][c0];
            *(bf16x8*)(hpb + ((size_t)(blk0B + r)) * FD + c0) = oB;
        }
    }
}

// ---------------- fused gather + channel GRU2 (MFMA, preconv weights) -------
__global__ __launch_bounds__(256) void gchannel_kernel(
    const __bf16* __restrict__ hpb, const int* __restrict__ offsets,
    const int* __restrict__ elist, float* __restrict__ h_c,
    const __bf16* __restrict__ w2xH, const __bf16* __restrict__ w2xL,
    const __bf16* __restrict__ w2hH, const __bf16* __restrict__ w2hL,
    const float* __restrict__ bih, const float* __restrict__ bhh,
    __bf16* __restrict__ hcb, int C)
{
    const int tid  = threadIdx.x;
    const int wid  = tid >> 6;
    const int lane = tid & 63;
    const int c    = lane & 15;
    const int kg   = lane >> 4;
    const int blk0 = blockIdx.x * 64;
    const int chA  = blk0 + wid*16 + c;

    // gather: 4-deep with dual accumulator banks (more loads in flight)
    float xr[8], xs[8];
    #pragma unroll
    for (int j = 0; j < 8; j++) { xr[j] = 0.f; xs[j] = 0.f; }
    int s = 0, e = 0;
    if (chA < C) { s = offsets[chA]; e = offsets[chA + 1]; }
    int i = s;
    for (; i + 4 <= e; i += 4) {
        int e0 = elist[i], e1 = elist[i + 1], e2 = elist[i + 2], e3 = elist[i + 3];
        bf16x8 v0 = *(const bf16x8*)(hpb + (size_t)e0 * FD + 8*kg);
        bf16x8 v1 = *(const bf16x8*)(hpb + (size_t)e1 * FD + 8*kg);
        bf16x8 v2 = *(const bf16x8*)(hpb + (size_t)e2 * FD + 8*kg);
        bf16x8 v3 = *(const bf16x8*)(hpb + (size_t)e3 * FD + 8*kg);
        #pragma unroll
        for (int j = 0; j < 8; j++) {
            xr[j] += (float)v0[j] + (float)v2[j];
            xs[j] += (float)v1[j] + (float)v3[j];
        }
    }
    for (; i < e; i++) {
        bf16x8 v0 = *(const bf16x8*)(hpb + (size_t)elist[i] * FD + 8*kg);
        #pragma unroll
        for (int j = 0; j < 8; j++) xr[j] += (float)v0[j];
    }
    #pragma unroll
    for (int j = 0; j < 8; j++) xr[j] += xs[j];

    float hr[8];
    if (chA < C) {
        const float4* ha = (const float4*)(h_c + (size_t)chA * FD + 8*kg);
        float4 h0 = ha[0], h1 = ha[1];
        hr[0]=h0.x; hr[1]=h0.y; hr[2]=h0.z; hr[3]=h0.w;
        hr[4]=h1.x; hr[5]=h1.y; hr[6]=h1.z; hr[7]=h1.w;
    } else {
        #pragma unroll
        for (int j = 0; j < 8; j++) hr[j] = 0.f;
    }
    bf16x8 AxH, AxL, AhH, AhL;
    #pragma unroll
    for (int j = 0; j < 8; j++) {
        __bf16 xh = (__bf16)xr[j]; AxH[j] = xh; AxL[j] = (__bf16)(xr[j] - (float)xh);
        __bf16 hh = (__bf16)hr[j]; AhH[j] = hh; AhL[j] = (__bf16)(hr[j] - (float)hh);
    }

    f32x4 cin_rz[4], cin_xn[2], cin_hn[2];
    #pragma unroll
    for (int t = 0; t < 4; t++) {
        float b = bih[16*t + c] + bhh[16*t + c];
        cin_rz[t] = (f32x4){b, b, b, b};
    }
    #pragma unroll
    for (int fi = 0; fi < 2; fi++) {
        float bi = bih[64 + 16*fi + c];
        float bh = bhh[64 + 16*fi + c];
        cin_xn[fi] = (f32x4){bi, bi, bi, bi};
        cin_hn[fi] = (f32x4){bh, bh, bh, bh};
    }

    f32x4 arz[4], xn[2], hn[2];
    #pragma unroll
    for (int t = 0; t < 4; t++) {
        size_t wo = (size_t)(16*t + c) * FD + 8*kg;
        bf16x8 BxH_ = *(const bf16x8*)(w2xH + wo);
        bf16x8 BxL_ = *(const bf16x8*)(w2xL + wo);
        bf16x8 BhH_ = *(const bf16x8*)(w2hH + wo);
        bf16x8 BhL_ = *(const bf16x8*)(w2hL + wo);
        f32x4 a = cin_rz[t];
        a = __builtin_amdgcn_mfma_f32_16x16x32_bf16(AxH, BxH_, a, 0, 0, 0);
        a = __builtin_amdgcn_mfma_f32_16x16x32_bf16(AxH, BxL_, a, 0, 0, 0);
        a = __builtin_amdgcn_mfma_f32_16x16x32_bf16(AxL, BxH_, a, 0, 0, 0);
        a = __builtin_amdgcn_mfma_f32_16x16x32_bf16(AhH, BhH_, a, 0, 0, 0);
        a = __builtin_amdgcn_mfma_f32_16x16x32_bf16(AhH, BhL_, a, 0, 0, 0);
        a = __builtin_amdgcn_mfma_f32_16x16x32_bf16(AhL, BhH_, a, 0, 0, 0);
        arz[t] = a;
    }
    #pragma unroll
    for (int fi = 0; fi < 2; fi++) {
        size_t wo = (size_t)(16*(4+fi) + c) * FD + 8*kg;
        bf16x8 BxH_ = *(const bf16x8*)(w2xH + wo);
        bf16x8 BxL_ = *(const bf16x8*)(w2xL + wo);
        bf16x8 BhH_ = *(const bf16x8*)(w2hH + wo);
        bf16x8 BhL_ = *(const bf16x8*)(w2hL + wo);
        f32x4 a = cin_xn[fi];
        a = __builtin_amdgcn_mfma_f32_16x16x32_bf16(AxH, BxH_, a, 0, 0, 0);
        a = __builtin_amdgcn_mfma_f32_16x16x32_bf16(AxH, BxL_, a, 0, 0, 0);
        a = __builtin_amdgcn_mfma_f32_16x16x32_bf16(AxL, BxH_, a, 0, 0, 0);
        xn[fi] = a;
        f32x4 b = cin_hn[fi];
        b = __builtin_amdgcn_mfma_f32_16x16x32_bf16(AhH, BhH_, b, 0, 0, 0);
        b = __builtin_amdgcn_mfma_f32_16x16x32_bf16(AhH, BhL_, b, 0, 0, 0);
        b = __builtin_amdgcn_mfma_f32_16x16x32_bf16(AhL, BhH_, b, 0, 0, 0);
        hn[fi] = b;
    }

    #pragma unroll
    for (int q = 0; q < 4; q++) {
        int row = blk0 + wid*16 + 4*kg + q;
        if (row < C) {
            #pragma unroll
            for (int fi = 0; fi < 2; fi++) {
                float r = sigmoidf_(arz[fi][q]);
                float z = sigmoidf_(arz[2+fi][q]);
                float n = tanhf_(fmaf(r, hn[fi][q], xn[fi][q]));
                float ho = h_c[(size_t)row * FD + c + 16*fi];
                float hv = fmaf(z, ho - n, n);
                h_c[(size_t)row * FD + c + 16*fi] = hv;
                hcb[(size_t)row * FD + c + 16*fi] = (__bf16)hv;
            }
        }
    }
}

// ---------------- fallback kernels (atomic path) ----------------------------

__global__ __launch_bounds__(256) void path_update_kernel(
    const float* __restrict__ h_c, float* __restrict__ h_p,
    const int* __restrict__ p2c,
    const float* __restrict__ Wih, const float* __restrict__ Whh,
    const float* __restrict__ bih, const float* __restrict__ bhh, int P)
{
    int p = blockIdx.x * blockDim.x + threadIdx.x;
    if (p >= P) return;

    float h[FD];
    const float4* hp4 = (const float4*)(h_p + (size_t)p * FD);
    #pragma unroll
    for (int i = 0; i < FD / 4; i++) {
        float4 v = hp4[i];
        h[4*i] = v.x; h[4*i+1] = v.y; h[4*i+2] = v.z; h[4*i+3] = v.w;
    }

    int idx[KNB];
    const int4* pi = (const int4*)(p2c + (size_t)p * KNB);
    int4 i0 = pi[0], i1 = pi[1];
    idx[0]=i0.x; idx[1]=i0.y; idx[2]=i0.z; idx[3]=i0.w;
    idx[4]=i1.x; idx[5]=i1.y; idx[6]=i1.z; idx[7]=i1.w;

    for (int k = 0; k < KNB; k++) {
        float x[FD];
        const float4* xr = (const float4*)(h_c + (size_t)idx[k] * FD);
        #pragma unroll
        for (int i = 0; i < FD / 4; i++) {
            float4 v = xr[i];
            x[4*i] = v.x; x[4*i+1] = v.y; x[4*i+2] = v.z; x[4*i+3] = v.w;
        }

        float hn[FD];
        #pragma unroll 4
        for (int j = 0; j < FD; j++) {
            float air = bih[j],        ahr = bhh[j];
            float aiz = bih[FD + j],   ahz = bhh[FD + j];
            float ain = bih[2*FD + j], ahn = bhh[2*FD + j];
            #pragma unroll
            for (int i = 0; i < FD; i++) {
                air = fmaf(Wih[j*FD + i],          x[i], air);
                ahr = fmaf(Whh[j*FD + i],          h[i], ahr);
                aiz = fmaf(Wih[(FD + j)*FD + i],   x[i], aiz);
                ahz = fmaf(Whh[(FD + j)*FD + i],   h[i], ahz);
                ain = fmaf(Wih[(2*FD + j)*FD + i], x[i], ain);
                ahn = fmaf(Whh[(2*FD + j)*FD + i], h[i], ahn);
            }
            float r = sigmoidf_(air + ahr);
            float z = sigmoidf_(aiz + ahz);
            float n = tanhf_(ain + r * ahn);
            hn[j] = (1.0f - z) * n + z * h[j];
        }
        #pragma unroll
        for (int j = 0; j < FD; j++) h[j] = hn[j];
    }

    float4* hpw = (float4*)(h_p + (size_t)p * FD);
    #pragma unroll
    for (int i = 0; i < FD / 4; i++) {
        float4 v;
        v.x = h[4*i]; v.y = h[4*i+1]; v.z = h[4*i+2]; v.w = h[4*i+3];
        hpw[i] = v;
    }
}

__global__ __launch_bounds__(256) void scatter_agg_atomic_kernel(
    const float* __restrict__ h_p, const int* __restrict__ p2c,
    float* __restrict__ agg, int P)
{
    int p = blockIdx.x * blockDim.x + threadIdx.x;
    if (p >= P) return;
    const float* hr = h_p + (size_t)p * FD;
    #pragma unroll
    for (int k = 0; k < KNB; k++) {
        int c = p2c[(size_t)p * KNB + k];
        float* ar = agg + (size_t)c * FD;
        #pragma unroll
        for (int i = 0; i < FD; i++) atomicAdd(ar + i, hr[i]);
    }
}

__global__ __launch_bounds__(256) void channel_update_kernel(
    const float* __restrict__ agg, float* __restrict__ h_c,
    const float* __restrict__ Wih, const float* __restrict__ Whh,
    const float* __restrict__ bih, const float* __restrict__ bhh, int C)
{
    int c = blockIdx.x * blockDim.x + threadIdx.x;
    if (c >= C) return;

    float h[FD], x[FD];
    const float4* hr = (const float4*)(h_c + (size_t)c * FD);
    const float4* xr = (const float4*)(agg + (size_t)c * FD);
    #pragma unroll
    for (int i = 0; i < FD / 4; i++) {
        float4 v = hr[i];
        h[4*i] = v.x; h[4*i+1] = v.y; h[4*i+2] = v.z; h[4*i+3] = v.w;
        float4 w = xr[i];
        x[4*i] = w.x; x[4*i+1] = w.y; x[4*i+2] = w.z; x[4*i+3] = w.w;
    }

    float hn[FD];
    #pragma unroll 4
    for (int j = 0; j < FD; j++) {
        float air = bih[j],        ahr = bhh[j];
        float aiz = bih[FD + j],   ahz = bhh[FD + j];
        float ain = bih[2*FD + j], ahn = bhh[2*FD + j];
        #pragma unroll
        for (int i = 0; i < FD; i++) {
            air = fmaf(Wih[j*FD + i],          x[i], air);
            ahr = fmaf(Whh[j*FD + i],          h[i], ahr);
            aiz = fmaf(Wih[(FD + j)*FD + i],   x[i], aiz);
            ahz = fmaf(Whh[(FD + j)*FD + i],   h[i], ahz);
            ain = fmaf(Wih[(2*FD + j)*FD + i], x[i], ain);
            ahn = fmaf(Whh[(2*FD + j)*FD + i], h[i], ahn);
        }
        float r = sigmoidf_(air + ahr);
        float z = sigmoidf_(aiz + ahz);
        float n = tanhf_(ain + r * ahn);
        hn[j] = (1.0f - z) * n + z * h[j];
    }

    float4* hw = (float4*)(h_c + (size_t)c * FD);
    #pragma unroll
    for (int i = 0; i < FD / 4; i++) {
        float4 v;
        v.x = hn[4*i]; v.y = hn[4*i+1]; v.z = hn[4*i+2]; v.w = hn[4*i+3];
        hw[i] = v;
    }
}

extern "C" void kernel_launch(void* const* d_in, const int* in_sizes, int n_in,
                              void* d_out, int out_size, void* d_ws, size_t ws_size,
                              hipStream_t stream) {
    const float* paths    = (const float*)d_in[0];
    const float* channels = (const float*)d_in[1];
    const int*   p2c      = (const int*)d_in[2];
    const float* Wih1 = (const float*)d_in[3];
    const float* Whh1 = (const float*)d_in[4];
    const float* bih1 = (const float*)d_in[5];
    const float* bhh1 = (const float*)d_in[6];
    const float* Wih2 = (const float*)d_in[7];
    const float* Whh2 = (const float*)d_in[8];
    const float* bih2 = (const float*)d_in[9];
    const float* bhh2 = (const float*)d_in[10];

    const int P = in_sizes[0] / FD;     // 200000
    const int C = in_sizes[1] / FD;     // 50000
    const int E = P * KNB;              // 1.6M edges
    const int NR = (C + 255) >> 8;      // 196 buckets

    float* h_p = (float*)d_out;                  // [P*FD]
    float* h_c = h_p + (size_t)P * FD;           // [C*FD]

    // ws: bsum[NR] bbase[NR] | offsets[C+1] | bstart[NR+1] | elist[E] | hcb |
    //     wbufs(6) | UNION{ build: ebuf[E](int2)+cnt1[NCH*NR] | iter: hpb }
    char* ws = (char*)d_ws;
    size_t bs_off  = 0;
    size_t ofs_off = (bs_off + (size_t)(2 * NR) * 4 + 255) & ~(size_t)255;
    size_t bst_off = (ofs_off + (size_t)(C + 1) * 4 + 255) & ~(size_t)255;
    size_t el_off  = (bst_off + (size_t)(NR + 1) * 4 + 255) & ~(size_t)255;
    size_t hcb_off = (el_off + (size_t)E * 4 + 255) & ~(size_t)255;
    size_t wb_off  = (hcb_off + (size_t)C * FD * 2 + 255) & ~(size_t)255;
    size_t wmat_b  = (size_t)96 * FD * 2;                 // 6 KB per matrix
    size_t uni_off = (wb_off + 6 * wmat_b + 255) & ~(size_t)255;
    size_t ebuf_b  = (size_t)E * 8;
    size_t cnt1_b  = (size_t)NCH * NR * 4;
    size_t hpb_b   = (size_t)P * FD * 2;
    size_t bld_b   = ebuf_b + cnt1_b;
    size_t uni_b   = (hpb_b > bld_b) ? hpb_b : bld_b;

    int*    bsum    = (int*)(ws + bs_off);
    int*    bbase   = bsum + NR;
    int*    offsets = (int*)(ws + ofs_off);
    int*    bstart  = (int*)(ws + bst_off);
    int*    elist   = (int*)(ws + el_off);
    __bf16* hcb     = (__bf16*)(ws + hcb_off);
    __bf16* w1x     = (__bf16*)(ws + wb_off);
    __bf16* w1h     = (__bf16*)(ws + wb_off + 1 * wmat_b);
    __bf16* w2xH    = (__bf16*)(ws + wb_off + 2 * wmat_b);
    __bf16* w2xL    = (__bf16*)(ws + wb_off + 3 * wmat_b);
    __bf16* w2hH    = (__bf16*)(ws + wb_off + 4 * wmat_b);
    __bf16* w2hL    = (__bf16*)(ws + wb_off + 5 * wmat_b);
    int2*   ebuf    = (int2*)(ws + uni_off);
    int*    cnt1    = (int*)(ws + uni_off + ebuf_b);
    __bf16* hpb     = (__bf16*)(ws + uni_off);   // time-disjoint w/ ebuf/cnt1

    const bool mfma_ok = (P % 64 == 0) && (C <= 65536);
    const bool tier1 = mfma_ok && (ws_size >= uni_off + uni_b);

    dim3 pb(256), pg((P + 255) / 256);
    dim3 cb(256), cg((C + 255) / 256);

    if (tier1) {
        hipMemcpyAsync(h_p, paths, (size_t)P * FD * sizeof(float),
                       hipMemcpyDeviceToDevice, stream);
        int n8 = C * FD / 8;
        hc_init_kernel<<<(n8 + 255) / 256, 256, 0, stream>>>(channels, h_c, hcb, n8);
        wconv_kernel<<<(96 * FD + 255) / 256, 256, 0, stream>>>(
            Wih1, Whh1, Wih2, Whh2, w1x, w1h, w2xH, w2xL, w2hH, w2hL);

        bincount_kernel<<<NCH, 256, 0, stream>>>(p2c, cnt1, E, NR);
        scan_chunks_kernel<<<1, 256, 0, stream>>>(cnt1, bstart, NR, E);
        binfill_kernel<<<NCH, 256, 0, stream>>>(p2c, cnt1, ebuf, E, NR);
        buckscan_kernel<<<NR, 256, 0, stream>>>(ebuf, bstart, offsets, bsum, C);
        scan_bsums_kernel<<<1, 256, 0, stream>>>(bsum, bbase, offsets, NR, C, E);
        addback_kernel<<<cg, cb, 0, stream>>>(offsets, bbase, C);
        buckfill_kernel<<<NR, 256, 0, stream>>>(ebuf, bstart, offsets, elist, C);

        const int ntiles = P / 64;                   // 3125
        const int pgrid  = (ntiles + 1) / 2;         // dual-tile blocks: 1563
        dim3 xg((C + 63) / 64), xb(256);
        for (int it = 0; it < NITER; it++) {
            path_fused_kernel<<<pgrid, 256, 0, stream>>>(h_p, p2c, hcb,
                                                         w1x, w1h, bih1, bhh1,
                                                         hpb, ntiles);
            gchannel_kernel<<<xg, xb, 0, stream>>>(hpb, offsets, elist, h_c,
                                                   w2xH, w2xL, w2hH, w2hL,
                                                   bih2, bhh2, hcb, C);
        }
    } else {
        float* agg0 = (float*)d_ws;
        size_t aggf_b = (size_t)C * FD * sizeof(float);
        hipMemcpyAsync(h_p, paths, (size_t)P * FD * sizeof(float),
                       hipMemcpyDeviceToDevice, stream);
        hipMemcpyAsync(h_c, channels, (size_t)C * FD * sizeof(float),
                       hipMemcpyDeviceToDevice, stream);
        for (int it = 0; it < NITER; it++) {
            path_update_kernel<<<pg, pb, 0, stream>>>(h_c, h_p, p2c,
                                                      Wih1, Whh1, bih1, bhh1, P);
            hipMemsetAsync(agg0, 0, aggf_b, stream);
            scatter_agg_atomic_kernel<<<pg, pb, 0, stream>>>(h_p, p2c, agg0, P);
            channel_update_kernel<<<cg, cb, 0, stream>>>(agg0, h_c,
                                                         Wih2, Whh2, bih2, bhh2, C);
        }
    }
}

// Round 13
// 537.777 us; speedup vs baseline: 7.7147x; 1.0371x over previous
//
#include <hip/hip_runtime.h>

#define FD 32
#define KNB 8
#define NITER 5
#define NCH 256   // edge chunks for the binning passes

typedef __bf16 bf16x8 __attribute__((ext_vector_type(8)));
typedef float  f32x4  __attribute__((ext_vector_type(4)));

// Fast HW transcendentals: v_rcp_f32 / v_exp_f32 instead of IEEE div expansion.
__device__ __forceinline__ float frcp_(float a) { return __builtin_amdgcn_rcpf(a); }
__device__ __forceinline__ float fexp2_(float a) { return __builtin_amdgcn_exp2f(a); }
__device__ __forceinline__ float sigmoidf_(float a) {
    return frcp_(1.0f + fexp2_(a * -1.44269504f));
}
__device__ __forceinline__ float tanhf_(float a) {
    return 1.0f - 2.0f * frcp_(fexp2_(a * 2.88539009f) + 1.0f);
}

// ---------------- atomic-free CSR build (two-level counting sort) -----------
// bucket r = channel >> 8; NR = ceil(C/256) buckets.

__global__ __launch_bounds__(256) void bincount_kernel(
    const int* __restrict__ p2c, int* __restrict__ cnt1, int E, int NR)
{
    __shared__ int lds[256];
    int b = blockIdx.x;
    int per = (E + NCH - 1) / NCH;
    int s0 = b * per, s1 = s0 + per; if (s1 > E) s1 = E;
    int t = threadIdx.x;
    if (t < NR) lds[t] = 0;
    __syncthreads();
    for (int e = s0 + t; e < s1; e += 256)
        atomicAdd(&lds[p2c[e] >> 8], 1);
    __syncthreads();
    if (t < NR) cnt1[(size_t)b * NR + t] = lds[t];
}

__global__ __launch_bounds__(256) void scan_chunks_kernel(
    int* __restrict__ cnt1, int* __restrict__ bstart, int NR, int E)
{
    __shared__ int tt[256];
    int t = threadIdx.x;
    int tot = 0;
    if (t < NR)
        for (int b = 0; b < NCH; b++) tot += cnt1[(size_t)b * NR + t];
    tt[t] = (t < NR) ? tot : 0;
    __syncthreads();
    for (int d = 1; d < 256; d <<= 1) {
        int v = (t >= d) ? tt[t - d] : 0;
        __syncthreads();
        tt[t] += v;
        __syncthreads();
    }
    if (t < NR) {
        int run = (t == 0) ? 0 : tt[t - 1];
        bstart[t] = run;
        for (int b = 0; b < NCH; b++) {
            int v = cnt1[(size_t)b * NR + t];
            cnt1[(size_t)b * NR + t] = run;
            run += v;
        }
        if (t == NR - 1) bstart[NR] = E;
    }
}

__global__ __launch_bounds__(256) void binfill_kernel(
    const int* __restrict__ p2c, const int* __restrict__ cnt1,
    int2* __restrict__ ebuf, int E, int NR)
{
    __shared__ int cur[256];
    int b = blockIdx.x;
    int per = (E + NCH - 1) / NCH;
    int s0 = b * per, s1 = s0 + per; if (s1 > E) s1 = E;
    int t = threadIdx.x;
    if (t < NR) cur[t] = cnt1[(size_t)b * NR + t];
    __syncthreads();
    for (int e = s0 + t; e < s1; e += 256) {
        int ch = p2c[e];
        int slot = atomicAdd(&cur[ch >> 8], 1);
        ebuf[slot] = make_int2(e >> 3, ch);   // (path id, channel); KNB == 8
    }
}

// buckscan: per-bucket channel histogram + in-LDS exclusive scan.
__global__ __launch_bounds__(256) void buckscan_kernel(
    const int2* __restrict__ ebuf, const int* __restrict__ bstart,
    int* __restrict__ offsets, int* __restrict__ bsum, int C)
{
    __shared__ int h[256];
    __shared__ int sc[256];
    int r = blockIdx.x;
    int t = threadIdx.x;
    h[t] = 0;
    __syncthreads();
    int s0 = bstart[r], s1 = bstart[r + 1];
    for (int i = s0 + t; i < s1; i += 256)
        atomicAdd(&h[ebuf[i].y & 255], 1);
    __syncthreads();
    int mine = h[t];
    sc[t] = mine;
    __syncthreads();
    #pragma unroll
    for (int d = 1; d < 256; d <<= 1) {
        int v = (t >= d) ? sc[t - d] : 0;
        __syncthreads();
        sc[t] += v;
        __syncthreads();
    }
    int c = (r << 8) + t;
    if (c < C) offsets[c] = sc[t] - mine;   // exclusive within bucket
    if (t == 255) bsum[r] = sc[255];
}

__global__ __launch_bounds__(256) void scan_bsums_kernel(
    const int* __restrict__ bsum, int* __restrict__ bbase,
    int* __restrict__ offsets, int NR, int C, int E)
{
    __shared__ int sc[256];
    int t = threadIdx.x;
    int mine = (t < NR) ? bsum[t] : 0;
    sc[t] = mine;
    __syncthreads();
    #pragma unroll
    for (int d = 1; d < 256; d <<= 1) {
        int v = (t >= d) ? sc[t - d] : 0;
        __syncthreads();
        sc[t] += v;
        __syncthreads();
    }
    if (t < NR) bbase[t] = sc[t] - mine;
    if (t == 0) offsets[C] = E;
}

__global__ __launch_bounds__(256) void addback_kernel(
    int* __restrict__ offsets, const int* __restrict__ bbase, int C)
{
    int c = blockIdx.x * blockDim.x + threadIdx.x;
    if (c < C) offsets[c] += bbase[c >> 8];
}

__global__ __launch_bounds__(256) void buckfill_kernel(
    const int2* __restrict__ ebuf, const int* __restrict__ bstart,
    const int* __restrict__ offsets, int* __restrict__ elist, int C)
{
    __shared__ int cur[256];
    int r = blockIdx.x;
    int t = threadIdx.x;
    int c = (r << 8) + t;
    cur[t] = (c < C) ? offsets[c] : 0;
    __syncthreads();
    int s0 = bstart[r], s1 = bstart[r + 1];
    for (int i = s0 + t; i < s1; i += 256) {
        int2 v = ebuf[i];
        int slot = atomicAdd(&cur[v.y & 255], 1);
        elist[slot] = v.x;
    }
}

// ---------------- init: h_c copy + bf16 shadow in one pass ------------------

__global__ __launch_bounds__(256) void hc_init_kernel(
    const float* __restrict__ src, float* __restrict__ h_c,
    __bf16* __restrict__ dst, int n8)
{
    int i = blockIdx.x * blockDim.x + threadIdx.x;
    if (i >= n8) return;
    const float4* s = (const float4*)(src + (size_t)i * 8);
    float4 u = s[0], v = s[1];
    float4* d = (float4*)(h_c + (size_t)i * 8);
    d[0] = u; d[1] = v;
    bf16x8 o;
    o[0]=(__bf16)u.x; o[1]=(__bf16)u.y; o[2]=(__bf16)u.z; o[3]=(__bf16)u.w;
    o[4]=(__bf16)v.x; o[5]=(__bf16)v.y; o[6]=(__bf16)v.z; o[7]=(__bf16)v.w;
    ((bf16x8*)dst)[i] = o;
}

// ---------------- weight pre-conversion (once per launch) -------------------
__global__ __launch_bounds__(256) void wconv_kernel(
    const float* __restrict__ W1i, const float* __restrict__ W1h,
    const float* __restrict__ W2i, const float* __restrict__ W2h,
    __bf16* __restrict__ w1x, __bf16* __restrict__ w1h,
    __bf16* __restrict__ w2xH, __bf16* __restrict__ w2xL,
    __bf16* __restrict__ w2hH, __bf16* __restrict__ w2hL)
{
    int i = blockIdx.x * blockDim.x + threadIdx.x;
    if (i >= 96 * FD) return;
    w1x[i] = (__bf16)W1i[i];
    w1h[i] = (__bf16)W1h[i];
    float c = W2i[i]; __bf16 ch = (__bf16)c;
    w2xH[i] = ch; w2xL[i] = (__bf16)(c - (float)ch);
    float d = W2h[i]; __bf16 dh = (__bf16)d;
    w2hH[i] = dh; w2hL[i] = (__bf16)(d - (float)dh);
}

// ---------------- fused path kernel v5: 1-wave blocks, wave-private tile ----
// Occupancy experiment: 64-thread blocks (1 wave), each wave owns a private
// 16-path tile (LDS 1280 B), ZERO barriers. Grid 4096 = exactly the 16
// waves/CU VGPR cap; grid-stride over P/16 wave-tiles.
#define HLP 40   // bf16 row pitch: 80 B, 16B-aligned
__global__ __launch_bounds__(64) void path_fused_kernel(
    float* __restrict__ h_p, const int* __restrict__ p2c,
    const __bf16* __restrict__ hcb,
    const __bf16* __restrict__ w1x, const __bf16* __restrict__ w1h,
    const float* __restrict__ bih, const float* __restrict__ bhh,
    __bf16* __restrict__ hpb, int ntiles16)
{
    __shared__ __bf16 hl[16][HLP];
    const int lane = threadIdx.x & 63;
    const int c    = lane & 15;
    const int kg   = lane >> 4;

    // B fragments + biases: once per wave (pre-converted bf16, 16B loads)
    bf16x8 Bx[6], Bh[6];
    #pragma unroll
    for (int t = 0; t < 6; t++) {
        Bx[t] = *(const bf16x8*)(w1x + (size_t)(16*t + c) * FD + 8*kg);
        Bh[t] = *(const bf16x8*)(w1h + (size_t)(16*t + c) * FD + 8*kg);
    }
    f32x4 cin_rz[4], cin_xn[2], cin_hn[2];
    #pragma unroll
    for (int t = 0; t < 4; t++) {
        float b = bih[16*t + c] + bhh[16*t + c];
        cin_rz[t] = (f32x4){b, b, b, b};
    }
    #pragma unroll
    for (int fi = 0; fi < 2; fi++) {
        float bi = bih[64 + 16*fi + c];
        float bh = bhh[64 + 16*fi + c];
        cin_xn[fi] = (f32x4){bi, bi, bi, bi};
        cin_hn[fi] = (f32x4){bh, bh, bh, bh};
    }

    for (int tile = blockIdx.x; tile < ntiles16; tile += gridDim.x) {
        const int blk0 = tile * 16;
        const int rbase = blk0 + 4*kg;

        // load h: f32 regs (D-layout) + bf16 LDS copy (wave-private rows)
        float hD[8];
        #pragma unroll
        for (int q = 0; q < 4; q++)
            #pragma unroll
            for (int fi = 0; fi < 2; fi++) {
                float v = h_p[(size_t)(rbase + q) * FD + c + 16*fi];
                hD[2*q + fi] = v;
                hl[4*kg + q][c + 16*fi] = (__bf16)v;
            }

        // prefetch all 8 steps' x-fragments
        const int pA = blk0 + c;
        const int4* pp = (const int4*)(p2c + (size_t)pA * KNB);
        int4 ia = pp[0], ib = pp[1];
        int idxA[KNB] = {ia.x, ia.y, ia.z, ia.w, ib.x, ib.y, ib.z, ib.w};
        bf16x8 Ax[KNB];
        #pragma unroll
        for (int k = 0; k < KNB; k++)
            Ax[k] = *(const bf16x8*)(hcb + (size_t)idxA[k] * FD + 8*kg);

        #pragma unroll
        for (int k = 0; k < KNB; k++) {
            bf16x8 Ah = *(const bf16x8*)&hl[c][8*kg];   // A row = lane's c

            f32x4 arz[4], xn[2], hn[2];
            #pragma unroll
            for (int t = 0; t < 4; t++) {
                arz[t] = __builtin_amdgcn_mfma_f32_16x16x32_bf16(Ax[k], Bx[t], cin_rz[t], 0, 0, 0);
                arz[t] = __builtin_amdgcn_mfma_f32_16x16x32_bf16(Ah,    Bh[t], arz[t],   0, 0, 0);
            }
            #pragma unroll
            for (int fi = 0; fi < 2; fi++) {
                xn[fi] = __builtin_amdgcn_mfma_f32_16x16x32_bf16(Ax[k], Bx[4+fi], cin_xn[fi], 0, 0, 0);
                hn[fi] = __builtin_amdgcn_mfma_f32_16x16x32_bf16(Ah,    Bh[4+fi], cin_hn[fi], 0, 0, 0);
            }

            #pragma unroll
            for (int q = 0; q < 4; q++)
                #pragma unroll
                for (int fi = 0; fi < 2; fi++) {
                    float r = sigmoidf_(arz[fi][q]);
                    float z = sigmoidf_(arz[2+fi][q]);
                    float n = tanhf_(fmaf(r, hn[fi][q], xn[fi][q]));
                    float ho = hD[2*q + fi];
                    float hv = fmaf(z, ho - n, n);
                    hD[2*q + fi] = hv;
                    hl[4*kg + q][c + 16*fi] = (__bf16)hv;
                }
        }

        // f32 h_p from own regs
        #pragma unroll
        for (int q = 0; q < 4; q++)
            #pragma unroll
            for (int fi = 0; fi < 2; fi++)
                h_p[(size_t)(rbase + q) * FD + c + 16*fi] = hD[2*q + fi];

        // bf16 shadow: wave-private rows -> NO barrier needed
        {
            int r  = lane >> 2;            // 0..15, all written by this wave
            int c0 = (lane & 3) * 8;
            bf16x8 o = *(const bf16x8*)&hl[r][c0];
            *(bf16x8*)(hpb + ((size_t)(blk0 + r)) * FD + c0) = o;
        }
    }
}

// ---------------- fused gather + channel GRU2 (MFMA, preconv weights) -------
__global__ __launch_bounds__(256) void gchannel_kernel(
    const __bf16* __restrict__ hpb, const int* __restrict__ offsets,
    const int* __restrict__ elist, float* __restrict__ h_c,
    const __bf16* __restrict__ w2xH, const __bf16* __restrict__ w2xL,
    const __bf16* __restrict__ w2hH, const __bf16* __restrict__ w2hL,
    const float* __restrict__ bih, const float* __restrict__ bhh,
    __bf16* __restrict__ hcb, int C)
{
    const int tid  = threadIdx.x;
    const int wid  = tid >> 6;
    const int lane = tid & 63;
    const int c    = lane & 15;
    const int kg   = lane >> 4;
    const int blk0 = blockIdx.x * 64;
    const int chA  = blk0 + wid*16 + c;

    // gather: 4-deep with dual accumulator banks (more loads in flight)
    float xr[8], xs[8];
    #pragma unroll
    for (int j = 0; j < 8; j++) { xr[j] = 0.f; xs[j] = 0.f; }
    int s = 0, e = 0;
    if (chA < C) { s = offsets[chA]; e = offsets[chA + 1]; }
    int i = s;
    for (; i + 4 <= e; i += 4) {
        int e0 = elist[i], e1 = elist[i + 1], e2 = elist[i + 2], e3 = elist[i + 3];
        bf16x8 v0 = *(const bf16x8*)(hpb + (size_t)e0 * FD + 8*kg);
        bf16x8 v1 = *(const bf16x8*)(hpb + (size_t)e1 * FD + 8*kg);
        bf16x8 v2 = *(const bf16x8*)(hpb + (size_t)e2 * FD + 8*kg);
        bf16x8 v3 = *(const bf16x8*)(hpb + (size_t)e3 * FD + 8*kg);
        #pragma unroll
        for (int j = 0; j < 8; j++) {
            xr[j] += (float)v0[j] + (float)v2[j];
            xs[j] += (float)v1[j] + (float)v3[j];
        }
    }
    for (; i < e; i++) {
        bf16x8 v0 = *(const bf16x8*)(hpb + (size_t)elist[i] * FD + 8*kg);
        #pragma unroll
        for (int j = 0; j < 8; j++) xr[j] += (float)v0[j];
    }
    #pragma unroll
    for (int j = 0; j < 8; j++) xr[j] += xs[j];

    float hr[8];
    if (chA < C) {
        const float4* ha = (const float4*)(h_c + (size_t)chA * FD + 8*kg);
        float4 h0 = ha[0], h1 = ha[1];
        hr[0]=h0.x; hr[1]=h0.y; hr[2]=h0.z; hr[3]=h0.w;
        hr[4]=h1.x; hr[5]=h1.y; hr[6]=h1.z; hr[7]=h1.w;
    } else {
        #pragma unroll
        for (int j = 0; j < 8; j++) hr[j] = 0.f;
    }
    bf16x8 AxH, AxL, AhH, AhL;
    #pragma unroll
    for (int j = 0; j < 8; j++) {
        __bf16 xh = (__bf16)xr[j]; AxH[j] = xh; AxL[j] = (__bf16)(xr[j] - (float)xh);
        __bf16 hh = (__bf16)hr[j]; AhH[j] = hh; AhL[j] = (__bf16)(hr[j] - (float)hh);
    }

    f32x4 cin_rz[4], cin_xn[2], cin_hn[2];
    #pragma unroll
    for (int t = 0; t < 4; t++) {
        float b = bih[16*t + c] + bhh[16*t + c];
        cin_rz[t] = (f32x4){b, b, b, b};
    }
    #pragma unroll
    for (int fi = 0; fi < 2; fi++) {
        float bi = bih[64 + 16*fi + c];
        float bh = bhh[64 + 16*fi + c];
        cin_xn[fi] = (f32x4){bi, bi, bi, bi};
        cin_hn[fi] = (f32x4){bh, bh, bh, bh};
    }

    f32x4 arz[4], xn[2], hn[2];
    #pragma unroll
    for (int t = 0; t < 4; t++) {
        size_t wo = (size_t)(16*t + c) * FD + 8*kg;
        bf16x8 BxH_ = *(const bf16x8*)(w2xH + wo);
        bf16x8 BxL_ = *(const bf16x8*)(w2xL + wo);
        bf16x8 BhH_ = *(const bf16x8*)(w2hH + wo);
        bf16x8 BhL_ = *(const bf16x8*)(w2hL + wo);
        f32x4 a = cin_rz[t];
        a = __builtin_amdgcn_mfma_f32_16x16x32_bf16(AxH, BxH_, a, 0, 0, 0);
        a = __builtin_amdgcn_mfma_f32_16x16x32_bf16(AxH, BxL_, a, 0, 0, 0);
        a = __builtin_amdgcn_mfma_f32_16x16x32_bf16(AxL, BxH_, a, 0, 0, 0);
        a = __builtin_amdgcn_mfma_f32_16x16x32_bf16(AhH, BhH_, a, 0, 0, 0);
        a = __builtin_amdgcn_mfma_f32_16x16x32_bf16(AhH, BhL_, a, 0, 0, 0);
        a = __builtin_amdgcn_mfma_f32_16x16x32_bf16(AhL, BhH_, a, 0, 0, 0);
        arz[t] = a;
    }
    #pragma unroll
    for (int fi = 0; fi < 2; fi++) {
        size_t wo = (size_t)(16*(4+fi) + c) * FD + 8*kg;
        bf16x8 BxH_ = *(const bf16x8*)(w2xH + wo);
        bf16x8 BxL_ = *(const bf16x8*)(w2xL + wo);
        bf16x8 BhH_ = *(const bf16x8*)(w2hH + wo);
        bf16x8 BhL_ = *(const bf16x8*)(w2hL + wo);
        f32x4 a = cin_xn[fi];
        a = __builtin_amdgcn_mfma_f32_16x16x32_bf16(AxH, BxH_, a, 0, 0, 0);
        a = __builtin_amdgcn_mfma_f32_16x16x32_bf16(AxH, BxL_, a, 0, 0, 0);
        a = __builtin_amdgcn_mfma_f32_16x16x32_bf16(AxL, BxH_, a, 0, 0, 0);
        xn[fi] = a;
        f32x4 b = cin_hn[fi];
        b = __builtin_amdgcn_mfma_f32_16x16x32_bf16(AhH, BhH_, b, 0, 0, 0);
        b = __builtin_amdgcn_mfma_f32_16x16x32_bf16(AhH, BhL_, b, 0, 0, 0);
        b = __builtin_amdgcn_mfma_f32_16x16x32_bf16(AhL, BhH_, b, 0, 0, 0);
        hn[fi] = b;
    }

    #pragma unroll
    for (int q = 0; q < 4; q++) {
        int row = blk0 + wid*16 + 4*kg + q;
        if (row < C) {
            #pragma unroll
            for (int fi = 0; fi < 2; fi++) {
                float r = sigmoidf_(arz[fi][q]);
                float z = sigmoidf_(arz[2+fi][q]);
                float n = tanhf_(fmaf(r, hn[fi][q], xn[fi][q]));
                float ho = h_c[(size_t)row * FD + c + 16*fi];
                float hv = fmaf(z, ho - n, n);
                h_c[(size_t)row * FD + c + 16*fi] = hv;
                hcb[(size_t)row * FD + c + 16*fi] = (__bf16)hv;
            }
        }
    }
}

// ---------------- fallback kernels (atomic path) ----------------------------

__global__ __launch_bounds__(256) void path_update_kernel(
    const float* __restrict__ h_c, float* __restrict__ h_p,
    const int* __restrict__ p2c,
    const float* __restrict__ Wih, const float* __restrict__ Whh,
    const float* __restrict__ bih, const float* __restrict__ bhh, int P)
{
    int p = blockIdx.x * blockDim.x + threadIdx.x;
    if (p >= P) return;

    float h[FD];
    const float4* hp4 = (const float4*)(h_p + (size_t)p * FD);
    #pragma unroll
    for (int i = 0; i < FD / 4; i++) {
        float4 v = hp4[i];
        h[4*i] = v.x; h[4*i+1] = v.y; h[4*i+2] = v.z; h[4*i+3] = v.w;
    }

    int idx[KNB];
    const int4* pi = (const int4*)(p2c + (size_t)p * KNB);
    int4 i0 = pi[0], i1 = pi[1];
    idx[0]=i0.x; idx[1]=i0.y; idx[2]=i0.z; idx[3]=i0.w;
    idx[4]=i1.x; idx[5]=i1.y; idx[6]=i1.z; idx[7]=i1.w;

    for (int k = 0; k < KNB; k++) {
        float x[FD];
        const float4* xr = (const float4*)(h_c + (size_t)idx[k] * FD);
        #pragma unroll
        for (int i = 0; i < FD / 4; i++) {
            float4 v = xr[i];
            x[4*i] = v.x; x[4*i+1] = v.y; x[4*i+2] = v.z; x[4*i+3] = v.w;
        }

        float hn[FD];
        #pragma unroll 4
        for (int j = 0; j < FD; j++) {
            float air = bih[j],        ahr = bhh[j];
            float aiz = bih[FD + j],   ahz = bhh[FD + j];
            float ain = bih[2*FD + j], ahn = bhh[2*FD + j];
            #pragma unroll
            for (int i = 0; i < FD; i++) {
                air = fmaf(Wih[j*FD + i],          x[i], air);
                ahr = fmaf(Whh[j*FD + i],          h[i], ahr);
                aiz = fmaf(Wih[(FD + j)*FD + i],   x[i], aiz);
                ahz = fmaf(Whh[(FD + j)*FD + i],   h[i], ahz);
                ain = fmaf(Wih[(2*FD + j)*FD + i], x[i], ain);
                ahn = fmaf(Whh[(2*FD + j)*FD + i], h[i], ahn);
            }
            float r = sigmoidf_(air + ahr);
            float z = sigmoidf_(aiz + ahz);
            float n = tanhf_(ain + r * ahn);
            hn[j] = (1.0f - z) * n + z * h[j];
        }
        #pragma unroll
        for (int j = 0; j < FD; j++) h[j] = hn[j];
    }

    float4* hpw = (float4*)(h_p + (size_t)p * FD);
    #pragma unroll
    for (int i = 0; i < FD / 4; i++) {
        float4 v;
        v.x = h[4*i]; v.y = h[4*i+1]; v.z = h[4*i+2]; v.w = h[4*i+3];
        hpw[i] = v;
    }
}

__global__ __launch_bounds__(256) void scatter_agg_atomic_kernel(
    const float* __restrict__ h_p, const int* __restrict__ p2c,
    float* __restrict__ agg, int P)
{
    int p = blockIdx.x * blockDim.x + threadIdx.x;
    if (p >= P) return;
    const float* hr = h_p + (size_t)p * FD;
    #pragma unroll
    for (int k = 0; k < KNB; k++) {
        int c = p2c[(size_t)p * KNB + k];
        float* ar = agg + (size_t)c * FD;
        #pragma unroll
        for (int i = 0; i < FD; i++) atomicAdd(ar + i, hr[i]);
    }
}

__global__ __launch_bounds__(256) void channel_update_kernel(
    const float* __restrict__ agg, float* __restrict__ h_c,
    const float* __restrict__ Wih, const float* __restrict__ Whh,
    const float* __restrict__ bih, const float* __restrict__ bhh, int C)
{
    int c = blockIdx.x * blockDim.x + threadIdx.x;
    if (c >= C) return;

    float h[FD], x[FD];
    const float4* hr = (const float4*)(h_c + (size_t)c * FD);
    const float4* xr = (const float4*)(agg + (size_t)c * FD);
    #pragma unroll
    for (int i = 0; i < FD / 4; i++) {
        float4 v = hr[i];
        h[4*i] = v.x; h[4*i+1] = v.y; h[4*i+2] = v.z; h[4*i+3] = v.w;
        float4 w = xr[i];
        x[4*i] = w.x; x[4*i+1] = w.y; x[4*i+2] = w.z; x[4*i+3] = w.w;
    }

    float hn[FD];
    #pragma unroll 4
    for (int j = 0; j < FD; j++) {
        float air = bih[j],        ahr = bhh[j];
        float aiz = bih[FD + j],   ahz = bhh[FD + j];
        float ain = bih[2*FD + j], ahn = bhh[2*FD + j];
        #pragma unroll
        for (int i = 0; i < FD; i++) {
            air = fmaf(Wih[j*FD + i],          x[i], air);
            ahr = fmaf(Whh[j*FD + i],          h[i], ahr);
            aiz = fmaf(Wih[(FD + j)*FD + i],   x[i], aiz);
            ahz = fmaf(Whh[(FD + j)*FD + i],   h[i], ahz);
            ain = fmaf(Wih[(2*FD + j)*FD + i], x[i], ain);
            ahn = fmaf(Whh[(2*FD + j)*FD + i], h[i], ahn);
        }
        float r = sigmoidf_(air + ahr);
        float z = sigmoidf_(aiz + ahz);
        float n = tanhf_(ain + r * ahn);
        hn[j] = (1.0f - z) * n + z * h[j];
    }

    float4* hw = (float4*)(h_c + (size_t)c * FD);
    #pragma unroll
    for (int i = 0; i < FD / 4; i++) {
        float4 v;
        v.x = hn[4*i]; v.y = hn[4*i+1]; v.z = hn[4*i+2]; v.w = hn[4*i+3];
        hw[i] = v;
    }
}

extern "C" void kernel_launch(void* const* d_in, const int* in_sizes, int n_in,
                              void* d_out, int out_size, void* d_ws, size_t ws_size,
                              hipStream_t stream) {
    const float* paths    = (const float*)d_in[0];
    const float* channels = (const float*)d_in[1];
    const int*   p2c      = (const int*)d_in[2];
    const float* Wih1 = (const float*)d_in[3];
    const float* Whh1 = (const float*)d_in[4];
    const float* bih1 = (const float*)d_in[5];
    const float* bhh1 = (const float*)d_in[6];
    const float* Wih2 = (const float*)d_in[7];
    const float* Whh2 = (const float*)d_in[8];
    const float* bih2 = (const float*)d_in[9];
    const float* bhh2 = (const float*)d_in[10];

    const int P = in_sizes[0] / FD;     // 200000
    const int C = in_sizes[1] / FD;     // 50000
    const int E = P * KNB;              // 1.6M edges
    const int NR = (C + 255) >> 8;      // 196 buckets

    float* h_p = (float*)d_out;                  // [P*FD]
    float* h_c = h_p + (size_t)P * FD;           // [C*FD]

    // ws: bsum[NR] bbase[NR] | offsets[C+1] | bstart[NR+1] | elist[E] | hcb |
    //     wbufs(6) | UNION{ build: ebuf[E](int2)+cnt1[NCH*NR] | iter: hpb }
    char* ws = (char*)d_ws;
    size_t bs_off  = 0;
    size_t ofs_off = (bs_off + (size_t)(2 * NR) * 4 + 255) & ~(size_t)255;
    size_t bst_off = (ofs_off + (size_t)(C + 1) * 4 + 255) & ~(size_t)255;
    size_t el_off  = (bst_off + (size_t)(NR + 1) * 4 + 255) & ~(size_t)255;
    size_t hcb_off = (el_off + (size_t)E * 4 + 255) & ~(size_t)255;
    size_t wb_off  = (hcb_off + (size_t)C * FD * 2 + 255) & ~(size_t)255;
    size_t wmat_b  = (size_t)96 * FD * 2;                 // 6 KB per matrix
    size_t uni_off = (wb_off + 6 * wmat_b + 255) & ~(size_t)255;
    size_t ebuf_b  = (size_t)E * 8;
    size_t cnt1_b  = (size_t)NCH * NR * 4;
    size_t hpb_b   = (size_t)P * FD * 2;
    size_t bld_b   = ebuf_b + cnt1_b;
    size_t uni_b   = (hpb_b > bld_b) ? hpb_b : bld_b;

    int*    bsum    = (int*)(ws + bs_off);
    int*    bbase   = bsum + NR;
    int*    offsets = (int*)(ws + ofs_off);
    int*    bstart  = (int*)(ws + bst_off);
    int*    elist   = (int*)(ws + el_off);
    __bf16* hcb     = (__bf16*)(ws + hcb_off);
    __bf16* w1x     = (__bf16*)(ws + wb_off);
    __bf16* w1h     = (__bf16*)(ws + wb_off + 1 * wmat_b);
    __bf16* w2xH    = (__bf16*)(ws + wb_off + 2 * wmat_b);
    __bf16* w2xL    = (__bf16*)(ws + wb_off + 3 * wmat_b);
    __bf16* w2hH    = (__bf16*)(ws + wb_off + 4 * wmat_b);
    __bf16* w2hL    = (__bf16*)(ws + wb_off + 5 * wmat_b);
    int2*   ebuf    = (int2*)(ws + uni_off);
    int*    cnt1    = (int*)(ws + uni_off + ebuf_b);
    __bf16* hpb     = (__bf16*)(ws + uni_off);   // time-disjoint w/ ebuf/cnt1

    const bool mfma_ok = (P % 64 == 0) && (C <= 65536);
    const bool tier1 = mfma_ok && (ws_size >= uni_off + uni_b);

    dim3 pb(256), pg((P + 255) / 256);
    dim3 cb(256), cg((C + 255) / 256);

    if (tier1) {
        hipMemcpyAsync(h_p, paths, (size_t)P * FD * sizeof(float),
                       hipMemcpyDeviceToDevice, stream);
        int n8 = C * FD / 8;
        hc_init_kernel<<<(n8 + 255) / 256, 256, 0, stream>>>(channels, h_c, hcb, n8);
        wconv_kernel<<<(96 * FD + 255) / 256, 256, 0, stream>>>(
            Wih1, Whh1, Wih2, Whh2, w1x, w1h, w2xH, w2xL, w2hH, w2hL);

        bincount_kernel<<<NCH, 256, 0, stream>>>(p2c, cnt1, E, NR);
        scan_chunks_kernel<<<1, 256, 0, stream>>>(cnt1, bstart, NR, E);
        binfill_kernel<<<NCH, 256, 0, stream>>>(p2c, cnt1, ebuf, E, NR);
        buckscan_kernel<<<NR, 256, 0, stream>>>(ebuf, bstart, offsets, bsum, C);
        scan_bsums_kernel<<<1, 256, 0, stream>>>(bsum, bbase, offsets, NR, C, E);
        addback_kernel<<<cg, cb, 0, stream>>>(offsets, bbase, C);
        buckfill_kernel<<<NR, 256, 0, stream>>>(ebuf, bstart, offsets, elist, C);

        const int ntiles16 = P / 16;                    // 12500 wave-tiles
        int pgrid = ntiles16 < 4096 ? ntiles16 : 4096;  // 16 waves/CU fill
        dim3 xg((C + 63) / 64), xb(256);
        for (int it = 0; it < NITER; it++) {
            path_fused_kernel<<<pgrid, 64, 0, stream>>>(h_p, p2c, hcb,
                                                        w1x, w1h, bih1, bhh1,
                                                        hpb, ntiles16);
            gchannel_kernel<<<xg, xb, 0, stream>>>(hpb, offsets, elist, h_c,
                                                   w2xH, w2xL, w2hH, w2hL,
                                                   bih2, bhh2, hcb, C);
        }
    } else {
        float* agg0 = (float*)d_ws;
        size_t aggf_b = (size_t)C * FD * sizeof(float);
        hipMemcpyAsync(h_p, paths, (size_t)P * FD * sizeof(float),
                       hipMemcpyDeviceToDevice, stream);
        hipMemcpyAsync(h_c, channels, (size_t)C * FD * sizeof(float),
                       hipMemcpyDeviceToDevice, stream);
        for (int it = 0; it < NITER; it++) {
            path_update_kernel<<<pg, pb, 0, stream>>>(h_c, h_p, p2c,
                                                      Wih1, Whh1, bih1, bhh1, P);
            hipMemsetAsync(agg0, 0, aggf_b, stream);
            scatter_agg_atomic_kernel<<<pg, pb, 0, stream>>>(h_p, p2c, agg0, P);
            channel_update_kernel<<<cg, cb, 0, stream>>>(agg0, h_c,
                                                         Wih2, Whh2, bih2, bhh2, C);
        }
    }
}

// Round 15
// 533.827 us; speedup vs baseline: 7.7718x; 1.0074x over previous
//
#include <hip/hip_runtime.h>

#define FD 32
#define KNB 8
#define NITER 5
#define NCH 256   // edge chunks for the binning passes

#define LOG2E 1.44269504f

typedef __bf16 bf16x8 __attribute__((ext_vector_type(8)));
typedef float  f32x4  __attribute__((ext_vector_type(4)));

// Fast HW transcendentals (round-13 numerics: scale applied in gate math,
// weights stored UNSCALED -> absmax stays at 0.0674; the round-14 weight-fold
// pushed absmax over threshold and was reverted).
__device__ __forceinline__ float frcp_(float a) { return __builtin_amdgcn_rcpf(a); }
__device__ __forceinline__ float fexp2_(float a) { return __builtin_amdgcn_exp2f(a); }
__device__ __forceinline__ float sigmoidf_(float a) {
    return frcp_(1.0f + fexp2_(a * -LOG2E));
}
__device__ __forceinline__ float tanhf_(float a) {
    return 1.0f - 2.0f * frcp_(fexp2_(a * 2.0f * LOG2E) + 1.0f);
}

// ---------------- atomic-free CSR build (two-level counting sort) -----------
// bucket r = channel >> 8; NR = ceil(C/256) buckets.

__global__ __launch_bounds__(256) void bincount_kernel(
    const int* __restrict__ p2c, int* __restrict__ cnt1, int E, int NR)
{
    __shared__ int lds[256];
    int b = blockIdx.x;
    int per = (E + NCH - 1) / NCH;
    int s0 = b * per, s1 = s0 + per; if (s1 > E) s1 = E;
    int t = threadIdx.x;
    if (t < NR) lds[t] = 0;
    __syncthreads();
    for (int e = s0 + t; e < s1; e += 256)
        atomicAdd(&lds[p2c[e] >> 8], 1);
    __syncthreads();
    if (t < NR) cnt1[(size_t)b * NR + t] = lds[t];
}

__global__ __launch_bounds__(256) void scan_chunks_kernel(
    int* __restrict__ cnt1, int* __restrict__ bstart, int NR, int E)
{
    __shared__ int tt[256];
    int t = threadIdx.x;
    int tot = 0;
    if (t < NR)
        for (int b = 0; b < NCH; b++) tot += cnt1[(size_t)b * NR + t];
    tt[t] = (t < NR) ? tot : 0;
    __syncthreads();
    for (int d = 1; d < 256; d <<= 1) {
        int v = (t >= d) ? tt[t - d] : 0;
        __syncthreads();
        tt[t] += v;
        __syncthreads();
    }
    if (t < NR) {
        int run = (t == 0) ? 0 : tt[t - 1];
        bstart[t] = run;
        for (int b = 0; b < NCH; b++) {
            int v = cnt1[(size_t)b * NR + t];
            cnt1[(size_t)b * NR + t] = run;
            run += v;
        }
        if (t == NR - 1) bstart[NR] = E;
    }
}

__global__ __launch_bounds__(256) void binfill_kernel(
    const int* __restrict__ p2c, const int* __restrict__ cnt1,
    int2* __restrict__ ebuf, int E, int NR)
{
    __shared__ int cur[256];
    int b = blockIdx.x;
    int per = (E + NCH - 1) / NCH;
    int s0 = b * per, s1 = s0 + per; if (s1 > E) s1 = E;
    int t = threadIdx.x;
    if (t < NR) cur[t] = cnt1[(size_t)b * NR + t];
    __syncthreads();
    for (int e = s0 + t; e < s1; e += 256) {
        int ch = p2c[e];
        int slot = atomicAdd(&cur[ch >> 8], 1);
        ebuf[slot] = make_int2(e >> 3, ch);   // (path id, channel); KNB == 8
    }
}

__global__ __launch_bounds__(256) void buckscan_kernel(
    const int2* __restrict__ ebuf, const int* __restrict__ bstart,
    int* __restrict__ offsets, int* __restrict__ bsum, int C)
{
    __shared__ int h[256];
    __shared__ int sc[256];
    int r = blockIdx.x;
    int t = threadIdx.x;
    h[t] = 0;
    __syncthreads();
    int s0 = bstart[r], s1 = bstart[r + 1];
    for (int i = s0 + t; i < s1; i += 256)
        atomicAdd(&h[ebuf[i].y & 255], 1);
    __syncthreads();
    int mine = h[t];
    sc[t] = mine;
    __syncthreads();
    #pragma unroll
    for (int d = 1; d < 256; d <<= 1) {
        int v = (t >= d) ? sc[t - d] : 0;
        __syncthreads();
        sc[t] += v;
        __syncthreads();
    }
    int c = (r << 8) + t;
    if (c < C) offsets[c] = sc[t] - mine;   // exclusive within bucket
    if (t == 255) bsum[r] = sc[255];
}

__global__ __launch_bounds__(256) void scan_bsums_kernel(
    const int* __restrict__ bsum, int* __restrict__ bbase,
    int* __restrict__ offsets, int NR, int C, int E)
{
    __shared__ int sc[256];
    int t = threadIdx.x;
    int mine = (t < NR) ? bsum[t] : 0;
    sc[t] = mine;
    __syncthreads();
    #pragma unroll
    for (int d = 1; d < 256; d <<= 1) {
        int v = (t >= d) ? sc[t - d] : 0;
        __syncthreads();
        sc[t] += v;
        __syncthreads();
    }
    if (t < NR) bbase[t] = sc[t] - mine;
    if (t == 0) offsets[C] = E;
}

__global__ __launch_bounds__(256) void addback_kernel(
    int* __restrict__ offsets, const int* __restrict__ bbase, int C)
{
    int c = blockIdx.x * blockDim.x + threadIdx.x;
    if (c < C) offsets[c] += bbase[c >> 8];
}

__global__ __launch_bounds__(256) void buckfill_kernel(
    const int2* __restrict__ ebuf, const int* __restrict__ bstart,
    const int* __restrict__ offsets, int* __restrict__ elist, int C)
{
    __shared__ int cur[256];
    int r = blockIdx.x;
    int t = threadIdx.x;
    int c = (r << 8) + t;
    cur[t] = (c < C) ? offsets[c] : 0;
    __syncthreads();
    int s0 = bstart[r], s1 = bstart[r + 1];
    for (int i = s0 + t; i < s1; i += 256) {
        int2 v = ebuf[i];
        int slot = atomicAdd(&cur[v.y & 255], 1);
        elist[slot] = v.x;
    }
}

// ---------------- init: h_c copy + bf16 shadow in one pass ------------------

__global__ __launch_bounds__(256) void hc_init_kernel(
    const float* __restrict__ src, float* __restrict__ h_c,
    __bf16* __restrict__ dst, int n8)
{
    int i = blockIdx.x * blockDim.x + threadIdx.x;
    if (i >= n8) return;
    const float4* s = (const float4*)(src + (size_t)i * 8);
    float4 u = s[0], v = s[1];
    float4* d = (float4*)(h_c + (size_t)i * 8);
    d[0] = u; d[1] = v;
    bf16x8 o;
    o[0]=(__bf16)u.x; o[1]=(__bf16)u.y; o[2]=(__bf16)u.z; o[3]=(__bf16)u.w;
    o[4]=(__bf16)v.x; o[5]=(__bf16)v.y; o[6]=(__bf16)v.z; o[7]=(__bf16)v.w;
    ((bf16x8*)dst)[i] = o;
}

// ---------------- weight pre-conversion (UNSCALED, round-13 numerics) -------
__global__ __launch_bounds__(256) void wconv_kernel(
    const float* __restrict__ W1i, const float* __restrict__ W1h,
    const float* __restrict__ W2i, const float* __restrict__ W2h,
    __bf16* __restrict__ w1x, __bf16* __restrict__ w1h,
    __bf16* __restrict__ w2xH, __bf16* __restrict__ w2xL,
    __bf16* __restrict__ w2hH, __bf16* __restrict__ w2hL)
{
    int i = blockIdx.x * blockDim.x + threadIdx.x;
    if (i >= 96 * FD) return;
    w1x[i] = (__bf16)W1i[i];
    w1h[i] = (__bf16)W1h[i];
    float c = W2i[i]; __bf16 ch = (__bf16)c;
    w2xH[i] = ch; w2xL[i] = (__bf16)(c - (float)ch);
    float d = W2h[i]; __bf16 dh = (__bf16)d;
    w2hH[i] = dh; w2hL[i] = (__bf16)(d - (float)dh);
}

// ---------------- fused path kernel v6: 1-wave blocks + next-tile prefetch --
#define HLP 40   // bf16 row pitch: 80 B, 16B-aligned, 2-way-max bank aliasing
__global__ __launch_bounds__(64) void path_fused_kernel(
    float* __restrict__ h_p, const int* __restrict__ p2c,
    const __bf16* __restrict__ hcb,
    const __bf16* __restrict__ w1x, const __bf16* __restrict__ w1h,
    const float* __restrict__ bih, const float* __restrict__ bhh,
    __bf16* __restrict__ hpb, int ntiles16)
{
    __shared__ __bf16 hl[16][HLP];
    const int lane = threadIdx.x & 63;
    const int c    = lane & 15;
    const int kg   = lane >> 4;

    // B fragments + bias seeds: once per wave (raw weights/biases, rd-13 math)
    bf16x8 Bx[6], Bh[6];
    #pragma unroll
    for (int t = 0; t < 6; t++) {
        Bx[t] = *(const bf16x8*)(w1x + (size_t)(16*t + c) * FD + 8*kg);
        Bh[t] = *(const bf16x8*)(w1h + (size_t)(16*t + c) * FD + 8*kg);
    }
    f32x4 cin_rz[4], cin_xn[2], cin_hn[2];
    #pragma unroll
    for (int t = 0; t < 4; t++) {
        float b = bih[16*t + c] + bhh[16*t + c];
        cin_rz[t] = (f32x4){b, b, b, b};
    }
    #pragma unroll
    for (int fi = 0; fi < 2; fi++) {
        float bi = bih[64 + 16*fi + c];
        float bh = bhh[64 + 16*fi + c];
        cin_xn[fi] = (f32x4){bi, bi, bi, bi};
        cin_hn[fi] = (f32x4){bh, bh, bh, bh};
    }

    int tile = blockIdx.x;
    if (tile >= ntiles16) return;

    // first-tile prologue loads
    float ch_[8]; int4 cia, cib;
    {
        const int rbase = tile * 16 + 4*kg;
        #pragma unroll
        for (int q = 0; q < 4; q++)
            #pragma unroll
            for (int fi = 0; fi < 2; fi++)
                ch_[2*q + fi] = h_p[(size_t)(rbase + q) * FD + c + 16*fi];
        const int4* pp = (const int4*)(p2c + (size_t)(tile * 16 + c) * KNB);
        cia = pp[0]; cib = pp[1];
    }

    while (true) {
        const int blk0 = tile * 16;
        const int rbase = blk0 + 4*kg;
        const int nt = tile + gridDim.x;
        const bool hasN = (nt < ntiles16);

        // stage current tile: regs -> hD + bf16 LDS
        float hD[8];
        #pragma unroll
        for (int q = 0; q < 4; q++)
            #pragma unroll
            for (int fi = 0; fi < 2; fi++) {
                float v = ch_[2*q + fi];
                hD[2*q + fi] = v;
                hl[4*kg + q][c + 16*fi] = (__bf16)v;
            }
        int idxA[KNB] = {cia.x, cia.y, cia.z, cia.w, cib.x, cib.y, cib.z, cib.w};
        bf16x8 Ax[KNB];
        #pragma unroll
        for (int k = 0; k < KNB; k++)
            Ax[k] = *(const bf16x8*)(hcb + (size_t)idxA[k] * FD + 8*kg);

        // prefetch NEXT tile's h rows + p2c (HBM latency hides under 8 steps)
        float nh[8]; int4 nia, nib;
        if (hasN) {
            const int nrbase = nt * 16 + 4*kg;
            #pragma unroll
            for (int q = 0; q < 4; q++)
                #pragma unroll
                for (int fi = 0; fi < 2; fi++)
                    nh[2*q + fi] = h_p[(size_t)(nrbase + q) * FD + c + 16*fi];
            const int4* pp = (const int4*)(p2c + (size_t)(nt * 16 + c) * KNB);
            nia = pp[0]; nib = pp[1];
        }

        #pragma unroll
        for (int k = 0; k < KNB; k++) {
            bf16x8 Ah = *(const bf16x8*)&hl[c][8*kg];

            f32x4 arz[4], xn[2], hn[2];
            #pragma unroll
            for (int t = 0; t < 4; t++) {
                arz[t] = __builtin_amdgcn_mfma_f32_16x16x32_bf16(Ax[k], Bx[t], cin_rz[t], 0, 0, 0);
                arz[t] = __builtin_amdgcn_mfma_f32_16x16x32_bf16(Ah,    Bh[t], arz[t],   0, 0, 0);
            }
            #pragma unroll
            for (int fi = 0; fi < 2; fi++) {
                xn[fi] = __builtin_amdgcn_mfma_f32_16x16x32_bf16(Ax[k], Bx[4+fi], cin_xn[fi], 0, 0, 0);
                hn[fi] = __builtin_amdgcn_mfma_f32_16x16x32_bf16(Ah,    Bh[4+fi], cin_hn[fi], 0, 0, 0);
            }

            #pragma unroll
            for (int q = 0; q < 4; q++)
                #pragma unroll
                for (int fi = 0; fi < 2; fi++) {
                    float r = sigmoidf_(arz[fi][q]);
                    float z = sigmoidf_(arz[2+fi][q]);
                    float n = tanhf_(fmaf(r, hn[fi][q], xn[fi][q]));
                    float ho = hD[2*q + fi];
                    float hv = fmaf(z, ho - n, n);
                    hD[2*q + fi] = hv;
                    hl[4*kg + q][c + 16*fi] = (__bf16)hv;
                }
        }

        // f32 h_p from own regs
        #pragma unroll
        for (int q = 0; q < 4; q++)
            #pragma unroll
            for (int fi = 0; fi < 2; fi++)
                h_p[(size_t)(rbase + q) * FD + c + 16*fi] = hD[2*q + fi];

        // bf16 shadow: wave-private rows -> no barrier
        {
            int r  = lane >> 2;
            int c0 = (lane & 3) * 8;
            bf16x8 o = *(const bf16x8*)&hl[r][c0];
            *(bf16x8*)(hpb + ((size_t)(blk0 + r)) * FD + c0) = o;
        }

        if (!hasN) break;
        #pragma unroll
        for (int j = 0; j < 8; j++) ch_[j] = nh[j];
        cia = nia; cib = nib;
        tile = nt;
    }
}

// ---------------- fused gather + channel GRU2 (MFMA, preconv weights) -------
// 2-wave blocks (32 channels) -> 1563 blocks for better CU fill.
__global__ __launch_bounds__(128) void gchannel_kernel(
    const __bf16* __restrict__ hpb, const int* __restrict__ offsets,
    const int* __restrict__ elist, float* __restrict__ h_c,
    const __bf16* __restrict__ w2xH, const __bf16* __restrict__ w2xL,
    const __bf16* __restrict__ w2hH, const __bf16* __restrict__ w2hL,
    const float* __restrict__ bih, const float* __restrict__ bhh,
    __bf16* __restrict__ hcb, int C)
{
    const int tid  = threadIdx.x;
    const int wid  = tid >> 6;          // 0..1
    const int lane = tid & 63;
    const int c    = lane & 15;
    const int kg   = lane >> 4;
    const int blk0 = blockIdx.x * 32;
    const int chA  = blk0 + wid*16 + c;

    // gather: 4-deep with dual accumulator banks
    float xr[8], xs[8];
    #pragma unroll
    for (int j = 0; j < 8; j++) { xr[j] = 0.f; xs[j] = 0.f; }
    int s = 0, e = 0;
    if (chA < C) { s = offsets[chA]; e = offsets[chA + 1]; }
    int i = s;
    for (; i + 4 <= e; i += 4) {
        int e0 = elist[i], e1 = elist[i + 1], e2 = elist[i + 2], e3 = elist[i + 3];
        bf16x8 v0 = *(const bf16x8*)(hpb + (size_t)e0 * FD + 8*kg);
        bf16x8 v1 = *(const bf16x8*)(hpb + (size_t)e1 * FD + 8*kg);
        bf16x8 v2 = *(const bf16x8*)(hpb + (size_t)e2 * FD + 8*kg);
        bf16x8 v3 = *(const bf16x8*)(hpb + (size_t)e3 * FD + 8*kg);
        #pragma unroll
        for (int j = 0; j < 8; j++) {
            xr[j] += (float)v0[j] + (float)v2[j];
            xs[j] += (float)v1[j] + (float)v3[j];
        }
    }
    for (; i < e; i++) {
        bf16x8 v0 = *(const bf16x8*)(hpb + (size_t)elist[i] * FD + 8*kg);
        #pragma unroll
        for (int j = 0; j < 8; j++) xr[j] += (float)v0[j];
    }
    #pragma unroll
    for (int j = 0; j < 8; j++) xr[j] += xs[j];

    float hr[8];
    if (chA < C) {
        const float4* ha = (const float4*)(h_c + (size_t)chA * FD + 8*kg);
        float4 h0 = ha[0], h1 = ha[1];
        hr[0]=h0.x; hr[1]=h0.y; hr[2]=h0.z; hr[3]=h0.w;
        hr[4]=h1.x; hr[5]=h1.y; hr[6]=h1.z; hr[7]=h1.w;
    } else {
        #pragma unroll
        for (int j = 0; j < 8; j++) hr[j] = 0.f;
    }
    bf16x8 AxH, AxL, AhH, AhL;
    #pragma unroll
    for (int j = 0; j < 8; j++) {
        __bf16 xh = (__bf16)xr[j]; AxH[j] = xh; AxL[j] = (__bf16)(xr[j] - (float)xh);
        __bf16 hh = (__bf16)hr[j]; AhH[j] = hh; AhL[j] = (__bf16)(hr[j] - (float)hh);
    }

    f32x4 cin_rz[4], cin_xn[2], cin_hn[2];
    #pragma unroll
    for (int t = 0; t < 4; t++) {
        float b = bih[16*t + c] + bhh[16*t + c];
        cin_rz[t] = (f32x4){b, b, b, b};
    }
    #pragma unroll
    for (int fi = 0; fi < 2; fi++) {
        float bi = bih[64 + 16*fi + c];
        float bh = bhh[64 + 16*fi + c];
        cin_xn[fi] = (f32x4){bi, bi, bi, bi};
        cin_hn[fi] = (f32x4){bh, bh, bh, bh};
    }

    f32x4 arz[4], xn[2], hn[2];
    #pragma unroll
    for (int t = 0; t < 4; t++) {
        size_t wo = (size_t)(16*t + c) * FD + 8*kg;
        bf16x8 BxH_ = *(const bf16x8*)(w2xH + wo);
        bf16x8 BxL_ = *(const bf16x8*)(w2xL + wo);
        bf16x8 BhH_ = *(const bf16x8*)(w2hH + wo);
        bf16x8 BhL_ = *(const bf16x8*)(w2hL + wo);
        f32x4 a = cin_rz[t];
        a = __builtin_amdgcn_mfma_f32_16x16x32_bf16(AxH, BxH_, a, 0, 0, 0);
        a = __builtin_amdgcn_mfma_f32_16x16x32_bf16(AxH, BxL_, a, 0, 0, 0);
        a = __builtin_amdgcn_mfma_f32_16x16x32_bf16(AxL, BxH_, a, 0, 0, 0);
        a = __builtin_amdgcn_mfma_f32_16x16x32_bf16(AhH, BhH_, a, 0, 0, 0);
        a = __builtin_amdgcn_mfma_f32_16x16x32_bf16(AhH, BhL_, a, 0, 0, 0);
        a = __builtin_amdgcn_mfma_f32_16x16x32_bf16(AhL, BhH_, a, 0, 0, 0);
        arz[t] = a;
    }
    #pragma unroll
    for (int fi = 0; fi < 2; fi++) {
        size_t wo = (size_t)(16*(4+fi) + c) * FD + 8*kg;
        bf16x8 BxH_ = *(const bf16x8*)(w2xH + wo);
        bf16x8 BxL_ = *(const bf16x8*)(w2xL + wo);
        bf16x8 BhH_ = *(const bf16x8*)(w2hH + wo);
        bf16x8 BhL_ = *(const bf16x8*)(w2hL + wo);
        f32x4 a = cin_xn[fi];
        a = __builtin_amdgcn_mfma_f32_16x16x32_bf16(AxH, BxH_, a, 0, 0, 0);
        a = __builtin_amdgcn_mfma_f32_16x16x32_bf16(AxH, BxL_, a, 0, 0, 0);
        a = __builtin_amdgcn_mfma_f32_16x16x32_bf16(AxL, BxH_, a, 0, 0, 0);
        xn[fi] = a;
        f32x4 b = cin_hn[fi];
        b = __builtin_amdgcn_mfma_f32_16x16x32_bf16(AhH, BhH_, b, 0, 0, 0);
        b = __builtin_amdgcn_mfma_f32_16x16x32_bf16(AhH, BhL_, b, 0, 0, 0);
        b = __builtin_amdgcn_mfma_f32_16x16x32_bf16(AhL, BhH_, b, 0, 0, 0);
        hn[fi] = b;
    }

    #pragma unroll
    for (int q = 0; q < 4; q++) {
        int row = blk0 + wid*16 + 4*kg + q;
        if (row < C) {
            #pragma unroll
            for (int fi = 0; fi < 2; fi++) {
                float r = sigmoidf_(arz[fi][q]);
                float z = sigmoidf_(arz[2+fi][q]);
                float n = tanhf_(fmaf(r, hn[fi][q], xn[fi][q]));
                float ho = h_c[(size_t)row * FD + c + 16*fi];
                float hv = fmaf(z, ho - n, n);
                h_c[(size_t)row * FD + c + 16*fi] = hv;
                hcb[(size_t)row * FD + c + 16*fi] = (__bf16)hv;
            }
        }
    }
}

// ---------------- fallback kernels (atomic path, raw weights) ---------------

__global__ __launch_bounds__(256) void path_update_kernel(
    const float* __restrict__ h_c, float* __restrict__ h_p,
    const int* __restrict__ p2c,
    const float* __restrict__ Wih, const float* __restrict__ Whh,
    const float* __restrict__ bih, const float* __restrict__ bhh, int P)
{
    int p = blockIdx.x * blockDim.x + threadIdx.x;
    if (p >= P) return;

    float h[FD];
    const float4* hp4 = (const float4*)(h_p + (size_t)p * FD);
    #pragma unroll
    for (int i = 0; i < FD / 4; i++) {
        float4 v = hp4[i];
        h[4*i] = v.x; h[4*i+1] = v.y; h[4*i+2] = v.z; h[4*i+3] = v.w;
    }

    int idx[KNB];
    const int4* pi = (const int4*)(p2c + (size_t)p * KNB);
    int4 i0 = pi[0], i1 = pi[1];
    idx[0]=i0.x; idx[1]=i0.y; idx[2]=i0.z; idx[3]=i0.w;
    idx[4]=i1.x; idx[5]=i1.y; idx[6]=i1.z; idx[7]=i1.w;

    for (int k = 0; k < KNB; k++) {
        float x[FD];
        const float4* xr = (const float4*)(h_c + (size_t)idx[k] * FD);
        #pragma unroll
        for (int i = 0; i < FD / 4; i++) {
            float4 v = xr[i];
            x[4*i] = v.x; x[4*i+1] = v.y; x[4*i+2] = v.z; x[4*i+3] = v.w;
        }

        float hn[FD];
        #pragma unroll 4
        for (int j = 0; j < FD; j++) {
            float air = bih[j],        ahr = bhh[j];
            float aiz = bih[FD + j],   ahz = bhh[FD + j];
            float ain = bih[2*FD + j], ahn = bhh[2*FD + j];
            #pragma unroll
            for (int i = 0; i < FD; i++) {
                air = fmaf(Wih[j*FD + i],          x[i], air);
                ahr = fmaf(Whh[j*FD + i],          h[i], ahr);
                aiz = fmaf(Wih[(FD + j)*FD + i],   x[i], aiz);
                ahz = fmaf(Whh[(FD + j)*FD + i],   h[i], ahz);
                ain = fmaf(Wih[(2*FD + j)*FD + i], x[i], ain);
                ahn = fmaf(Whh[(2*FD + j)*FD + i], h[i], ahn);
            }
            float r = sigmoidf_(air + ahr);
            float z = sigmoidf_(aiz + ahz);
            float n = tanhf_(ain + r * ahn);
            hn[j] = (1.0f - z) * n + z * h[j];
        }
        #pragma unroll
        for (int j = 0; j < FD; j++) h[j] = hn[j];
    }

    float4* hpw = (float4*)(h_p + (size_t)p * FD);
    #pragma unroll
    for (int i = 0; i < FD / 4; i++) {
        float4 v;
        v.x = h[4*i]; v.y = h[4*i+1]; v.z = h[4*i+2]; v.w = h[4*i+3];
        hpw[i] = v;
    }
}

__global__ __launch_bounds__(256) void scatter_agg_atomic_kernel(
    const float* __restrict__ h_p, const int* __restrict__ p2c,
    float* __restrict__ agg, int P)
{
    int p = blockIdx.x * blockDim.x + threadIdx.x;
    if (p >= P) return;
    const float* hr = h_p + (size_t)p * FD;
    #pragma unroll
    for (int k = 0; k < KNB; k++) {
        int c = p2c[(size_t)p * KNB + k];
        float* ar = agg + (size_t)c * FD;
        #pragma unroll
        for (int i = 0; i < FD; i++) atomicAdd(ar + i, hr[i]);
    }
}

__global__ __launch_bounds__(256) void channel_update_kernel(
    const float* __restrict__ agg, float* __restrict__ h_c,
    const float* __restrict__ Wih, const float* __restrict__ Whh,
    const float* __restrict__ bih, const float* __restrict__ bhh, int C)
{
    int c = blockIdx.x * blockDim.x + threadIdx.x;
    if (c >= C) return;

    float h[FD], x[FD];
    const float4* hr = (const float4*)(h_c + (size_t)c * FD);
    const float4* xr = (const float4*)(agg + (size_t)c * FD);
    #pragma unroll
    for (int i = 0; i < FD / 4; i++) {
        float4 v = hr[i];
        h[4*i] = v.x; h[4*i+1] = v.y; h[4*i+2] = v.z; h[4*i+3] = v.w;
        float4 w = xr[i];
        x[4*i] = w.x; x[4*i+1] = w.y; x[4*i+2] = w.z; x[4*i+3] = w.w;
    }

    float hn[FD];
    #pragma unroll 4
    for (int j = 0; j < FD; j++) {
        float air = bih[j],        ahr = bhh[j];
        float aiz = bih[FD + j],   ahz = bhh[FD + j];
        float ain = bih[2*FD + j], ahn = bhh[2*FD + j];
        #pragma unroll
        for (int i = 0; i < FD; i++) {
            air = fmaf(Wih[j*FD + i],          x[i], air);
            ahr = fmaf(Whh[j*FD + i],          h[i], ahr);
            aiz = fmaf(Wih[(FD + j)*FD + i],   x[i], aiz);
            ahz = fmaf(Whh[(FD + j)*FD + i],   h[i], ahz);
            ain = fmaf(Wih[(2*FD + j)*FD + i], x[i], ain);
            ahn = fmaf(Whh[(2*FD + j)*FD + i], h[i], ahn);
        }
        float r = sigmoidf_(air + ahr);
        float z = sigmoidf_(aiz + ahz);
        float n = tanhf_(ain + r * ahn);
        hn[j] = (1.0f - z) * n + z * h[j];
    }

    float4* hw = (float4*)(h_c + (size_t)c * FD);
    #pragma unroll
    for (int i = 0; i < FD / 4; i++) {
        float4 v;
        v.x = hn[4*i]; v.y = hn[4*i+1]; v.z = hn[4*i+2]; v.w = hn[4*i+3];
        hw[i] = v;
    }
}

extern "C" void kernel_launch(void* const* d_in, const int* in_sizes, int n_in,
                              void* d_out, int out_size, void* d_ws, size_t ws_size,
                              hipStream_t stream) {
    const float* paths    = (const float*)d_in[0];
    const float* channels = (const float*)d_in[1];
    const int*   p2c      = (const int*)d_in[2];
    const float* Wih1 = (const float*)d_in[3];
    const float* Whh1 = (const float*)d_in[4];
    const float* bih1 = (const float*)d_in[5];
    const float* bhh1 = (const float*)d_in[6];
    const float* Wih2 = (const float*)d_in[7];
    const float* Whh2 = (const float*)d_in[8];
    const float* bih2 = (const float*)d_in[9];
    const float* bhh2 = (const float*)d_in[10];

    const int P = in_sizes[0] / FD;     // 200000
    const int C = in_sizes[1] / FD;     // 50000
    const int E = P * KNB;              // 1.6M edges
    const int NR = (C + 255) >> 8;      // 196 buckets

    float* h_p = (float*)d_out;                  // [P*FD]
    float* h_c = h_p + (size_t)P * FD;           // [C*FD]

    // ws: bsum[NR] bbase[NR] | offsets[C+1] | bstart[NR+1] | elist[E] | hcb |
    //     wbufs(6) | UNION{ build: ebuf[E](int2)+cnt1[NCH*NR] | iter: hpb }
    char* ws = (char*)d_ws;
    size_t bs_off  = 0;
    size_t ofs_off = (bs_off + (size_t)(2 * NR) * 4 + 255) & ~(size_t)255;
    size_t bst_off = (ofs_off + (size_t)(C + 1) * 4 + 255) & ~(size_t)255;
    size_t el_off  = (bst_off + (size_t)(NR + 1) * 4 + 255) & ~(size_t)255;
    size_t hcb_off = (el_off + (size_t)E * 4 + 255) & ~(size_t)255;
    size_t wb_off  = (hcb_off + (size_t)C * FD * 2 + 255) & ~(size_t)255;
    size_t wmat_b  = (size_t)96 * FD * 2;                 // 6 KB per matrix
    size_t uni_off = (wb_off + 6 * wmat_b + 255) & ~(size_t)255;
    size_t ebuf_b  = (size_t)E * 8;
    size_t cnt1_b  = (size_t)NCH * NR * 4;
    size_t hpb_b   = (size_t)P * FD * 2;
    size_t bld_b   = ebuf_b + cnt1_b;
    size_t uni_b   = (hpb_b > bld_b) ? hpb_b : bld_b;

    int*    bsum    = (int*)(ws + bs_off);
    int*    bbase   = bsum + NR;
    int*    offsets = (int*)(ws + ofs_off);
    int*    bstart  = (int*)(ws + bst_off);
    int*    elist   = (int*)(ws + el_off);
    __bf16* hcb     = (__bf16*)(ws + hcb_off);
    __bf16* w1x     = (__bf16*)(ws + wb_off);
    __bf16* w1h     = (__bf16*)(ws + wb_off + 1 * wmat_b);
    __bf16* w2xH    = (__bf16*)(ws + wb_off + 2 * wmat_b);
    __bf16* w2xL    = (__bf16*)(ws + wb_off + 3 * wmat_b);
    __bf16* w2hH    = (__bf16*)(ws + wb_off + 4 * wmat_b);
    __bf16* w2hL    = (__bf16*)(ws + wb_off + 5 * wmat_b);
    int2*   ebuf    = (int2*)(ws + uni_off);
    int*    cnt1    = (int*)(ws + uni_off + ebuf_b);
    __bf16* hpb     = (__bf16*)(ws + uni_off);   // time-disjoint w/ ebuf/cnt1

    const bool mfma_ok = (P % 64 == 0) && (C <= 65536);
    const bool tier1 = mfma_ok && (ws_size >= uni_off + uni_b);

    dim3 pb(256), pg((P + 255) / 256);
    dim3 cb(256), cg((C + 255) / 256);

    if (tier1) {
        hipMemcpyAsync(h_p, paths, (size_t)P * FD * sizeof(float),
                       hipMemcpyDeviceToDevice, stream);
        int n8 = C * FD / 8;
        hc_init_kernel<<<(n8 + 255) / 256, 256, 0, stream>>>(channels, h_c, hcb, n8);
        wconv_kernel<<<(96 * FD + 255) / 256, 256, 0, stream>>>(
            Wih1, Whh1, Wih2, Whh2, w1x, w1h, w2xH, w2xL, w2hH, w2hL);

        bincount_kernel<<<NCH, 256, 0, stream>>>(p2c, cnt1, E, NR);
        scan_chunks_kernel<<<1, 256, 0, stream>>>(cnt1, bstart, NR, E);
        binfill_kernel<<<NCH, 256, 0, stream>>>(p2c, cnt1, ebuf, E, NR);
        buckscan_kernel<<<NR, 256, 0, stream>>>(ebuf, bstart, offsets, bsum, C);
        scan_bsums_kernel<<<1, 256, 0, stream>>>(bsum, bbase, offsets, NR, C, E);
        addback_kernel<<<cg, cb, 0, stream>>>(offsets, bbase, C);
        buckfill_kernel<<<NR, 256, 0, stream>>>(ebuf, bstart, offsets, elist, C);

        const int ntiles16 = P / 16;                    // 12500 wave-tiles
        int pgrid = ntiles16 < 4096 ? ntiles16 : 4096;  // residency fill
        dim3 xg((C + 31) / 32), xb(128);
        for (int it = 0; it < NITER; it++) {
            path_fused_kernel<<<pgrid, 64, 0, stream>>>(h_p, p2c, hcb,
                                                        w1x, w1h, bih1, bhh1,
                                                        hpb, ntiles16);
            gchannel_kernel<<<xg, xb, 0, stream>>>(hpb, offsets, elist, h_c,
                                                   w2xH, w2xL, w2hH, w2hL,
                                                   bih2, bhh2, hcb, C);
        }
    } else {
        float* agg0 = (float*)d_ws;
        size_t aggf_b = (size_t)C * FD * sizeof(float);
        hipMemcpyAsync(h_p, paths, (size_t)P * FD * sizeof(float),
                       hipMemcpyDeviceToDevice, stream);
        hipMemcpyAsync(h_c, channels, (size_t)C * FD * sizeof(float),
                       hipMemcpyDeviceToDevice, stream);
        for (int it = 0; it < NITER; it++) {
            path_update_kernel<<<pg, pb, 0, stream>>>(h_c, h_p, p2c,
                                                      Wih1, Whh1, bih1, bhh1, P);
            hipMemsetAsync(agg0, 0, aggf_b, stream);
            scatter_agg_atomic_kernel<<<pg, pb, 0, stream>>>(h_p, p2c, agg0, P);
            channel_update_kernel<<<cg, cb, 0, stream>>>(agg0, h_c,
                                                         Wih2, Whh2, bih2, bhh2, C);
        }
    }
}